// Round 7
// baseline (393.265 us; speedup 1.0000x reference)
//
#include <hip/hip_runtime.h>
#include <hip/hip_bf16.h>

typedef unsigned short u16;
typedef unsigned int u32;
typedef unsigned long long u64;
typedef __attribute__((ext_vector_type(8))) short short8;
typedef __attribute__((ext_vector_type(4))) float floatx4;

#define AS1 __attribute__((address_space(1)))
#define AS3 __attribute__((address_space(3)))

// ---- bf16 <-> f32 helpers (raw bits, RNE) ----
__device__ __forceinline__ float bf2f(u16 u) {
    u32 x = ((u32)u) << 16;
    float f;
    __builtin_memcpy(&f, &x, 4);
    return f;
}
__device__ __forceinline__ u16 f2bf(float f) {
    u32 x;
    __builtin_memcpy(&x, &f, 4);
    u32 r = (x + 0x7fffu + ((x >> 16) & 1u)) >> 16;
    return (u16)r;
}
// packed 2xf32 -> 2xbf16 (v_cvt_pk_bf16_f32), returned as u32 (lo=first)
__device__ __forceinline__ u32 f2bf_pk(float a, float b) {
    __hip_bfloat162 h = __float22bfloat162_rn(float2{a, b});
    u32 r;
    __builtin_memcpy(&r, &h, 4);
    return r;
}

// ==========================================================================
// Merged prep: z<4 = weight transposes (f32 RxC -> bf16 CxR), z=4 = X cast.
// ==========================================================================
__global__ __launch_bounds__(1024) void prep_weights(const float* __restrict__ Wq,
                                                     const float* __restrict__ Wk,
                                                     const float* __restrict__ Wv,
                                                     const float* __restrict__ Wo,
                                                     const float* __restrict__ X,
                                                     u16* __restrict__ WqkvT,
                                                     u16* __restrict__ WoT,
                                                     u16* __restrict__ Xb) {
    const int z = blockIdx.z;
    const int tx = threadIdx.x, ty = threadIdx.y;
    if (z == 4) {  // convert X: 2048 active blocks x 4096 floats
        int idx = blockIdx.y * 64 + blockIdx.x;
        if (idx >= 2048) return;
        int tid = ty * 32 + tx;
        size_t i = (size_t)idx * 4096 + (size_t)tid * 4;
        float4 v = *(const float4*)(X + i);
        u16 o[4] = {f2bf(v.x), f2bf(v.y), f2bf(v.z), f2bf(v.w)};
        *(u64*)(Xb + i) = *(u64*)o;
        return;
    }
    const float* in;
    u16* out;
    int C;
    if (z == 0) { in = Wq; out = WqkvT; C = 2048; }
    else if (z == 1) { in = Wk; out = WqkvT + 2048 * 2048; C = 1024; }
    else if (z == 2) { in = Wv; out = WqkvT + 3072 * 2048; C = 1024; }
    else { in = Wo; out = WoT; C = 2048; }
    const int c0 = blockIdx.x * 32, r0 = blockIdx.y * 32;
    if (c0 >= C) return;
    __shared__ u16 t[32][33];
    t[ty][tx] = f2bf(in[(size_t)(r0 + ty) * C + c0 + tx]);
    __syncthreads();
    out[(size_t)(c0 + ty) * 2048 + r0 + tx] = t[tx][ty];
}

// ==========================================================================
// GEMM: C[M,N] = A[M,K] @ Bt[N,K]^T (bf16 in, fp32 acc, OUT_T out)
// 256x256 tile, BK=64, 512 thr (8 waves 2Mx4N), 8-phase-per-2-K-tiles
// schedule: counted vmcnt(6), raw s_barrier, XOR-swizzled LDS, setprio.
// ==========================================================================
template <typename OUT_T>
__global__ __launch_bounds__(512, 2) void gemm256(const u16* __restrict__ A,
                                                  const u16* __restrict__ Bt,
                                                  OUT_T* __restrict__ C,
                                                  int M, int N, int K) {
    (void)M;
    __shared__ __align__(16) u16 lds[2][2][2][128 * 64];  // [buf][A/B][half][r*64+c]
    const int tid = threadIdx.x;
    const int wave = tid >> 6, lane = tid & 63;
    const int lr = lane & 15, lq = lane >> 4;
    const int wm = wave >> 2, wn = wave & 3;
    const int m0 = blockIdx.y * 256, n0 = blockIdx.x * 256;

    const int srow = lane >> 3;                    // 0..7 within 8-row group
    const int schunk = ((lane & 7) ^ srow) << 3;   // source chunk (elems)
    const int slot = wave << 1;

    auto stage = [&](const u16* src, int rbase, int buf, int mat, int half, int k0) {
#pragma unroll
        for (int j = 0; j < 2; j++) {
            int r = rbase + half * 128 + (slot + j) * 8 + srow;
            __builtin_amdgcn_global_load_lds(
                (const AS1 void*)(src + (size_t)r * K + k0 + schunk),
                (AS3 void*)(&lds[buf][mat][half][(slot + j) * 512]), 16, 0, 0);
        }
    };

    floatx4 zf = {0.f, 0.f, 0.f, 0.f};
    floatx4 acc[8][4];
#pragma unroll
    for (int i = 0; i < 8; i++)
#pragma unroll
        for (int jn = 0; jn < 4; jn++) acc[i][jn] = zf;

    const int NT = K >> 6;

    stage(Bt, n0, 0, 1, 0, 0);
    stage(Bt, n0, 0, 1, 1, 0);
    stage(A, m0, 0, 0, 0, 0);
    stage(A, m0, 0, 0, 1, 0);
    if (NT > 1) {
        stage(Bt, n0, 1, 1, 0, 64);
        stage(Bt, n0, 1, 1, 1, 64);
        stage(A, m0, 1, 0, 0, 64);
        asm volatile("s_waitcnt vmcnt(6)" ::: "memory");
    } else {
        asm volatile("s_waitcnt vmcnt(0)" ::: "memory");
    }
    __builtin_amdgcn_s_barrier();

    for (int kt = 0; kt < NT; kt++) {
        const int b = kt & 1;
        const u16* Ab = &lds[b][0][wm][0];
        const u16* Bb = &lds[b][1][wn >> 1][0];
        const int brow = (wn & 1) * 64;
        const int sx = lr & 7;
        const int nk = (kt + 2) << 6;

        // ---- phase 0 ----
        short8 bf0[4], bf1[4], af[4];
#pragma unroll
        for (int jn = 0; jn < 4; jn++) {
            int rh = brow + jn * 16 + lr;
            bf0[jn] = *(const short8*)(Bb + rh * 64 + ((lq ^ sx) << 3));
            bf1[jn] = *(const short8*)(Bb + rh * 64 + (((4 + lq) ^ sx) << 3));
        }
#pragma unroll
        for (int i = 0; i < 4; i++)
            af[i] = *(const short8*)(Ab + (i * 16 + lr) * 64 + ((lq ^ sx) << 3));
        if (kt + 1 < NT) stage(A, m0, b ^ 1, 0, 1, (kt + 1) << 6);
        __builtin_amdgcn_s_barrier();
        asm volatile("s_waitcnt lgkmcnt(0)" ::: "memory");
        __builtin_amdgcn_sched_barrier(0);
        __builtin_amdgcn_s_setprio(1);
#pragma unroll
        for (int i = 0; i < 4; i++)
#pragma unroll
            for (int jn = 0; jn < 4; jn++)
                acc[i][jn] = __builtin_amdgcn_mfma_f32_16x16x32_bf16(af[i], bf0[jn], acc[i][jn], 0, 0, 0);
        __builtin_amdgcn_s_setprio(0);
        __builtin_amdgcn_s_barrier();

        // ---- phase 1 ----
        short8 ag[4];
#pragma unroll
        for (int i = 0; i < 4; i++)
            ag[i] = *(const short8*)(Ab + ((i + 4) * 16 + lr) * 64 + ((lq ^ sx) << 3));
        if (kt + 2 < NT) stage(Bt, n0, b, 1, 0, nk);
        __builtin_amdgcn_s_barrier();
        asm volatile("s_waitcnt lgkmcnt(0)" ::: "memory");
        __builtin_amdgcn_sched_barrier(0);
        __builtin_amdgcn_s_setprio(1);
#pragma unroll
        for (int i = 0; i < 4; i++)
#pragma unroll
            for (int jn = 0; jn < 4; jn++)
                acc[i + 4][jn] = __builtin_amdgcn_mfma_f32_16x16x32_bf16(ag[i], bf0[jn], acc[i + 4][jn], 0, 0, 0);
        __builtin_amdgcn_s_setprio(0);
        __builtin_amdgcn_s_barrier();

        // ---- phase 2 ----
        short8 c0[4], c1[4];
#pragma unroll
        for (int i = 0; i < 4; i++) {
            c0[i] = *(const short8*)(Ab + (i * 16 + lr) * 64 + (((4 + lq) ^ sx) << 3));
            c1[i] = *(const short8*)(Ab + ((i + 4) * 16 + lr) * 64 + (((4 + lq) ^ sx) << 3));
        }
        if (kt + 2 < NT) stage(Bt, n0, b, 1, 1, nk);
        __builtin_amdgcn_s_barrier();
        asm volatile("s_waitcnt lgkmcnt(0)" ::: "memory");
        __builtin_amdgcn_sched_barrier(0);
        __builtin_amdgcn_s_setprio(1);
#pragma unroll
        for (int i = 0; i < 4; i++)
#pragma unroll
            for (int jn = 0; jn < 4; jn++)
                acc[i][jn] = __builtin_amdgcn_mfma_f32_16x16x32_bf16(c0[i], bf1[jn], acc[i][jn], 0, 0, 0);
        __builtin_amdgcn_s_setprio(0);
        __builtin_amdgcn_s_barrier();

        // ---- phase 3 ----
        if (kt + 2 < NT) stage(A, m0, b, 0, 0, nk);
        __builtin_amdgcn_s_barrier();
        __builtin_amdgcn_s_setprio(1);
#pragma unroll
        for (int i = 0; i < 4; i++)
#pragma unroll
            for (int jn = 0; jn < 4; jn++)
                acc[i + 4][jn] = __builtin_amdgcn_mfma_f32_16x16x32_bf16(c1[i], bf1[jn], acc[i + 4][jn], 0, 0, 0);
        __builtin_amdgcn_s_setprio(0);
        if (kt + 2 < NT) asm volatile("s_waitcnt vmcnt(6)" ::: "memory");
        else asm volatile("s_waitcnt vmcnt(0)" ::: "memory");
        __builtin_amdgcn_s_barrier();
    }

#pragma unroll
    for (int i = 0; i < 8; i++)
#pragma unroll
        for (int jn = 0; jn < 4; jn++)
#pragma unroll
            for (int r = 0; r < 4; r++) {
                int row = m0 + wm * 128 + i * 16 + lq * 4 + r;
                int col = n0 + wn * 64 + jn * 16 + lr;
                if constexpr (sizeof(OUT_T) == 2)
                    C[(size_t)row * N + col] = f2bf(acc[i][jn][r]);
                else
                    C[(size_t)row * N + col] = acc[i][jn][r];
            }
}

// ==========================================================================
// GEMM: BM=256 x BN=128, BK=64, 512 thr = 8 waves (4M x 2N), 64x64/wave.
// Same 8-phase counted-vmcnt schedule; 3 stage-units/tile -> vmcnt(4).
// Grid (N/128, M/256) -> 256 blocks for the Wo GEMM (full GPU).
// ==========================================================================
template <typename OUT_T>
__global__ __launch_bounds__(512, 2) void gemm128n(const u16* __restrict__ A,
                                                   const u16* __restrict__ Bt,
                                                   OUT_T* __restrict__ C,
                                                   int M, int N, int K) {
    (void)M;
    __shared__ __align__(16) u16 Abuf[2][2][128 * 64];  // [buf][half][r*64+c]
    __shared__ __align__(16) u16 Bbuf[2][128 * 64];     // [buf][r*64+c]
    const int tid = threadIdx.x;
    const int wave = tid >> 6, lane = tid & 63;
    const int lr = lane & 15, lq = lane >> 4;
    const int wm = wave >> 1, wn = wave & 1;
    const int m0 = blockIdx.y * 256, n0 = blockIdx.x * 128;

    const int srow = lane >> 3;
    const int schunk = ((lane & 7) ^ srow) << 3;
    const int slot = wave << 1;

    auto stage = [&](const u16* src, int rowbase, u16* ldsbase, int k0) {
#pragma unroll
        for (int j = 0; j < 2; j++) {
            int r = rowbase + (slot + j) * 8 + srow;
            __builtin_amdgcn_global_load_lds(
                (const AS1 void*)(src + (size_t)r * K + k0 + schunk),
                (AS3 void*)(ldsbase + (slot + j) * 512), 16, 0, 0);
        }
    };

    floatx4 zf = {0.f, 0.f, 0.f, 0.f};
    floatx4 acc[4][4];
#pragma unroll
    for (int i = 0; i < 4; i++)
#pragma unroll
        for (int jn = 0; jn < 4; jn++) acc[i][jn] = zf;

    const int NT = K >> 6;

    // prologue: t0 = {Ah0, Ah1, B}; t1 = {Ah0, B} (Ah1(t1) comes in t0.ph0)
    stage(A, m0, &Abuf[0][0][0], 0);
    stage(A, m0 + 128, &Abuf[0][1][0], 0);
    stage(Bt, n0, &Bbuf[0][0], 0);
    if (NT > 1) {
        stage(A, m0, &Abuf[1][0][0], 64);
        stage(Bt, n0, &Bbuf[1][0], 64);
        asm volatile("s_waitcnt vmcnt(4)" ::: "memory");
    } else {
        asm volatile("s_waitcnt vmcnt(0)" ::: "memory");
    }
    __builtin_amdgcn_s_barrier();

    for (int kt = 0; kt < NT; kt++) {
        const int b = kt & 1;
        const u16* Ab = &Abuf[b][wm >> 1][0];
        const u16* Bb = &Bbuf[b][0];
        const int ar = (wm & 1) * 64;
        const int br = wn * 64;
        const int sx = lr & 7;
        const int nk = (kt + 2) << 6;

        // ---- phase 0: read bf0,bf1,af(kk0); stage Ah1(kt+1); mfma kk0 i0-1 ----
        short8 bf0[4], bf1[4], af[4];
#pragma unroll
        for (int jn = 0; jn < 4; jn++) {
            int rh = br + jn * 16 + lr;
            bf0[jn] = *(const short8*)(Bb + rh * 64 + ((lq ^ sx) << 3));
            bf1[jn] = *(const short8*)(Bb + rh * 64 + (((4 + lq) ^ sx) << 3));
        }
#pragma unroll
        for (int i = 0; i < 4; i++)
            af[i] = *(const short8*)(Ab + (ar + i * 16 + lr) * 64 + ((lq ^ sx) << 3));
        if (kt + 1 < NT) stage(A, m0 + 128, &Abuf[b ^ 1][1][0], (kt + 1) << 6);
        __builtin_amdgcn_s_barrier();
        asm volatile("s_waitcnt lgkmcnt(0)" ::: "memory");
        __builtin_amdgcn_sched_barrier(0);
        __builtin_amdgcn_s_setprio(1);
#pragma unroll
        for (int i = 0; i < 2; i++)
#pragma unroll
            for (int jn = 0; jn < 4; jn++)
                acc[i][jn] = __builtin_amdgcn_mfma_f32_16x16x32_bf16(af[i], bf0[jn], acc[i][jn], 0, 0, 0);
        __builtin_amdgcn_s_setprio(0);
        __builtin_amdgcn_s_barrier();

        // ---- phase 1: stage B(kt+2); mfma kk0 i2-3 ----
        if (kt + 2 < NT) stage(Bt, n0, &Bbuf[b][0], nk);
        __builtin_amdgcn_s_barrier();
        __builtin_amdgcn_s_setprio(1);
#pragma unroll
        for (int i = 2; i < 4; i++)
#pragma unroll
            for (int jn = 0; jn < 4; jn++)
                acc[i][jn] = __builtin_amdgcn_mfma_f32_16x16x32_bf16(af[i], bf0[jn], acc[i][jn], 0, 0, 0);
        __builtin_amdgcn_s_setprio(0);
        __builtin_amdgcn_s_barrier();

        // ---- phase 2: read ag(kk1); mfma kk1 i0-1 ----
        short8 ag[4];
#pragma unroll
        for (int i = 0; i < 4; i++)
            ag[i] = *(const short8*)(Ab + (ar + i * 16 + lr) * 64 + (((4 + lq) ^ sx) << 3));
        __builtin_amdgcn_s_barrier();
        asm volatile("s_waitcnt lgkmcnt(0)" ::: "memory");
        __builtin_amdgcn_sched_barrier(0);
        __builtin_amdgcn_s_setprio(1);
#pragma unroll
        for (int i = 0; i < 2; i++)
#pragma unroll
            for (int jn = 0; jn < 4; jn++)
                acc[i][jn] = __builtin_amdgcn_mfma_f32_16x16x32_bf16(ag[i], bf1[jn], acc[i][jn], 0, 0, 0);
        __builtin_amdgcn_s_setprio(0);
        __builtin_amdgcn_s_barrier();

        // ---- phase 3: stage Ah0(kt+2); mfma kk1 i2-3; counted vmcnt ----
        if (kt + 2 < NT) stage(A, m0, &Abuf[b][0][0], nk);
        __builtin_amdgcn_s_barrier();
        __builtin_amdgcn_s_setprio(1);
#pragma unroll
        for (int i = 2; i < 4; i++)
#pragma unroll
            for (int jn = 0; jn < 4; jn++)
                acc[i][jn] = __builtin_amdgcn_mfma_f32_16x16x32_bf16(ag[i], bf1[jn], acc[i][jn], 0, 0, 0);
        __builtin_amdgcn_s_setprio(0);
        if (kt + 2 < NT) asm volatile("s_waitcnt vmcnt(4)" ::: "memory");
        else asm volatile("s_waitcnt vmcnt(0)" ::: "memory");
        __builtin_amdgcn_s_barrier();
    }

#pragma unroll
    for (int i = 0; i < 4; i++)
#pragma unroll
        for (int jn = 0; jn < 4; jn++)
#pragma unroll
            for (int r = 0; r < 4; r++) {
                int row = m0 + wm * 64 + i * 16 + lq * 4 + r;
                int col = n0 + wn * 64 + jn * 16 + lr;
                if constexpr (sizeof(OUT_T) == 2)
                    C[(size_t)row * N + col] = f2bf(acc[i][jn][r]);
                else
                    C[(size_t)row * N + col] = acc[i][jn][r];
            }
}

// ==========================================================================
// Merged post-QKV prep: blocks <24576 do RMS-norm+RoPE on Q/K (in place);
// blocks >=24576 transpose V into Vt (b,kv,d,s). 256 threads each.
// ==========================================================================
__global__ __launch_bounds__(256) void prep_qkv(u16* __restrict__ QKV,
                                                u16* __restrict__ Vt,
                                                const float* __restrict__ cosb,
                                                const float* __restrict__ sinb,
                                                const float* __restrict__ qw,
                                                const float* __restrict__ kw) {
    const int bx = blockIdx.x;
    const int tid = threadIdx.x;
    if (bx >= 24576) {  // V transpose: 4096 blocks
        const int idx = bx - 24576;
        const int s0 = (idx & 63) * 32;
        const int d0 = ((idx >> 6) & 3) * 32;
        const int zz = idx >> 8;
        const int b = zz >> 3, kv = zz & 7;
        __shared__ u16 t[32][33];
        const int tx = tid & 31, ty0 = tid >> 5;  // 32 x 8
#pragma unroll
        for (int p = 0; p < 4; p++) {
            int r = ty0 + p * 8;
            t[r][tx] = QKV[(size_t)(b * 2048 + s0 + r) * 4096 + 3072 + kv * 128 + d0 + tx];
        }
        __syncthreads();
#pragma unroll
        for (int p = 0; p < 4; p++) {
            int r = ty0 + p * 8;
            Vt[(size_t)((b * 8 + kv) * 128 + d0 + r) * 2048 + s0 + tx] = t[tx][r];
        }
        return;
    }
    const int wave = tid >> 6, lane = tid & 63;
    const int t = bx * 4 + wave;  // 0..98303
    u16* ptr;
    const float* w;
    float scale;
    int bs;
    if (t < 65536) {
        bs = t >> 4;
        ptr = QKV + (size_t)bs * 4096 + (t & 15) * 128;
        w = qw;
        scale = 0.08838834764831845f * 1.4426950408889634f;  // D^-0.5 * log2(e)
    } else {
        int t2 = t - 65536;
        bs = t2 >> 3;
        ptr = QKV + (size_t)bs * 4096 + 2048 + (t2 & 7) * 128;
        w = kw;
        scale = 1.0f;
    }
    const int d = lane * 2;
    u32 xv = *(const u32*)(ptr + d);
    float x0 = bf2f((u16)(xv & 0xffff)), x1 = bf2f((u16)(xv >> 16));
    float ss = x0 * x0 + x1 * x1;
#pragma unroll
    for (int off = 1; off < 64; off <<= 1) ss += __shfl_xor(ss, off);
    float rn = rsqrtf(ss * (1.0f / 128.0f) + 1e-6f);
    float2 wv = *(const float2*)(w + d);
    float y0 = x0 * rn * wv.x;
    float y1 = x1 * rn * wv.y;
    float p0 = __shfl_xor(y0, 32);
    float p1 = __shfl_xor(y1, 32);
    float sgn = (lane < 32) ? -1.0f : 1.0f;
    float2 cv = *(const float2*)(cosb + (size_t)bs * 128 + d);
    float2 sv = *(const float2*)(sinb + (size_t)bs * 128 + d);
    float o0 = (y0 * cv.x + sgn * p0 * sv.x) * scale;
    float o1 = (y1 * cv.y + sgn * p1 * sv.y) * scale;
    *(u32*)(ptr + d) = (u32)f2bf(o0) | ((u32)f2bf(o1) << 16);
}

// ==========================================================================
// Causal GQA flash attention, transposed-score formulation.
// QBLK=64 (4 waves, 256 thr), KVBLK=64.
// LDS 50KB: K double-buffered (32KB) + V single-buffered (16KB) + ones rows
// (2KB) so PV's jn=8 column accumulates l = sum(P) inside the MFMA.
// Counted-vmcnt barriers (T4). 3 blocks/CU = 12 waves/CU.
// BALANCED flat 1024-grid decode: g=id>>8, c=id&255; qt alternates xx /
// 31-xx with g so (assuming round-robin CU ~ id mod 256) each CU's four
// blocks have qt = {xx, 31-xx, xx, 31-xx} -> exactly 66 key-tiles per CU
// (r6's LPT decode concentrated long chains: 80 vs 52 per CU). Perf
// heuristic only — coverage of all (qt,h,b) is exact regardless.
// T5 setprio, T13 defer-max.
// ==========================================================================
__global__ __launch_bounds__(256, 3) void attn_kernel(const u16* __restrict__ QKV,
                                                      const u16* __restrict__ Vt,
                                                      u16* __restrict__ O) {
    __shared__ __align__(16) u16 Ks[2][64 * 128];   // [key][d] swizzled, 32KB
    __shared__ __align__(16) u16 Vs[144 * 64];      // [d][key] swizzled + ones rows 128..143
    const int tid = threadIdx.x;
    const int wave = tid >> 6, lane = tid & 63;
    const int lr = lane & 15, lq = lane >> 4;

    // balanced complementary decode
    const int id = blockIdx.x;        // 0..1023
    const int g = id >> 8;            // 0..3
    const int c = id & 255;
    const int xx = c & 31;
    const int hh = c >> 5;            // 0..7
    const int qt = (g & 1) ? (31 - xx) : xx;
    const int h = hh + ((g & 2) << 2);
    const int b = g & 1;

    const int kv = h >> 1;
    const int q0 = qt * 64;
    const int wq = wave * 16;

    // async stage of one 64-key K tile into buffer `buf` (4 instrs/wave)
    auto stageK = [&](int buf, int k0s) {
#pragma unroll
        for (int jj = 0; jj < 4; jj++) {   // Ks: 64 rows x 256 B
            int r = wave * 16 + jj * 4 + (lane >> 4);
            int ch = (lane & 15) ^ (r & 15);   // inverse-swizzled source chunk
            __builtin_amdgcn_global_load_lds(
                (const AS1 void*)(QKV + (size_t)(b * 2048 + k0s + r) * 4096 + 2048 + kv * 128 + ch * 8),
                (AS3 void*)(&Ks[buf][(wave * 16 + jj * 4) * 128]), 16, 0, 0);
        }
    };
    // async stage of the V tile (rows 0..127 only; ones rows untouched)
    auto stageV = [&](int k0s) {
#pragma unroll
        for (int jj = 0; jj < 4; jj++) {   // Vs: 128 rows x 128 B
            int r = wave * 32 + jj * 8 + (lane >> 3);
            int ch = (lane & 7) ^ (r & 7);
            __builtin_amdgcn_global_load_lds(
                (const AS1 void*)(Vt + (size_t)((b * 8 + kv) * 128 + r) * 2048 + k0s + ch * 8),
                (AS3 void*)(&Vs[(wave * 32 + jj * 8) * 64]), 16, 0, 0);
        }
    };

    // fill ones rows (128..143) once; any swizzled read sees 1.0
    *(u64*)(&Vs[128 * 64 + tid * 4]) = 0x3F803F803F803F80ULL;
    asm volatile("s_waitcnt lgkmcnt(0)" ::: "memory");

    // Q fragments in registers (B-operand: n=qrow on lr, k=d on lq*8+j)
    short8 qf[4];
#pragma unroll
    for (int t = 0; t < 4; t++)
        qf[t] = *(const short8*)(QKV + (size_t)(b * 2048 + q0 + wq + lr) * 4096 + h * 128 + t * 32 + lq * 8);

    floatx4 zf = {0.f, 0.f, 0.f, 0.f};
    floatx4 oacc[9];   // [8] = l column (ones rows of Vs)
#pragma unroll
    for (int jn = 0; jn < 9; jn++) oacc[jn] = zf;
    float mstate = -1e30f;

    const int nIter = qt + 1;

    stageK(0, 0);

    for (int kt = 0; kt < nIter; kt++) {
        const int k0 = kt * 64;
        const int cur = kt & 1;
        // barrier #1: own outstanding = K(kt) only -> vmcnt(0) is exact.
        // Vs free (PV(kt-1) done), Ks[cur^1] free (QK^T(kt-1) done).
        asm volatile("s_waitcnt vmcnt(0)" ::: "memory");
        __builtin_amdgcn_s_barrier();
        stageV(k0);
        if (kt + 1 < nIter) stageK(cur ^ 1, k0 + 64);

        const bool active = (k0 <= q0 + wq + 15);
        u64 pb[4];
        if (active) {
            const u16* KsC = &Ks[cur][0];
            floatx4 sacc[4];
#pragma unroll
            for (int jm = 0; jm < 4; jm++) sacc[jm] = zf;
            __builtin_amdgcn_s_setprio(1);
#pragma unroll
            for (int t = 0; t < 4; t++) {
                short8 a[4];
#pragma unroll
                for (int jm = 0; jm < 4; jm++)
                    a[jm] = *(const short8*)(KsC + (jm * 16 + lr) * 128 + (((t * 4 + lq) ^ lr) << 3));
#pragma unroll
                for (int jm = 0; jm < 4; jm++)
                    sacc[jm] = __builtin_amdgcn_mfma_f32_16x16x32_bf16(a[jm], qf[t], sacc[jm], 0, 0, 0);
            }
            __builtin_amdgcn_s_setprio(0);

            if (k0 + 63 > q0 + wq) {
#pragma unroll
                for (int jm = 0; jm < 4; jm++) {
                    int diff = (q0 + wq + lr) - (k0 + jm * 16 + lq * 4);
#pragma unroll
                    for (int r = 0; r < 4; r++)
                        if (r > diff) sacc[jm][r] = -1e30f;
                }
            }

            // per-qrow max (tree within jm, then cross-quad)
            float mx = -1e30f;
#pragma unroll
            for (int jm = 0; jm < 4; jm++) {
                float a0 = fmaxf(sacc[jm][0], sacc[jm][1]);
                float a1 = fmaxf(sacc[jm][2], sacc[jm][3]);
                mx = fmaxf(mx, fmaxf(a0, a1));
            }
            mx = fmaxf(mx, __shfl_xor(mx, 16));
            mx = fmaxf(mx, __shfl_xor(mx, 32));

            // T13 defer-max: skip rescale when all rows grew <= 8 (log2 dom)
            bool defer = __all(mx - mstate <= 8.0f);
            float mnew = defer ? mstate : fmaxf(mstate, mx);

#pragma unroll
            for (int jm = 0; jm < 4; jm++)
#pragma unroll
                for (int r = 0; r < 4; r++)
                    sacc[jm][r] = exp2f(sacc[jm][r] - mnew);

            if (!defer) {
                float alpha = exp2f(mstate - mnew);
                mstate = mnew;
                float ao[4];
#pragma unroll
                for (int r = 0; r < 4; r++) ao[r] = __shfl(alpha, lq * 4 + r);
#pragma unroll
                for (int jn = 0; jn < 9; jn++)   // includes l column
#pragma unroll
                    for (int r = 0; r < 4; r++) oacc[jn][r] *= ao[r];
            }

#pragma unroll
            for (int jm = 0; jm < 4; jm++) {
                u32 lo = f2bf_pk(sacc[jm][0], sacc[jm][1]);
                u32 hi = f2bf_pk(sacc[jm][2], sacc[jm][3]);
                pb[jm] = (u64)lo | ((u64)hi << 32);
            }
        }

        // barrier #2: wait ONLY the V loads (first 4 in own queue);
        // K(kt+1) (4 newer loads) stays in flight across PV + next barrier.
        if (kt + 1 < nIter) asm volatile("s_waitcnt vmcnt(4)" ::: "memory");
        else                asm volatile("s_waitcnt vmcnt(0)" ::: "memory");
        __builtin_amdgcn_s_barrier();

        if (active) {
            // O += P @ [V | 1]; jn=8 accumulates l per qrow inside MFMA.
            __builtin_amdgcn_s_setprio(1);
#pragma unroll
            for (int t = 0; t < 2; t++) {
                union { short8 v; u64 q[2]; } pa;
                pa.q[0] = pb[2 * t];
                pa.q[1] = pb[2 * t + 1];
#pragma unroll
                for (int jn = 0; jn < 9; jn++) {
                    const u16* vrow = Vs + (jn * 16 + lr) * 64 + (lq & 1) * 4;
                    union { short8 v; u64 q[2]; } vb;
                    vb.q[0] = *(const u64*)(vrow + (((t * 4 + (lq >> 1)) ^ (lr & 7)) << 3));
                    vb.q[1] = *(const u64*)(vrow + (((t * 4 + 2 + (lq >> 1)) ^ (lr & 7)) << 3));
                    oacc[jn] = __builtin_amdgcn_mfma_f32_16x16x32_bf16(pa.v, vb.v, oacc[jn], 0, 0, 0);
                }
            }
            __builtin_amdgcn_s_setprio(0);
        }
    }

    // epilogue: l already at the right lanes (oacc[8][r], qrow = lq*4+r)
#pragma unroll
    for (int jn = 0; jn < 8; jn++)
#pragma unroll
        for (int r = 0; r < 4; r++) {
            int row = q0 + wq + lq * 4 + r;
            O[(size_t)(b * 2048 + row) * 2048 + h * 128 + jn * 16 + lr] =
                f2bf(oacc[jn][r] / oacc[8][r]);
        }
}

// ==========================================================================
extern "C" void kernel_launch(void* const* d_in, const int* in_sizes, int n_in,
                              void* d_out, int out_size, void* d_ws, size_t ws_size,
                              hipStream_t stream) {
    const float* X = (const float*)d_in[0];
    const float* cosb = (const float*)d_in[1];
    const float* sinb = (const float*)d_in[2];
    const float* Wq = (const float*)d_in[3];
    const float* Wk = (const float*)d_in[4];
    const float* Wv = (const float*)d_in[5];
    const float* Wo = (const float*)d_in[6];
    const float* qw = (const float*)d_in[7];
    const float* kw = (const float*)d_in[8];
    float* out = (float*)d_out;
    u16* ws = (u16*)d_ws;

    u16* WqkvT = ws;                    // 4096x2048 = 8388608
    u16* WoT = WqkvT + 8388608;         // 4194304
    u16* Xb = WoT + 4194304;            // 8388608 (dead after QKV GEMM)
    u16* QKVb = Xb + 8388608;           // 4096x4096 = 16777216
    u16* Vtb = QKVb + 16777216;         // 4194304
    u16* Ob = Xb;                       // alias
    // total 41,943,040 u16 = 83.9 MB

    prep_weights<<<dim3(64, 64, 5), dim3(32, 32), 0, stream>>>(Wq, Wk, Wv, Wo, X,
                                                               WqkvT, WoT, Xb);

    gemm256<u16><<<dim3(16, 16), 512, 0, stream>>>(Xb, WqkvT, QKVb, 4096, 4096, 2048);

    prep_qkv<<<28672, 256, 0, stream>>>(QKVb, Vtb, cosb, sinb, qw, kw);

    attn_kernel<<<1024, 256, 0, stream>>>(QKVb, Vtb, Ob);

    gemm128n<float><<<dim3(16, 16), 512, 0, stream>>>(Ob, WoT, out, 4096, 2048, 2048);
}

// Round 8
// 388.167 us; speedup vs baseline: 1.0131x; 1.0131x over previous
//
#include <hip/hip_runtime.h>
#include <hip/hip_bf16.h>

typedef unsigned short u16;
typedef unsigned int u32;
typedef unsigned long long u64;
typedef __attribute__((ext_vector_type(8))) short short8;
typedef __attribute__((ext_vector_type(4))) float floatx4;

#define AS1 __attribute__((address_space(1)))
#define AS3 __attribute__((address_space(3)))

// ---- bf16 <-> f32 helpers (raw bits, RNE) ----
__device__ __forceinline__ float bf2f(u16 u) {
    u32 x = ((u32)u) << 16;
    float f;
    __builtin_memcpy(&f, &x, 4);
    return f;
}
__device__ __forceinline__ u16 f2bf(float f) {
    u32 x;
    __builtin_memcpy(&x, &f, 4);
    u32 r = (x + 0x7fffu + ((x >> 16) & 1u)) >> 16;
    return (u16)r;
}
// packed 2xf32 -> 2xbf16 (v_cvt_pk_bf16_f32), returned as u32 (lo=first)
__device__ __forceinline__ u32 f2bf_pk(float a, float b) {
    __hip_bfloat162 h = __float22bfloat162_rn(float2{a, b});
    u32 r;
    __builtin_memcpy(&r, &h, 4);
    return r;
}

// ==========================================================================
// Merged prep: z<4 = weight transposes (f32 RxC -> bf16 CxR), z=4 = X cast.
// ==========================================================================
__global__ __launch_bounds__(1024) void prep_weights(const float* __restrict__ Wq,
                                                     const float* __restrict__ Wk,
                                                     const float* __restrict__ Wv,
                                                     const float* __restrict__ Wo,
                                                     const float* __restrict__ X,
                                                     u16* __restrict__ WqkvT,
                                                     u16* __restrict__ WoT,
                                                     u16* __restrict__ Xb) {
    const int z = blockIdx.z;
    const int tx = threadIdx.x, ty = threadIdx.y;
    if (z == 4) {  // convert X: 2048 active blocks x 4096 floats
        int idx = blockIdx.y * 64 + blockIdx.x;
        if (idx >= 2048) return;
        int tid = ty * 32 + tx;
        size_t i = (size_t)idx * 4096 + (size_t)tid * 4;
        float4 v = *(const float4*)(X + i);
        u16 o[4] = {f2bf(v.x), f2bf(v.y), f2bf(v.z), f2bf(v.w)};
        *(u64*)(Xb + i) = *(u64*)o;
        return;
    }
    const float* in;
    u16* out;
    int C;
    if (z == 0) { in = Wq; out = WqkvT; C = 2048; }
    else if (z == 1) { in = Wk; out = WqkvT + 2048 * 2048; C = 1024; }
    else if (z == 2) { in = Wv; out = WqkvT + 3072 * 2048; C = 1024; }
    else { in = Wo; out = WoT; C = 2048; }
    const int c0 = blockIdx.x * 32, r0 = blockIdx.y * 32;
    if (c0 >= C) return;
    __shared__ u16 t[32][33];
    t[ty][tx] = f2bf(in[(size_t)(r0 + ty) * C + c0 + tx]);
    __syncthreads();
    out[(size_t)(c0 + ty) * 2048 + r0 + tx] = t[tx][ty];
}

// ==========================================================================
// GEMM: C[M,N] = A[M,K] @ Bt[N,K]^T (bf16 in, fp32 acc, OUT_T out)
// 256x256 tile, BK=64, 512 thr (8 waves 2Mx4N), 8-phase-per-2-K-tiles
// schedule: counted vmcnt(6), raw s_barrier, XOR-swizzled LDS, setprio.
// ==========================================================================
template <typename OUT_T>
__global__ __launch_bounds__(512, 2) void gemm256(const u16* __restrict__ A,
                                                  const u16* __restrict__ Bt,
                                                  OUT_T* __restrict__ C,
                                                  int M, int N, int K) {
    (void)M;
    __shared__ __align__(16) u16 lds[2][2][2][128 * 64];  // [buf][A/B][half][r*64+c]
    const int tid = threadIdx.x;
    const int wave = tid >> 6, lane = tid & 63;
    const int lr = lane & 15, lq = lane >> 4;
    const int wm = wave >> 2, wn = wave & 3;
    const int m0 = blockIdx.y * 256, n0 = blockIdx.x * 256;

    const int srow = lane >> 3;                    // 0..7 within 8-row group
    const int schunk = ((lane & 7) ^ srow) << 3;   // source chunk (elems)
    const int slot = wave << 1;

    auto stage = [&](const u16* src, int rbase, int buf, int mat, int half, int k0) {
#pragma unroll
        for (int j = 0; j < 2; j++) {
            int r = rbase + half * 128 + (slot + j) * 8 + srow;
            __builtin_amdgcn_global_load_lds(
                (const AS1 void*)(src + (size_t)r * K + k0 + schunk),
                (AS3 void*)(&lds[buf][mat][half][(slot + j) * 512]), 16, 0, 0);
        }
    };

    floatx4 zf = {0.f, 0.f, 0.f, 0.f};
    floatx4 acc[8][4];
#pragma unroll
    for (int i = 0; i < 8; i++)
#pragma unroll
        for (int jn = 0; jn < 4; jn++) acc[i][jn] = zf;

    const int NT = K >> 6;

    stage(Bt, n0, 0, 1, 0, 0);
    stage(Bt, n0, 0, 1, 1, 0);
    stage(A, m0, 0, 0, 0, 0);
    stage(A, m0, 0, 0, 1, 0);
    if (NT > 1) {
        stage(Bt, n0, 1, 1, 0, 64);
        stage(Bt, n0, 1, 1, 1, 64);
        stage(A, m0, 1, 0, 0, 64);
        asm volatile("s_waitcnt vmcnt(6)" ::: "memory");
    } else {
        asm volatile("s_waitcnt vmcnt(0)" ::: "memory");
    }
    __builtin_amdgcn_s_barrier();

    for (int kt = 0; kt < NT; kt++) {
        const int b = kt & 1;
        const u16* Ab = &lds[b][0][wm][0];
        const u16* Bb = &lds[b][1][wn >> 1][0];
        const int brow = (wn & 1) * 64;
        const int sx = lr & 7;
        const int nk = (kt + 2) << 6;

        // ---- phase 0 ----
        short8 bf0[4], bf1[4], af[4];
#pragma unroll
        for (int jn = 0; jn < 4; jn++) {
            int rh = brow + jn * 16 + lr;
            bf0[jn] = *(const short8*)(Bb + rh * 64 + ((lq ^ sx) << 3));
            bf1[jn] = *(const short8*)(Bb + rh * 64 + (((4 + lq) ^ sx) << 3));
        }
#pragma unroll
        for (int i = 0; i < 4; i++)
            af[i] = *(const short8*)(Ab + (i * 16 + lr) * 64 + ((lq ^ sx) << 3));
        if (kt + 1 < NT) stage(A, m0, b ^ 1, 0, 1, (kt + 1) << 6);
        __builtin_amdgcn_s_barrier();
        asm volatile("s_waitcnt lgkmcnt(0)" ::: "memory");
        __builtin_amdgcn_sched_barrier(0);
        __builtin_amdgcn_s_setprio(1);
#pragma unroll
        for (int i = 0; i < 4; i++)
#pragma unroll
            for (int jn = 0; jn < 4; jn++)
                acc[i][jn] = __builtin_amdgcn_mfma_f32_16x16x32_bf16(af[i], bf0[jn], acc[i][jn], 0, 0, 0);
        __builtin_amdgcn_s_setprio(0);
        __builtin_amdgcn_s_barrier();

        // ---- phase 1 ----
        short8 ag[4];
#pragma unroll
        for (int i = 0; i < 4; i++)
            ag[i] = *(const short8*)(Ab + ((i + 4) * 16 + lr) * 64 + ((lq ^ sx) << 3));
        if (kt + 2 < NT) stage(Bt, n0, b, 1, 0, nk);
        __builtin_amdgcn_s_barrier();
        asm volatile("s_waitcnt lgkmcnt(0)" ::: "memory");
        __builtin_amdgcn_sched_barrier(0);
        __builtin_amdgcn_s_setprio(1);
#pragma unroll
        for (int i = 0; i < 4; i++)
#pragma unroll
            for (int jn = 0; jn < 4; jn++)
                acc[i + 4][jn] = __builtin_amdgcn_mfma_f32_16x16x32_bf16(ag[i], bf0[jn], acc[i + 4][jn], 0, 0, 0);
        __builtin_amdgcn_s_setprio(0);
        __builtin_amdgcn_s_barrier();

        // ---- phase 2 ----
        short8 c0[4], c1[4];
#pragma unroll
        for (int i = 0; i < 4; i++) {
            c0[i] = *(const short8*)(Ab + (i * 16 + lr) * 64 + (((4 + lq) ^ sx) << 3));
            c1[i] = *(const short8*)(Ab + ((i + 4) * 16 + lr) * 64 + (((4 + lq) ^ sx) << 3));
        }
        if (kt + 2 < NT) stage(Bt, n0, b, 1, 1, nk);
        __builtin_amdgcn_s_barrier();
        asm volatile("s_waitcnt lgkmcnt(0)" ::: "memory");
        __builtin_amdgcn_sched_barrier(0);
        __builtin_amdgcn_s_setprio(1);
#pragma unroll
        for (int i = 0; i < 4; i++)
#pragma unroll
            for (int jn = 0; jn < 4; jn++)
                acc[i][jn] = __builtin_amdgcn_mfma_f32_16x16x32_bf16(c0[i], bf1[jn], acc[i][jn], 0, 0, 0);
        __builtin_amdgcn_s_setprio(0);
        __builtin_amdgcn_s_barrier();

        // ---- phase 3 ----
        if (kt + 2 < NT) stage(A, m0, b, 0, 0, nk);
        __builtin_amdgcn_s_barrier();
        __builtin_amdgcn_s_setprio(1);
#pragma unroll
        for (int i = 0; i < 4; i++)
#pragma unroll
            for (int jn = 0; jn < 4; jn++)
                acc[i + 4][jn] = __builtin_amdgcn_mfma_f32_16x16x32_bf16(c1[i], bf1[jn], acc[i + 4][jn], 0, 0, 0);
        __builtin_amdgcn_s_setprio(0);
        if (kt + 2 < NT) asm volatile("s_waitcnt vmcnt(6)" ::: "memory");
        else asm volatile("s_waitcnt vmcnt(0)" ::: "memory");
        __builtin_amdgcn_s_barrier();
    }

#pragma unroll
    for (int i = 0; i < 8; i++)
#pragma unroll
        for (int jn = 0; jn < 4; jn++)
#pragma unroll
            for (int r = 0; r < 4; r++) {
                int row = m0 + wm * 128 + i * 16 + lq * 4 + r;
                int col = n0 + wn * 64 + jn * 16 + lr;
                if constexpr (sizeof(OUT_T) == 2)
                    C[(size_t)row * N + col] = f2bf(acc[i][jn][r]);
                else
                    C[(size_t)row * N + col] = acc[i][jn][r];
            }
}

// ==========================================================================
// GEMM: BM=256 x BN=128, BK=64, 512 thr = 8 waves (4M x 2N), 64x64/wave.
// Same 8-phase counted-vmcnt schedule; 3 stage-units/tile -> vmcnt(4).
// Grid (N/128, M/256) -> 256 blocks for the Wo GEMM (full GPU).
// ==========================================================================
template <typename OUT_T>
__global__ __launch_bounds__(512, 2) void gemm128n(const u16* __restrict__ A,
                                                   const u16* __restrict__ Bt,
                                                   OUT_T* __restrict__ C,
                                                   int M, int N, int K) {
    (void)M;
    __shared__ __align__(16) u16 Abuf[2][2][128 * 64];  // [buf][half][r*64+c]
    __shared__ __align__(16) u16 Bbuf[2][128 * 64];     // [buf][r*64+c]
    const int tid = threadIdx.x;
    const int wave = tid >> 6, lane = tid & 63;
    const int lr = lane & 15, lq = lane >> 4;
    const int wm = wave >> 1, wn = wave & 1;
    const int m0 = blockIdx.y * 256, n0 = blockIdx.x * 128;

    const int srow = lane >> 3;
    const int schunk = ((lane & 7) ^ srow) << 3;
    const int slot = wave << 1;

    auto stage = [&](const u16* src, int rowbase, u16* ldsbase, int k0) {
#pragma unroll
        for (int j = 0; j < 2; j++) {
            int r = rowbase + (slot + j) * 8 + srow;
            __builtin_amdgcn_global_load_lds(
                (const AS1 void*)(src + (size_t)r * K + k0 + schunk),
                (AS3 void*)(ldsbase + (slot + j) * 512), 16, 0, 0);
        }
    };

    floatx4 zf = {0.f, 0.f, 0.f, 0.f};
    floatx4 acc[4][4];
#pragma unroll
    for (int i = 0; i < 4; i++)
#pragma unroll
        for (int jn = 0; jn < 4; jn++) acc[i][jn] = zf;

    const int NT = K >> 6;

    // prologue: t0 = {Ah0, Ah1, B}; t1 = {Ah0, B} (Ah1(t1) comes in t0.ph0)
    stage(A, m0, &Abuf[0][0][0], 0);
    stage(A, m0 + 128, &Abuf[0][1][0], 0);
    stage(Bt, n0, &Bbuf[0][0], 0);
    if (NT > 1) {
        stage(A, m0, &Abuf[1][0][0], 64);
        stage(Bt, n0, &Bbuf[1][0], 64);
        asm volatile("s_waitcnt vmcnt(4)" ::: "memory");
    } else {
        asm volatile("s_waitcnt vmcnt(0)" ::: "memory");
    }
    __builtin_amdgcn_s_barrier();

    for (int kt = 0; kt < NT; kt++) {
        const int b = kt & 1;
        const u16* Ab = &Abuf[b][wm >> 1][0];
        const u16* Bb = &Bbuf[b][0];
        const int ar = (wm & 1) * 64;
        const int br = wn * 64;
        const int sx = lr & 7;
        const int nk = (kt + 2) << 6;

        // ---- phase 0: read bf0,bf1,af(kk0); stage Ah1(kt+1); mfma kk0 i0-1 ----
        short8 bf0[4], bf1[4], af[4];
#pragma unroll
        for (int jn = 0; jn < 4; jn++) {
            int rh = br + jn * 16 + lr;
            bf0[jn] = *(const short8*)(Bb + rh * 64 + ((lq ^ sx) << 3));
            bf1[jn] = *(const short8*)(Bb + rh * 64 + (((4 + lq) ^ sx) << 3));
        }
#pragma unroll
        for (int i = 0; i < 4; i++)
            af[i] = *(const short8*)(Ab + (ar + i * 16 + lr) * 64 + ((lq ^ sx) << 3));
        if (kt + 1 < NT) stage(A, m0 + 128, &Abuf[b ^ 1][1][0], (kt + 1) << 6);
        __builtin_amdgcn_s_barrier();
        asm volatile("s_waitcnt lgkmcnt(0)" ::: "memory");
        __builtin_amdgcn_sched_barrier(0);
        __builtin_amdgcn_s_setprio(1);
#pragma unroll
        for (int i = 0; i < 2; i++)
#pragma unroll
            for (int jn = 0; jn < 4; jn++)
                acc[i][jn] = __builtin_amdgcn_mfma_f32_16x16x32_bf16(af[i], bf0[jn], acc[i][jn], 0, 0, 0);
        __builtin_amdgcn_s_setprio(0);
        __builtin_amdgcn_s_barrier();

        // ---- phase 1: stage B(kt+2); mfma kk0 i2-3 ----
        if (kt + 2 < NT) stage(Bt, n0, &Bbuf[b][0], nk);
        __builtin_amdgcn_s_barrier();
        __builtin_amdgcn_s_setprio(1);
#pragma unroll
        for (int i = 2; i < 4; i++)
#pragma unroll
            for (int jn = 0; jn < 4; jn++)
                acc[i][jn] = __builtin_amdgcn_mfma_f32_16x16x32_bf16(af[i], bf0[jn], acc[i][jn], 0, 0, 0);
        __builtin_amdgcn_s_setprio(0);
        __builtin_amdgcn_s_barrier();

        // ---- phase 2: read ag(kk1); mfma kk1 i0-1 ----
        short8 ag[4];
#pragma unroll
        for (int i = 0; i < 4; i++)
            ag[i] = *(const short8*)(Ab + (ar + i * 16 + lr) * 64 + (((4 + lq) ^ sx) << 3));
        __builtin_amdgcn_s_barrier();
        asm volatile("s_waitcnt lgkmcnt(0)" ::: "memory");
        __builtin_amdgcn_sched_barrier(0);
        __builtin_amdgcn_s_setprio(1);
#pragma unroll
        for (int i = 0; i < 2; i++)
#pragma unroll
            for (int jn = 0; jn < 4; jn++)
                acc[i][jn] = __builtin_amdgcn_mfma_f32_16x16x32_bf16(ag[i], bf1[jn], acc[i][jn], 0, 0, 0);
        __builtin_amdgcn_s_setprio(0);
        __builtin_amdgcn_s_barrier();

        // ---- phase 3: stage Ah0(kt+2); mfma kk1 i2-3; counted vmcnt ----
        if (kt + 2 < NT) stage(A, m0, &Abuf[b][0][0], nk);
        __builtin_amdgcn_s_barrier();
        __builtin_amdgcn_s_setprio(1);
#pragma unroll
        for (int i = 2; i < 4; i++)
#pragma unroll
            for (int jn = 0; jn < 4; jn++)
                acc[i][jn] = __builtin_amdgcn_mfma_f32_16x16x32_bf16(ag[i], bf1[jn], acc[i][jn], 0, 0, 0);
        __builtin_amdgcn_s_setprio(0);
        if (kt + 2 < NT) asm volatile("s_waitcnt vmcnt(4)" ::: "memory");
        else asm volatile("s_waitcnt vmcnt(0)" ::: "memory");
        __builtin_amdgcn_s_barrier();
    }

#pragma unroll
    for (int i = 0; i < 4; i++)
#pragma unroll
        for (int jn = 0; jn < 4; jn++)
#pragma unroll
            for (int r = 0; r < 4; r++) {
                int row = m0 + wm * 64 + i * 16 + lq * 4 + r;
                int col = n0 + wn * 64 + jn * 16 + lr;
                if constexpr (sizeof(OUT_T) == 2)
                    C[(size_t)row * N + col] = f2bf(acc[i][jn][r]);
                else
                    C[(size_t)row * N + col] = acc[i][jn][r];
            }
}

// ==========================================================================
// Merged post-QKV prep: blocks <24576 do RMS-norm+RoPE on Q/K (in place);
// blocks >=24576 transpose V into Vt (b,kv,d,s). 256 threads each.
// ==========================================================================
__global__ __launch_bounds__(256) void prep_qkv(u16* __restrict__ QKV,
                                                u16* __restrict__ Vt,
                                                const float* __restrict__ cosb,
                                                const float* __restrict__ sinb,
                                                const float* __restrict__ qw,
                                                const float* __restrict__ kw) {
    const int bx = blockIdx.x;
    const int tid = threadIdx.x;
    if (bx >= 24576) {  // V transpose: 4096 blocks
        const int idx = bx - 24576;
        const int s0 = (idx & 63) * 32;
        const int d0 = ((idx >> 6) & 3) * 32;
        const int zz = idx >> 8;
        const int b = zz >> 3, kv = zz & 7;
        __shared__ u16 t[32][33];
        const int tx = tid & 31, ty0 = tid >> 5;  // 32 x 8
#pragma unroll
        for (int p = 0; p < 4; p++) {
            int r = ty0 + p * 8;
            t[r][tx] = QKV[(size_t)(b * 2048 + s0 + r) * 4096 + 3072 + kv * 128 + d0 + tx];
        }
        __syncthreads();
#pragma unroll
        for (int p = 0; p < 4; p++) {
            int r = ty0 + p * 8;
            Vt[(size_t)((b * 8 + kv) * 128 + d0 + r) * 2048 + s0 + tx] = t[tx][r];
        }
        return;
    }
    const int wave = tid >> 6, lane = tid & 63;
    const int t = bx * 4 + wave;  // 0..98303
    u16* ptr;
    const float* w;
    float scale;
    int bs;
    if (t < 65536) {
        bs = t >> 4;
        ptr = QKV + (size_t)bs * 4096 + (t & 15) * 128;
        w = qw;
        scale = 0.08838834764831845f * 1.4426950408889634f;  // D^-0.5 * log2(e)
    } else {
        int t2 = t - 65536;
        bs = t2 >> 3;
        ptr = QKV + (size_t)bs * 4096 + 2048 + (t2 & 7) * 128;
        w = kw;
        scale = 1.0f;
    }
    const int d = lane * 2;
    u32 xv = *(const u32*)(ptr + d);
    float x0 = bf2f((u16)(xv & 0xffff)), x1 = bf2f((u16)(xv >> 16));
    float ss = x0 * x0 + x1 * x1;
#pragma unroll
    for (int off = 1; off < 64; off <<= 1) ss += __shfl_xor(ss, off);
    float rn = rsqrtf(ss * (1.0f / 128.0f) + 1e-6f);
    float2 wv = *(const float2*)(w + d);
    float y0 = x0 * rn * wv.x;
    float y1 = x1 * rn * wv.y;
    float p0 = __shfl_xor(y0, 32);
    float p1 = __shfl_xor(y1, 32);
    float sgn = (lane < 32) ? -1.0f : 1.0f;
    float2 cv = *(const float2*)(cosb + (size_t)bs * 128 + d);
    float2 sv = *(const float2*)(sinb + (size_t)bs * 128 + d);
    float o0 = (y0 * cv.x + sgn * p0 * sv.x) * scale;
    float o1 = (y1 * cv.y + sgn * p1 * sv.y) * scale;
    *(u32*)(ptr + d) = (u32)f2bf(o0) | ((u32)f2bf(o1) << 16);
}

// ==========================================================================
// Causal GQA flash attention, transposed-score formulation.
// QBLK=64 (4 waves, 256 thr), KVBLK=64.
// LDS 50KB: K double-buffered (32KB) + V single-buffered (16KB) + ones rows
// (2KB) so PV's jn=8 column accumulates l = sum(P) inside the MFMA.
// Counted-vmcnt barriers (T4). 3 blocks/CU = 12 waves/CU.
// XCD-STREAM decode (r7 post-mortem): under round-robin placement
// (XCD ~ id&7, CU ~ id&255), XCD x serves only TWO (kv,b) streams
// (s = 2x+(g&1)) -> 2MB K/V working set < 4MB L2 (r7's decode hit 16
// streams = 16MB -> thrash, FETCH 27->69MB). qt = u or 31-u alternating
// with g -> per-CU chains {u+1, 32-u}x2 = 66 tiles, balanced. Bijective
// over (qt,h,b); placement assumptions are perf-only, never correctness.
// T5 setprio, T13 defer-max.
// ==========================================================================
__global__ __launch_bounds__(256, 3) void attn_kernel(const u16* __restrict__ QKV,
                                                      const u16* __restrict__ Vt,
                                                      u16* __restrict__ O) {
    __shared__ __align__(16) u16 Ks[2][64 * 128];   // [key][d] swizzled, 32KB
    __shared__ __align__(16) u16 Vs[144 * 64];      // [d][key] swizzled + ones rows 128..143
    const int tid = threadIdx.x;
    const int wave = tid >> 6, lane = tid & 63;
    const int lr = lane & 15, lq = lane >> 4;

    // XCD-stream decode
    const int id = blockIdx.x;        // 0..1023
    const int x = id & 7;             // XCD (round-robin heuristic)
    const int u = (id >> 3) & 31;     // CU within XCD
    const int g = id >> 8;            // 0..3 generation
    const int s = x * 2 + (g & 1);    // stream 0..15
    const int kv = s & 7;
    const int b = s >> 3;
    const int h = kv * 2 + (g >> 1);
    const int qt = (g & 1) ? (31 - u) : u;

    const int q0 = qt * 64;
    const int wq = wave * 16;

    // async stage of one 64-key K tile into buffer `buf` (4 instrs/wave)
    auto stageK = [&](int buf, int k0s) {
#pragma unroll
        for (int jj = 0; jj < 4; jj++) {   // Ks: 64 rows x 256 B
            int r = wave * 16 + jj * 4 + (lane >> 4);
            int ch = (lane & 15) ^ (r & 15);   // inverse-swizzled source chunk
            __builtin_amdgcn_global_load_lds(
                (const AS1 void*)(QKV + (size_t)(b * 2048 + k0s + r) * 4096 + 2048 + kv * 128 + ch * 8),
                (AS3 void*)(&Ks[buf][(wave * 16 + jj * 4) * 128]), 16, 0, 0);
        }
    };
    // async stage of the V tile (rows 0..127 only; ones rows untouched)
    auto stageV = [&](int k0s) {
#pragma unroll
        for (int jj = 0; jj < 4; jj++) {   // Vs: 128 rows x 128 B
            int r = wave * 32 + jj * 8 + (lane >> 3);
            int ch = (lane & 7) ^ (r & 7);
            __builtin_amdgcn_global_load_lds(
                (const AS1 void*)(Vt + (size_t)((b * 8 + kv) * 128 + r) * 2048 + k0s + ch * 8),
                (AS3 void*)(&Vs[(wave * 32 + jj * 8) * 64]), 16, 0, 0);
        }
    };

    // fill ones rows (128..143) once; any swizzled read sees 1.0
    *(u64*)(&Vs[128 * 64 + tid * 4]) = 0x3F803F803F803F80ULL;
    asm volatile("s_waitcnt lgkmcnt(0)" ::: "memory");

    // Q fragments in registers (B-operand: n=qrow on lr, k=d on lq*8+j)
    short8 qf[4];
#pragma unroll
    for (int t = 0; t < 4; t++)
        qf[t] = *(const short8*)(QKV + (size_t)(b * 2048 + q0 + wq + lr) * 4096 + h * 128 + t * 32 + lq * 8);

    floatx4 zf = {0.f, 0.f, 0.f, 0.f};
    floatx4 oacc[9];   // [8] = l column (ones rows of Vs)
#pragma unroll
    for (int jn = 0; jn < 9; jn++) oacc[jn] = zf;
    float mstate = -1e30f;

    const int nIter = qt + 1;

    stageK(0, 0);

    for (int kt = 0; kt < nIter; kt++) {
        const int k0 = kt * 64;
        const int cur = kt & 1;
        // barrier #1: own outstanding = K(kt) only -> vmcnt(0) is exact.
        // Vs free (PV(kt-1) done), Ks[cur^1] free (QK^T(kt-1) done).
        asm volatile("s_waitcnt vmcnt(0)" ::: "memory");
        __builtin_amdgcn_s_barrier();
        stageV(k0);
        if (kt + 1 < nIter) stageK(cur ^ 1, k0 + 64);

        const bool active = (k0 <= q0 + wq + 15);
        u64 pb[4];
        if (active) {
            const u16* KsC = &Ks[cur][0];
            floatx4 sacc[4];
#pragma unroll
            for (int jm = 0; jm < 4; jm++) sacc[jm] = zf;
            __builtin_amdgcn_s_setprio(1);
#pragma unroll
            for (int t = 0; t < 4; t++) {
                short8 a[4];
#pragma unroll
                for (int jm = 0; jm < 4; jm++)
                    a[jm] = *(const short8*)(KsC + (jm * 16 + lr) * 128 + (((t * 4 + lq) ^ lr) << 3));
#pragma unroll
                for (int jm = 0; jm < 4; jm++)
                    sacc[jm] = __builtin_amdgcn_mfma_f32_16x16x32_bf16(a[jm], qf[t], sacc[jm], 0, 0, 0);
            }
            __builtin_amdgcn_s_setprio(0);

            if (k0 + 63 > q0 + wq) {
#pragma unroll
                for (int jm = 0; jm < 4; jm++) {
                    int diff = (q0 + wq + lr) - (k0 + jm * 16 + lq * 4);
#pragma unroll
                    for (int r = 0; r < 4; r++)
                        if (r > diff) sacc[jm][r] = -1e30f;
                }
            }

            // per-qrow max (tree within jm, then cross-quad)
            float mx = -1e30f;
#pragma unroll
            for (int jm = 0; jm < 4; jm++) {
                float a0 = fmaxf(sacc[jm][0], sacc[jm][1]);
                float a1 = fmaxf(sacc[jm][2], sacc[jm][3]);
                mx = fmaxf(mx, fmaxf(a0, a1));
            }
            mx = fmaxf(mx, __shfl_xor(mx, 16));
            mx = fmaxf(mx, __shfl_xor(mx, 32));

            // T13 defer-max: skip rescale when all rows grew <= 8 (log2 dom)
            bool defer = __all(mx - mstate <= 8.0f);
            float mnew = defer ? mstate : fmaxf(mstate, mx);

#pragma unroll
            for (int jm = 0; jm < 4; jm++)
#pragma unroll
                for (int r = 0; r < 4; r++)
                    sacc[jm][r] = exp2f(sacc[jm][r] - mnew);

            if (!defer) {
                float alpha = exp2f(mstate - mnew);
                mstate = mnew;
                float ao[4];
#pragma unroll
                for (int r = 0; r < 4; r++) ao[r] = __shfl(alpha, lq * 4 + r);
#pragma unroll
                for (int jn = 0; jn < 9; jn++)   // includes l column
#pragma unroll
                    for (int r = 0; r < 4; r++) oacc[jn][r] *= ao[r];
            }

#pragma unroll
            for (int jm = 0; jm < 4; jm++) {
                u32 lo = f2bf_pk(sacc[jm][0], sacc[jm][1]);
                u32 hi = f2bf_pk(sacc[jm][2], sacc[jm][3]);
                pb[jm] = (u64)lo | ((u64)hi << 32);
            }
        }

        // barrier #2: wait ONLY the V loads (first 4 in own queue);
        // K(kt+1) (4 newer loads) stays in flight across PV + next barrier.
        if (kt + 1 < nIter) asm volatile("s_waitcnt vmcnt(4)" ::: "memory");
        else                asm volatile("s_waitcnt vmcnt(0)" ::: "memory");
        __builtin_amdgcn_s_barrier();

        if (active) {
            // O += P @ [V | 1]; jn=8 accumulates l per qrow inside MFMA.
            __builtin_amdgcn_s_setprio(1);
#pragma unroll
            for (int t = 0; t < 2; t++) {
                union { short8 v; u64 q[2]; } pa;
                pa.q[0] = pb[2 * t];
                pa.q[1] = pb[2 * t + 1];
#pragma unroll
                for (int jn = 0; jn < 9; jn++) {
                    const u16* vrow = Vs + (jn * 16 + lr) * 64 + (lq & 1) * 4;
                    union { short8 v; u64 q[2]; } vb;
                    vb.q[0] = *(const u64*)(vrow + (((t * 4 + (lq >> 1)) ^ (lr & 7)) << 3));
                    vb.q[1] = *(const u64*)(vrow + (((t * 4 + 2 + (lq >> 1)) ^ (lr & 7)) << 3));
                    oacc[jn] = __builtin_amdgcn_mfma_f32_16x16x32_bf16(pa.v, vb.v, oacc[jn], 0, 0, 0);
                }
            }
            __builtin_amdgcn_s_setprio(0);
        }
    }

    // epilogue: l already at the right lanes (oacc[8][r], qrow = lq*4+r)
#pragma unroll
    for (int jn = 0; jn < 8; jn++)
#pragma unroll
        for (int r = 0; r < 4; r++) {
            int row = q0 + wq + lq * 4 + r;
            O[(size_t)(b * 2048 + row) * 2048 + h * 128 + jn * 16 + lr] =
                f2bf(oacc[jn][r] / oacc[8][r]);
        }
}

// ==========================================================================
extern "C" void kernel_launch(void* const* d_in, const int* in_sizes, int n_in,
                              void* d_out, int out_size, void* d_ws, size_t ws_size,
                              hipStream_t stream) {
    const float* X = (const float*)d_in[0];
    const float* cosb = (const float*)d_in[1];
    const float* sinb = (const float*)d_in[2];
    const float* Wq = (const float*)d_in[3];
    const float* Wk = (const float*)d_in[4];
    const float* Wv = (const float*)d_in[5];
    const float* Wo = (const float*)d_in[6];
    const float* qw = (const float*)d_in[7];
    const float* kw = (const float*)d_in[8];
    float* out = (float*)d_out;
    u16* ws = (u16*)d_ws;

    u16* WqkvT = ws;                    // 4096x2048 = 8388608
    u16* WoT = WqkvT + 8388608;         // 4194304
    u16* Xb = WoT + 4194304;            // 8388608 (dead after QKV GEMM)
    u16* QKVb = Xb + 8388608;           // 4096x4096 = 16777216
    u16* Vtb = QKVb + 16777216;         // 4194304
    u16* Ob = Xb;                       // alias
    // total 41,943,040 u16 = 83.9 MB

    prep_weights<<<dim3(64, 64, 5), dim3(32, 32), 0, stream>>>(Wq, Wk, Wv, Wo, X,
                                                               WqkvT, WoT, Xb);

    gemm256<u16><<<dim3(16, 16), 512, 0, stream>>>(Xb, WqkvT, QKVb, 4096, 4096, 2048);

    prep_qkv<<<28672, 256, 0, stream>>>(QKVb, Vtb, cosb, sinb, qw, kw);

    attn_kernel<<<1024, 256, 0, stream>>>(QKVb, Vtb, Ob);

    gemm128n<float><<<dim3(16, 16), 512, 0, stream>>>(Ob, WoT, out, 4096, 2048, 2048);
}

// Round 10
// 342.623 us; speedup vs baseline: 1.1478x; 1.1329x over previous
//
#include <hip/hip_runtime.h>
#include <hip/hip_bf16.h>

typedef unsigned short u16;
typedef unsigned int u32;
typedef unsigned long long u64;
typedef __attribute__((ext_vector_type(8))) short short8;
typedef __attribute__((ext_vector_type(4))) float floatx4;

#define AS1 __attribute__((address_space(1)))
#define AS3 __attribute__((address_space(3)))

// ---- bf16 <-> f32 helpers (raw bits, RNE) ----
__device__ __forceinline__ float bf2f(u16 u) {
    u32 x = ((u32)u) << 16;
    float f;
    __builtin_memcpy(&f, &x, 4);
    return f;
}
__device__ __forceinline__ u16 f2bf(float f) {
    u32 x;
    __builtin_memcpy(&x, &f, 4);
    u32 r = (x + 0x7fffu + ((x >> 16) & 1u)) >> 16;
    return (u16)r;
}
// packed 2xf32 -> 2xbf16 (v_cvt_pk_bf16_f32), returned as u32 (lo=first)
__device__ __forceinline__ u32 f2bf_pk(float a, float b) {
    __hip_bfloat162 h = __float22bfloat162_rn(float2{a, b});
    u32 r;
    __builtin_memcpy(&r, &h, 4);
    return r;
}

// ==========================================================================
// Merged prep: z<4 = weight transposes (f32 RxC -> bf16 CxR), z=4 = X cast.
// 64x64 tiles, 2x2 micro-tile/thread: float2 reads (8B/lane), u32 packed
// writes (128B/wave segments). Block = dim3(32,8) — 2D indexing required.
// ==========================================================================
__global__ __launch_bounds__(256) void prep_weights(const float* __restrict__ Wq,
                                                    const float* __restrict__ Wk,
                                                    const float* __restrict__ Wv,
                                                    const float* __restrict__ Wo,
                                                    const float* __restrict__ X,
                                                    u16* __restrict__ WqkvT,
                                                    u16* __restrict__ WoT,
                                                    u16* __restrict__ Xb) {
    const int z = blockIdx.z;
    const int tx = threadIdx.x, ty = threadIdx.y;   // 32 x 8
    if (z == 4) {  // X cast: 1024 blocks x 256 thr x 8 float4 = 8.39M f32
        int tid = ty * 32 + tx;
        int idx = blockIdx.y * 32 + blockIdx.x;     // 0..1023
        if (idx >= 1024) return;
        size_t base = (size_t)idx * 256 + tid;
#pragma unroll
        for (int p = 0; p < 8; p++) {
            size_t i = (base + (size_t)p * 262144) * 4;
            float4 v = *(const float4*)(X + i);
            u16 o[4] = {f2bf(v.x), f2bf(v.y), f2bf(v.z), f2bf(v.w)};
            *(u64*)(Xb + i) = *(u64*)o;
        }
        return;
    }
    const float* in;
    u16* out;
    int C;
    if (z == 0) { in = Wq; out = WqkvT; C = 2048; }
    else if (z == 1) { in = Wk; out = WqkvT + 2048 * 2048; C = 1024; }
    else if (z == 2) { in = Wv; out = WqkvT + 3072 * 2048; C = 1024; }
    else { in = Wo; out = WoT; C = 2048; }
    const int c0 = blockIdx.x * 64, r0 = blockIdx.y * 64;
    if (c0 >= C) return;
    __shared__ u16 t[64][66];
#pragma unroll
    for (int p = 0; p < 4; p++) {
        int rr = (ty + 8 * p) * 2;
#pragma unroll
        for (int i = 0; i < 2; i++) {
            float2 v = *(const float2*)(in + (size_t)(r0 + rr + i) * C + c0 + tx * 2);
            *(u32*)&t[rr + i][tx * 2] = f2bf_pk(v.x, v.y);
        }
    }
    __syncthreads();
#pragma unroll
    for (int p = 0; p < 4; p++) {
        int cc = (ty + 8 * p) * 2;
        u32 a = *(const u32*)&t[tx * 2][cc];       // r=2tx : (col cc | col cc+1)
        u32 bq = *(const u32*)&t[tx * 2 + 1][cc];  // r=2tx+1
        u32 pk0 = (a & 0xffffu) | (bq << 16);            // col cc, rows 2tx,2tx+1
        u32 pk1 = (a >> 16) | (bq & 0xffff0000u);        // col cc+1
        *(u32*)(out + (size_t)(c0 + cc) * 2048 + r0 + tx * 2) = pk0;
        *(u32*)(out + (size_t)(c0 + cc + 1) * 2048 + r0 + tx * 2) = pk1;
    }
}

// ==========================================================================
// GEMM: C[M,N] = A[M,K] @ Bt[N,K]^T (bf16 in, fp32 acc, OUT_T out)
// 256x256 tile, BK=64, 512 thr (8 waves 2Mx4N), 8-phase-per-2-K-tiles
// schedule: counted vmcnt(6), raw s_barrier, XOR-swizzled LDS, setprio.
// ==========================================================================
template <typename OUT_T>
__global__ __launch_bounds__(512, 2) void gemm256(const u16* __restrict__ A,
                                                  const u16* __restrict__ Bt,
                                                  OUT_T* __restrict__ C,
                                                  int M, int N, int K) {
    (void)M;
    __shared__ __align__(16) u16 lds[2][2][2][128 * 64];  // [buf][A/B][half][r*64+c]
    const int tid = threadIdx.x;
    const int wave = tid >> 6, lane = tid & 63;
    const int lr = lane & 15, lq = lane >> 4;
    const int wm = wave >> 2, wn = wave & 3;
    const int m0 = blockIdx.y * 256, n0 = blockIdx.x * 256;

    const int srow = lane >> 3;                    // 0..7 within 8-row group
    const int schunk = ((lane & 7) ^ srow) << 3;   // source chunk (elems)
    const int slot = wave << 1;

    auto stage = [&](const u16* src, int rbase, int buf, int mat, int half, int k0) {
#pragma unroll
        for (int j = 0; j < 2; j++) {
            int r = rbase + half * 128 + (slot + j) * 8 + srow;
            __builtin_amdgcn_global_load_lds(
                (const AS1 void*)(src + (size_t)r * K + k0 + schunk),
                (AS3 void*)(&lds[buf][mat][half][(slot + j) * 512]), 16, 0, 0);
        }
    };

    floatx4 zf = {0.f, 0.f, 0.f, 0.f};
    floatx4 acc[8][4];
#pragma unroll
    for (int i = 0; i < 8; i++)
#pragma unroll
        for (int jn = 0; jn < 4; jn++) acc[i][jn] = zf;

    const int NT = K >> 6;

    stage(Bt, n0, 0, 1, 0, 0);
    stage(Bt, n0, 0, 1, 1, 0);
    stage(A, m0, 0, 0, 0, 0);
    stage(A, m0, 0, 0, 1, 0);
    if (NT > 1) {
        stage(Bt, n0, 1, 1, 0, 64);
        stage(Bt, n0, 1, 1, 1, 64);
        stage(A, m0, 1, 0, 0, 64);
        asm volatile("s_waitcnt vmcnt(6)" ::: "memory");
    } else {
        asm volatile("s_waitcnt vmcnt(0)" ::: "memory");
    }
    __builtin_amdgcn_s_barrier();

    for (int kt = 0; kt < NT; kt++) {
        const int b = kt & 1;
        const u16* Ab = &lds[b][0][wm][0];
        const u16* Bb = &lds[b][1][wn >> 1][0];
        const int brow = (wn & 1) * 64;
        const int sx = lr & 7;
        const int nk = (kt + 2) << 6;

        // ---- phase 0 ----
        short8 bf0[4], bf1[4], af[4];
#pragma unroll
        for (int jn = 0; jn < 4; jn++) {
            int rh = brow + jn * 16 + lr;
            bf0[jn] = *(const short8*)(Bb + rh * 64 + ((lq ^ sx) << 3));
            bf1[jn] = *(const short8*)(Bb + rh * 64 + (((4 + lq) ^ sx) << 3));
        }
#pragma unroll
        for (int i = 0; i < 4; i++)
            af[i] = *(const short8*)(Ab + (i * 16 + lr) * 64 + ((lq ^ sx) << 3));
        if (kt + 1 < NT) stage(A, m0, b ^ 1, 0, 1, (kt + 1) << 6);
        __builtin_amdgcn_s_barrier();
        asm volatile("s_waitcnt lgkmcnt(0)" ::: "memory");
        __builtin_amdgcn_sched_barrier(0);
        __builtin_amdgcn_s_setprio(1);
#pragma unroll
        for (int i = 0; i < 4; i++)
#pragma unroll
            for (int jn = 0; jn < 4; jn++)
                acc[i][jn] = __builtin_amdgcn_mfma_f32_16x16x32_bf16(af[i], bf0[jn], acc[i][jn], 0, 0, 0);
        __builtin_amdgcn_s_setprio(0);
        __builtin_amdgcn_s_barrier();

        // ---- phase 1 ----
        short8 ag[4];
#pragma unroll
        for (int i = 0; i < 4; i++)
            ag[i] = *(const short8*)(Ab + ((i + 4) * 16 + lr) * 64 + ((lq ^ sx) << 3));
        if (kt + 2 < NT) stage(Bt, n0, b, 1, 0, nk);
        __builtin_amdgcn_s_barrier();
        asm volatile("s_waitcnt lgkmcnt(0)" ::: "memory");
        __builtin_amdgcn_sched_barrier(0);
        __builtin_amdgcn_s_setprio(1);
#pragma unroll
        for (int i = 0; i < 4; i++)
#pragma unroll
            for (int jn = 0; jn < 4; jn++)
                acc[i + 4][jn] = __builtin_amdgcn_mfma_f32_16x16x32_bf16(ag[i], bf0[jn], acc[i + 4][jn], 0, 0, 0);
        __builtin_amdgcn_s_setprio(0);
        __builtin_amdgcn_s_barrier();

        // ---- phase 2 ----
        short8 c0[4], c1[4];
#pragma unroll
        for (int i = 0; i < 4; i++) {
            c0[i] = *(const short8*)(Ab + (i * 16 + lr) * 64 + (((4 + lq) ^ sx) << 3));
            c1[i] = *(const short8*)(Ab + ((i + 4) * 16 + lr) * 64 + (((4 + lq) ^ sx) << 3));
        }
        if (kt + 2 < NT) stage(Bt, n0, b, 1, 1, nk);
        __builtin_amdgcn_s_barrier();
        asm volatile("s_waitcnt lgkmcnt(0)" ::: "memory");
        __builtin_amdgcn_sched_barrier(0);
        __builtin_amdgcn_s_setprio(1);
#pragma unroll
        for (int i = 0; i < 4; i++)
#pragma unroll
            for (int jn = 0; jn < 4; jn++)
                acc[i][jn] = __builtin_amdgcn_mfma_f32_16x16x32_bf16(c0[i], bf1[jn], acc[i][jn], 0, 0, 0);
        __builtin_amdgcn_s_setprio(0);
        __builtin_amdgcn_s_barrier();

        // ---- phase 3 ----
        if (kt + 2 < NT) stage(A, m0, b, 0, 0, nk);
        __builtin_amdgcn_s_barrier();
        __builtin_amdgcn_s_setprio(1);
#pragma unroll
        for (int i = 0; i < 4; i++)
#pragma unroll
            for (int jn = 0; jn < 4; jn++)
                acc[i + 4][jn] = __builtin_amdgcn_mfma_f32_16x16x32_bf16(c1[i], bf1[jn], acc[i + 4][jn], 0, 0, 0);
        __builtin_amdgcn_s_setprio(0);
        if (kt + 2 < NT) asm volatile("s_waitcnt vmcnt(6)" ::: "memory");
        else asm volatile("s_waitcnt vmcnt(0)" ::: "memory");
        __builtin_amdgcn_s_barrier();
    }

#pragma unroll
    for (int i = 0; i < 8; i++)
#pragma unroll
        for (int jn = 0; jn < 4; jn++)
#pragma unroll
            for (int r = 0; r < 4; r++) {
                int row = m0 + wm * 128 + i * 16 + lq * 4 + r;
                int col = n0 + wn * 64 + jn * 16 + lr;
                if constexpr (sizeof(OUT_T) == 2)
                    C[(size_t)row * N + col] = f2bf(acc[i][jn][r]);
                else
                    C[(size_t)row * N + col] = acc[i][jn][r];
            }
}

// ==========================================================================
// GEMM: BM=256 x BN=128, BK=64, 512 thr = 8 waves (4M x 2N), 64x64/wave.
// Same 8-phase counted-vmcnt schedule; 3 stage-units/tile -> vmcnt(4).
// Grid (N/128, M/256) -> 256 blocks for the Wo GEMM (full GPU).
// ==========================================================================
template <typename OUT_T>
__global__ __launch_bounds__(512, 2) void gemm128n(const u16* __restrict__ A,
                                                   const u16* __restrict__ Bt,
                                                   OUT_T* __restrict__ C,
                                                   int M, int N, int K) {
    (void)M;
    __shared__ __align__(16) u16 Abuf[2][2][128 * 64];  // [buf][half][r*64+c]
    __shared__ __align__(16) u16 Bbuf[2][128 * 64];     // [buf][r*64+c]
    const int tid = threadIdx.x;
    const int wave = tid >> 6, lane = tid & 63;
    const int lr = lane & 15, lq = lane >> 4;
    const int wm = wave >> 1, wn = wave & 1;
    const int m0 = blockIdx.y * 256, n0 = blockIdx.x * 128;

    const int srow = lane >> 3;
    const int schunk = ((lane & 7) ^ srow) << 3;
    const int slot = wave << 1;

    auto stage = [&](const u16* src, int rowbase, u16* ldsbase, int k0) {
#pragma unroll
        for (int j = 0; j < 2; j++) {
            int r = rowbase + (slot + j) * 8 + srow;
            __builtin_amdgcn_global_load_lds(
                (const AS1 void*)(src + (size_t)r * K + k0 + schunk),
                (AS3 void*)(ldsbase + (slot + j) * 512), 16, 0, 0);
        }
    };

    floatx4 zf = {0.f, 0.f, 0.f, 0.f};
    floatx4 acc[4][4];
#pragma unroll
    for (int i = 0; i < 4; i++)
#pragma unroll
        for (int jn = 0; jn < 4; jn++) acc[i][jn] = zf;

    const int NT = K >> 6;

    // prologue: t0 = {Ah0, Ah1, B}; t1 = {Ah0, B} (Ah1(t1) comes in t0.ph0)
    stage(A, m0, &Abuf[0][0][0], 0);
    stage(A, m0 + 128, &Abuf[0][1][0], 0);
    stage(Bt, n0, &Bbuf[0][0], 0);
    if (NT > 1) {
        stage(A, m0, &Abuf[1][0][0], 64);
        stage(Bt, n0, &Bbuf[1][0], 64);
        asm volatile("s_waitcnt vmcnt(4)" ::: "memory");
    } else {
        asm volatile("s_waitcnt vmcnt(0)" ::: "memory");
    }
    __builtin_amdgcn_s_barrier();

    for (int kt = 0; kt < NT; kt++) {
        const int b = kt & 1;
        const u16* Ab = &Abuf[b][wm >> 1][0];
        const u16* Bb = &Bbuf[b][0];
        const int ar = (wm & 1) * 64;
        const int br = wn * 64;
        const int sx = lr & 7;
        const int nk = (kt + 2) << 6;

        // ---- phase 0: read bf0,bf1,af(kk0); stage Ah1(kt+1); mfma kk0 i0-1 ----
        short8 bf0[4], bf1[4], af[4];
#pragma unroll
        for (int jn = 0; jn < 4; jn++) {
            int rh = br + jn * 16 + lr;
            bf0[jn] = *(const short8*)(Bb + rh * 64 + ((lq ^ sx) << 3));
            bf1[jn] = *(const short8*)(Bb + rh * 64 + (((4 + lq) ^ sx) << 3));
        }
#pragma unroll
        for (int i = 0; i < 4; i++)
            af[i] = *(const short8*)(Ab + (ar + i * 16 + lr) * 64 + ((lq ^ sx) << 3));
        if (kt + 1 < NT) stage(A, m0 + 128, &Abuf[b ^ 1][1][0], (kt + 1) << 6);
        __builtin_amdgcn_s_barrier();
        asm volatile("s_waitcnt lgkmcnt(0)" ::: "memory");
        __builtin_amdgcn_sched_barrier(0);
        __builtin_amdgcn_s_setprio(1);
#pragma unroll
        for (int i = 0; i < 2; i++)
#pragma unroll
            for (int jn = 0; jn < 4; jn++)
                acc[i][jn] = __builtin_amdgcn_mfma_f32_16x16x32_bf16(af[i], bf0[jn], acc[i][jn], 0, 0, 0);
        __builtin_amdgcn_s_setprio(0);
        __builtin_amdgcn_s_barrier();

        // ---- phase 1: stage B(kt+2); mfma kk0 i2-3 ----
        if (kt + 2 < NT) stage(Bt, n0, &Bbuf[b][0], nk);
        __builtin_amdgcn_s_barrier();
        __builtin_amdgcn_s_setprio(1);
#pragma unroll
        for (int i = 2; i < 4; i++)
#pragma unroll
            for (int jn = 0; jn < 4; jn++)
                acc[i][jn] = __builtin_amdgcn_mfma_f32_16x16x32_bf16(af[i], bf0[jn], acc[i][jn], 0, 0, 0);
        __builtin_amdgcn_s_setprio(0);
        __builtin_amdgcn_s_barrier();

        // ---- phase 2: read ag(kk1); mfma kk1 i0-1 ----
        short8 ag[4];
#pragma unroll
        for (int i = 0; i < 4; i++)
            ag[i] = *(const short8*)(Ab + (ar + i * 16 + lr) * 64 + (((4 + lq) ^ sx) << 3));
        __builtin_amdgcn_s_barrier();
        asm volatile("s_waitcnt lgkmcnt(0)" ::: "memory");
        __builtin_amdgcn_sched_barrier(0);
        __builtin_amdgcn_s_setprio(1);
#pragma unroll
        for (int i = 0; i < 2; i++)
#pragma unroll
            for (int jn = 0; jn < 4; jn++)
                acc[i][jn] = __builtin_amdgcn_mfma_f32_16x16x32_bf16(ag[i], bf1[jn], acc[i][jn], 0, 0, 0);
        __builtin_amdgcn_s_setprio(0);
        __builtin_amdgcn_s_barrier();

        // ---- phase 3: stage Ah0(kt+2); mfma kk1 i2-3; counted vmcnt ----
        if (kt + 2 < NT) stage(A, m0, &Abuf[b][0][0], nk);
        __builtin_amdgcn_s_barrier();
        __builtin_amdgcn_s_setprio(1);
#pragma unroll
        for (int i = 2; i < 4; i++)
#pragma unroll
            for (int jn = 0; jn < 4; jn++)
                acc[i][jn] = __builtin_amdgcn_mfma_f32_16x16x32_bf16(ag[i], bf1[jn], acc[i][jn], 0, 0, 0);
        __builtin_amdgcn_s_setprio(0);
        if (kt + 2 < NT) asm volatile("s_waitcnt vmcnt(4)" ::: "memory");
        else asm volatile("s_waitcnt vmcnt(0)" ::: "memory");
        __builtin_amdgcn_s_barrier();
    }

#pragma unroll
    for (int i = 0; i < 4; i++)
#pragma unroll
        for (int jn = 0; jn < 4; jn++)
#pragma unroll
            for (int r = 0; r < 4; r++) {
                int row = m0 + wm * 64 + i * 16 + lq * 4 + r;
                int col = n0 + wn * 64 + jn * 16 + lr;
                if constexpr (sizeof(OUT_T) == 2)
                    C[(size_t)row * N + col] = f2bf(acc[i][jn][r]);
                else
                    C[(size_t)row * N + col] = acc[i][jn][r];
            }
}

// ==========================================================================
// Merged post-QKV prep.
// Blocks < 12288: RMS-norm + RoPE, 2 head-rows per wave (u64 = 8B/lane
// loads, float4 w/cos/sin, half-wave shfl reduce). In place on QKV.
// Blocks >= 12288: V transpose, 64x64 tile, 2x2 micro (u32 in / u32 out).
// ==========================================================================
__global__ __launch_bounds__(256) void prep_qkv(u16* __restrict__ QKV,
                                                u16* __restrict__ Vt,
                                                const float* __restrict__ cosb,
                                                const float* __restrict__ sinb,
                                                const float* __restrict__ qw,
                                                const float* __restrict__ kw) {
    const int bx = blockIdx.x;
    const int tid = threadIdx.x;
    if (bx >= 12288) {  // V transpose: 1024 blocks
        const int idx = bx - 12288;
        const int s0 = (idx & 31) * 64;
        const int d0 = ((idx >> 5) & 1) * 64;
        const int zz = idx >> 6;            // 0..15
        const int b = zz >> 3, kv = zz & 7;
        __shared__ u16 t[64][66];
        const int tx = tid & 31, ty = tid >> 5;   // 32 x 8
        const u16* src = QKV + (size_t)(b * 2048 + s0) * 4096 + 3072 + kv * 128 + d0;
#pragma unroll
        for (int p = 0; p < 4; p++) {
            int rr = (ty + 8 * p) * 2;
#pragma unroll
            for (int i = 0; i < 2; i++)
                *(u32*)&t[rr + i][tx * 2] = *(const u32*)(src + (size_t)(rr + i) * 4096 + tx * 2);
        }
        __syncthreads();
        u16* dst = Vt + (size_t)((b * 8 + kv) * 128 + d0) * 2048 + s0;
#pragma unroll
        for (int p = 0; p < 4; p++) {
            int cc = (ty + 8 * p) * 2;
            u32 a = *(const u32*)&t[tx * 2][cc];
            u32 bq = *(const u32*)&t[tx * 2 + 1][cc];
            u32 pk0 = (a & 0xffffu) | (bq << 16);
            u32 pk1 = (a >> 16) | (bq & 0xffff0000u);
            *(u32*)(dst + (size_t)cc * 2048 + tx * 2) = pk0;
            *(u32*)(dst + (size_t)(cc + 1) * 2048 + tx * 2) = pk1;
        }
        return;
    }
    // norm+rope: 12288 blocks x 4 waves x 2 rows = 98304 rows
    const int wave = tid >> 6, lane = tid & 63;
    const int half = lane >> 5, l5 = lane & 31;
    const int t = bx * 4 + wave;        // 0..49151
    const int R = t * 2 + half;         // row id (never straddles Q/K: 65536 even)
    u16* ptr;
    const float* w;
    float scale;
    int bs;
    if (R < 65536) {
        bs = R >> 4;
        ptr = QKV + (size_t)bs * 4096 + (R & 15) * 128;
        w = qw;
        scale = 0.08838834764831845f * 1.4426950408889634f;  // D^-0.5 * log2(e)
    } else {
        int R2 = R - 65536;
        bs = R2 >> 3;
        ptr = QKV + (size_t)bs * 4096 + 2048 + (R2 & 7) * 128;
        w = kw;
        scale = 1.0f;
    }
    const int d = l5 * 4;
    u64 xv = *(const u64*)(ptr + d);
    float x0 = bf2f((u16)xv), x1 = bf2f((u16)(xv >> 16));
    float x2 = bf2f((u16)(xv >> 32)), x3 = bf2f((u16)(xv >> 48));
    float ss = x0 * x0 + x1 * x1 + x2 * x2 + x3 * x3;
#pragma unroll
    for (int off = 1; off < 32; off <<= 1) ss += __shfl_xor(ss, off);
    float rn = rsqrtf(ss * (1.0f / 128.0f) + 1e-6f);
    float4 wv = *(const float4*)(w + d);
    float y0 = x0 * rn * wv.x, y1 = x1 * rn * wv.y;
    float y2 = x2 * rn * wv.z, y3 = x3 * rn * wv.w;
    // rotate_half partner: d^64 <-> lane l5^16 (same half)
    float p0 = __shfl_xor(y0, 16), p1 = __shfl_xor(y1, 16);
    float p2 = __shfl_xor(y2, 16), p3 = __shfl_xor(y3, 16);
    float sgn = (l5 < 16) ? -1.0f : 1.0f;
    float4 cv = *(const float4*)(cosb + (size_t)bs * 128 + d);
    float4 sv = *(const float4*)(sinb + (size_t)bs * 128 + d);
    float o0 = (y0 * cv.x + sgn * p0 * sv.x) * scale;
    float o1 = (y1 * cv.y + sgn * p1 * sv.y) * scale;
    float o2 = (y2 * cv.z + sgn * p2 * sv.z) * scale;
    float o3 = (y3 * cv.w + sgn * p3 * sv.w) * scale;
    u64 res = (u64)f2bf_pk(o0, o1) | ((u64)f2bf_pk(o2, o3) << 32);
    *(u64*)(ptr + d) = res;
}

// ==========================================================================
// Causal GQA flash attention, transposed-score formulation.
// QBLK=64 (4 waves, 256 thr), KVBLK=64.
// LDS 50KB: K double-buffered (32KB) + V single-buffered (16KB) + ones rows
// (2KB) so PV's jn=8 column accumulates l = sum(P) inside the MFMA.
// Counted-vmcnt barriers (T4). 3 blocks/CU = 12 waves/CU.
// Decode: r6 LPT (qt = 31 - id/32) — the empirically best of three decode
// variants (r6 85.6 / r7 115.7 / r8 110.9 µs); placement models failed to
// predict better, so this is pinned. T5 setprio, T13 defer-max.
// ==========================================================================
__global__ __launch_bounds__(256, 3) void attn_kernel(const u16* __restrict__ QKV,
                                                      const u16* __restrict__ Vt,
                                                      u16* __restrict__ O) {
    __shared__ __align__(16) u16 Ks[2][64 * 128];   // [key][d] swizzled, 32KB
    __shared__ __align__(16) u16 Vs[144 * 64];      // [d][key] swizzled + ones rows 128..143
    const int tid = threadIdx.x;
    const int wave = tid >> 6, lane = tid & 63;
    const int lr = lane & 15, lq = lane >> 4;

    // LPT decode: rank 0 = longest (qt=31)
    const int id = blockIdx.x;        // 0..1023
    const int qt = 31 - (id >> 5);
    const int j = id & 31;
    const int h = j & 15;
    const int b = j >> 4;

    const int kv = h >> 1;
    const int q0 = qt * 64;
    const int wq = wave * 16;

    // async stage of one 64-key K tile into buffer `buf` (4 instrs/wave)
    auto stageK = [&](int buf, int k0s) {
#pragma unroll
        for (int jj = 0; jj < 4; jj++) {   // Ks: 64 rows x 256 B
            int r = wave * 16 + jj * 4 + (lane >> 4);
            int ch = (lane & 15) ^ (r & 15);   // inverse-swizzled source chunk
            __builtin_amdgcn_global_load_lds(
                (const AS1 void*)(QKV + (size_t)(b * 2048 + k0s + r) * 4096 + 2048 + kv * 128 + ch * 8),
                (AS3 void*)(&Ks[buf][(wave * 16 + jj * 4) * 128]), 16, 0, 0);
        }
    };
    // async stage of the V tile (rows 0..127 only; ones rows untouched)
    auto stageV = [&](int k0s) {
#pragma unroll
        for (int jj = 0; jj < 4; jj++) {   // Vs: 128 rows x 128 B
            int r = wave * 32 + jj * 8 + (lane >> 3);
            int ch = (lane & 7) ^ (r & 7);
            __builtin_amdgcn_global_load_lds(
                (const AS1 void*)(Vt + (size_t)((b * 8 + kv) * 128 + r) * 2048 + k0s + ch * 8),
                (AS3 void*)(&Vs[(wave * 32 + jj * 8) * 64]), 16, 0, 0);
        }
    };

    // fill ones rows (128..143) once; any swizzled read sees 1.0
    *(u64*)(&Vs[128 * 64 + tid * 4]) = 0x3F803F803F803F80ULL;
    asm volatile("s_waitcnt lgkmcnt(0)" ::: "memory");

    // Q fragments in registers (B-operand: n=qrow on lr, k=d on lq*8+j)
    short8 qf[4];
#pragma unroll
    for (int t = 0; t < 4; t++)
        qf[t] = *(const short8*)(QKV + (size_t)(b * 2048 + q0 + wq + lr) * 4096 + h * 128 + t * 32 + lq * 8);

    floatx4 zf = {0.f, 0.f, 0.f, 0.f};
    floatx4 oacc[9];   // [8] = l column (ones rows of Vs)
#pragma unroll
    for (int jn = 0; jn < 9; jn++) oacc[jn] = zf;
    float mstate = -1e30f;

    const int nIter = qt + 1;

    stageK(0, 0);

    for (int kt = 0; kt < nIter; kt++) {
        const int k0 = kt * 64;
        const int cur = kt & 1;
        // barrier #1: own outstanding = K(kt) only -> vmcnt(0) is exact.
        asm volatile("s_waitcnt vmcnt(0)" ::: "memory");
        __builtin_amdgcn_s_barrier();
        stageV(k0);
        if (kt + 1 < nIter) stageK(cur ^ 1, k0 + 64);

        const bool active = (k0 <= q0 + wq + 15);
        u64 pb[4];
        if (active) {
            const u16* KsC = &Ks[cur][0];
            floatx4 sacc[4];
#pragma unroll
            for (int jm = 0; jm < 4; jm++) sacc[jm] = zf;
            __builtin_amdgcn_s_setprio(1);
#pragma unroll
            for (int t = 0; t < 4; t++) {
                short8 a[4];
#pragma unroll
                for (int jm = 0; jm < 4; jm++)
                    a[jm] = *(const short8*)(KsC + (jm * 16 + lr) * 128 + (((t * 4 + lq) ^ lr) << 3));
#pragma unroll
                for (int jm = 0; jm < 4; jm++)
                    sacc[jm] = __builtin_amdgcn_mfma_f32_16x16x32_bf16(a[jm], qf[t], sacc[jm], 0, 0, 0);
            }
            __builtin_amdgcn_s_setprio(0);

            if (k0 + 63 > q0 + wq) {
#pragma unroll
                for (int jm = 0; jm < 4; jm++) {
                    int diff = (q0 + wq + lr) - (k0 + jm * 16 + lq * 4);
#pragma unroll
                    for (int r = 0; r < 4; r++)
                        if (r > diff) sacc[jm][r] = -1e30f;
                }
            }

            // per-qrow max (tree within jm, then cross-quad)
            float mx = -1e30f;
#pragma unroll
            for (int jm = 0; jm < 4; jm++) {
                float a0 = fmaxf(sacc[jm][0], sacc[jm][1]);
                float a1 = fmaxf(sacc[jm][2], sacc[jm][3]);
                mx = fmaxf(mx, fmaxf(a0, a1));
            }
            mx = fmaxf(mx, __shfl_xor(mx, 16));
            mx = fmaxf(mx, __shfl_xor(mx, 32));

            // T13 defer-max: skip rescale when all rows grew <= 8 (log2 dom)
            bool defer = __all(mx - mstate <= 8.0f);
            float mnew = defer ? mstate : fmaxf(mstate, mx);

#pragma unroll
            for (int jm = 0; jm < 4; jm++)
#pragma unroll
                for (int r = 0; r < 4; r++)
                    sacc[jm][r] = exp2f(sacc[jm][r] - mnew);

            if (!defer) {
                float alpha = exp2f(mstate - mnew);
                mstate = mnew;
                float ao[4];
#pragma unroll
                for (int r = 0; r < 4; r++) ao[r] = __shfl(alpha, lq * 4 + r);
#pragma unroll
                for (int jn = 0; jn < 9; jn++)   // includes l column
#pragma unroll
                    for (int r = 0; r < 4; r++) oacc[jn][r] *= ao[r];
            }

#pragma unroll
            for (int jm = 0; jm < 4; jm++) {
                u32 lo = f2bf_pk(sacc[jm][0], sacc[jm][1]);
                u32 hi = f2bf_pk(sacc[jm][2], sacc[jm][3]);
                pb[jm] = (u64)lo | ((u64)hi << 32);
            }
        }

        // barrier #2: wait ONLY the V loads (first 4 in own queue);
        // K(kt+1) (4 newer loads) stays in flight across PV + next barrier.
        if (kt + 1 < nIter) asm volatile("s_waitcnt vmcnt(4)" ::: "memory");
        else                asm volatile("s_waitcnt vmcnt(0)" ::: "memory");
        __builtin_amdgcn_s_barrier();

        if (active) {
            // O += P @ [V | 1]; jn=8 accumulates l per qrow inside MFMA.
            __builtin_amdgcn_s_setprio(1);
#pragma unroll
            for (int t = 0; t < 2; t++) {
                union { short8 v; u64 q[2]; } pa;
                pa.q[0] = pb[2 * t];
                pa.q[1] = pb[2 * t + 1];
#pragma unroll
                for (int jn = 0; jn < 9; jn++) {
                    const u16* vrow = Vs + (jn * 16 + lr) * 64 + (lq & 1) * 4;
                    union { short8 v; u64 q[2]; } vb;
                    vb.q[0] = *(const u64*)(vrow + (((t * 4 + (lq >> 1)) ^ (lr & 7)) << 3));
                    vb.q[1] = *(const u64*)(vrow + (((t * 4 + 2 + (lq >> 1)) ^ (lr & 7)) << 3));
                    oacc[jn] = __builtin_amdgcn_mfma_f32_16x16x32_bf16(pa.v, vb.v, oacc[jn], 0, 0, 0);
                }
            }
            __builtin_amdgcn_s_setprio(0);
        }
    }

    // epilogue: l already at the right lanes (oacc[8][r], qrow = lq*4+r)
#pragma unroll
    for (int jn = 0; jn < 8; jn++)
#pragma unroll
        for (int r = 0; r < 4; r++) {
            int row = q0 + wq + lq * 4 + r;
            O[(size_t)(b * 2048 + row) * 2048 + h * 128 + jn * 16 + lr] =
                f2bf(oacc[jn][r] / oacc[8][r]);
        }
}

// ==========================================================================
extern "C" void kernel_launch(void* const* d_in, const int* in_sizes, int n_in,
                              void* d_out, int out_size, void* d_ws, size_t ws_size,
                              hipStream_t stream) {
    const float* X = (const float*)d_in[0];
    const float* cosb = (const float*)d_in[1];
    const float* sinb = (const float*)d_in[2];
    const float* Wq = (const float*)d_in[3];
    const float* Wk = (const float*)d_in[4];
    const float* Wv = (const float*)d_in[5];
    const float* Wo = (const float*)d_in[6];
    const float* qw = (const float*)d_in[7];
    const float* kw = (const float*)d_in[8];
    float* out = (float*)d_out;
    u16* ws = (u16*)d_ws;

    u16* WqkvT = ws;                    // 4096x2048 = 8388608
    u16* WoT = WqkvT + 8388608;         // 4194304
    u16* Xb = WoT + 4194304;            // 8388608 (dead after QKV GEMM)
    u16* QKVb = Xb + 8388608;           // 4096x4096 = 16777216
    u16* Vtb = QKVb + 16777216;         // 4194304
    u16* Ob = Xb;                       // alias
    // total 41,943,040 u16 = 83.9 MB

    prep_weights<<<dim3(32, 32, 5), dim3(32, 8), 0, stream>>>(Wq, Wk, Wv, Wo, X,
                                                              WqkvT, WoT, Xb);

    gemm256<u16><<<dim3(16, 16), 512, 0, stream>>>(Xb, WqkvT, QKVb, 4096, 4096, 2048);

    prep_qkv<<<13312, 256, 0, stream>>>(QKVb, Vtb, cosb, sinb, qw, kw);

    attn_kernel<<<1024, 256, 0, stream>>>(QKVb, Vtb, Ob);

    gemm128n<float><<<dim3(16, 16), 512, 0, stream>>>(Ob, WoT, out, 4096, 2048, 2048);
}

// Round 11
// 342.103 us; speedup vs baseline: 1.1496x; 1.0015x over previous
//
#include <hip/hip_runtime.h>
#include <hip/hip_bf16.h>

typedef unsigned short u16;
typedef unsigned int u32;
typedef unsigned long long u64;
typedef __attribute__((ext_vector_type(8))) short short8;
typedef __attribute__((ext_vector_type(4))) float floatx4;

#define AS1 __attribute__((address_space(1)))
#define AS3 __attribute__((address_space(3)))

// ---- bf16 <-> f32 helpers (raw bits, RNE) ----
__device__ __forceinline__ float bf2f(u16 u) {
    u32 x = ((u32)u) << 16;
    float f;
    __builtin_memcpy(&f, &x, 4);
    return f;
}
__device__ __forceinline__ u16 f2bf(float f) {
    u32 x;
    __builtin_memcpy(&x, &f, 4);
    u32 r = (x + 0x7fffu + ((x >> 16) & 1u)) >> 16;
    return (u16)r;
}
// packed 2xf32 -> 2xbf16 (v_cvt_pk_bf16_f32), returned as u32 (lo=first)
__device__ __forceinline__ u32 f2bf_pk(float a, float b) {
    __hip_bfloat162 h = __float22bfloat162_rn(float2{a, b});
    u32 r;
    __builtin_memcpy(&r, &h, 4);
    return r;
}

// ==========================================================================
// Merged prep: z<4 = weight transposes (f32 RxC -> bf16 CxR), z=4 = X cast.
// 64x64 tiles, 2x2 micro-tile/thread: float2 reads (8B/lane), u32 packed
// writes (128B/wave segments). Block = dim3(32,8) — 2D indexing required.
// ==========================================================================
__global__ __launch_bounds__(256) void prep_weights(const float* __restrict__ Wq,
                                                    const float* __restrict__ Wk,
                                                    const float* __restrict__ Wv,
                                                    const float* __restrict__ Wo,
                                                    const float* __restrict__ X,
                                                    u16* __restrict__ WqkvT,
                                                    u16* __restrict__ WoT,
                                                    u16* __restrict__ Xb) {
    const int z = blockIdx.z;
    const int tx = threadIdx.x, ty = threadIdx.y;   // 32 x 8
    if (z == 4) {  // X cast: 1024 blocks x 256 thr x 8 float4 = 8.39M f32
        int tid = ty * 32 + tx;
        int idx = blockIdx.y * 32 + blockIdx.x;     // 0..1023
        if (idx >= 1024) return;
        size_t base = (size_t)idx * 256 + tid;
#pragma unroll
        for (int p = 0; p < 8; p++) {
            size_t i = (base + (size_t)p * 262144) * 4;
            float4 v = *(const float4*)(X + i);
            u16 o[4] = {f2bf(v.x), f2bf(v.y), f2bf(v.z), f2bf(v.w)};
            *(u64*)(Xb + i) = *(u64*)o;
        }
        return;
    }
    const float* in;
    u16* out;
    int C;
    if (z == 0) { in = Wq; out = WqkvT; C = 2048; }
    else if (z == 1) { in = Wk; out = WqkvT + 2048 * 2048; C = 1024; }
    else if (z == 2) { in = Wv; out = WqkvT + 3072 * 2048; C = 1024; }
    else { in = Wo; out = WoT; C = 2048; }
    const int c0 = blockIdx.x * 64, r0 = blockIdx.y * 64;
    if (c0 >= C) return;
    __shared__ u16 t[64][66];
#pragma unroll
    for (int p = 0; p < 4; p++) {
        int rr = (ty + 8 * p) * 2;
#pragma unroll
        for (int i = 0; i < 2; i++) {
            float2 v = *(const float2*)(in + (size_t)(r0 + rr + i) * C + c0 + tx * 2);
            *(u32*)&t[rr + i][tx * 2] = f2bf_pk(v.x, v.y);
        }
    }
    __syncthreads();
#pragma unroll
    for (int p = 0; p < 4; p++) {
        int cc = (ty + 8 * p) * 2;
        u32 a = *(const u32*)&t[tx * 2][cc];       // r=2tx : (col cc | col cc+1)
        u32 bq = *(const u32*)&t[tx * 2 + 1][cc];  // r=2tx+1
        u32 pk0 = (a & 0xffffu) | (bq << 16);            // col cc, rows 2tx,2tx+1
        u32 pk1 = (a >> 16) | (bq & 0xffff0000u);        // col cc+1
        *(u32*)(out + (size_t)(c0 + cc) * 2048 + r0 + tx * 2) = pk0;
        *(u32*)(out + (size_t)(c0 + cc + 1) * 2048 + r0 + tx * 2) = pk1;
    }
}

// ==========================================================================
// GEMM: C[M,N] = A[M,K] @ Bt[N,K]^T (bf16 in, fp32 acc, OUT_T out)
// 256x256 tile, BK=64, 512 thr (8 waves 2Mx4N), 8-phase-per-2-K-tiles
// schedule: counted vmcnt(6), raw s_barrier, XOR-swizzled LDS, setprio.
// FUSEV (QKV instantiation only): blocks with n0>=3072 hold the V columns;
// epilogue writes them transposed straight to Vt (b,kv,d,s) as packed u64
// (4 acc r-values = 4 consecutive s) and skips the C write — eliminates the
// separate V transpose kernel pass and the QKV V-region round trip.
// ==========================================================================
template <typename OUT_T, bool FUSEV>
__global__ __launch_bounds__(512, 2) void gemm256(const u16* __restrict__ A,
                                                  const u16* __restrict__ Bt,
                                                  OUT_T* __restrict__ C,
                                                  u16* __restrict__ Vt,
                                                  int M, int N, int K) {
    (void)M;
    __shared__ __align__(16) u16 lds[2][2][2][128 * 64];  // [buf][A/B][half][r*64+c]
    const int tid = threadIdx.x;
    const int wave = tid >> 6, lane = tid & 63;
    const int lr = lane & 15, lq = lane >> 4;
    const int wm = wave >> 2, wn = wave & 3;
    const int m0 = blockIdx.y * 256, n0 = blockIdx.x * 256;

    const int srow = lane >> 3;                    // 0..7 within 8-row group
    const int schunk = ((lane & 7) ^ srow) << 3;   // source chunk (elems)
    const int slot = wave << 1;

    auto stage = [&](const u16* src, int rbase, int buf, int mat, int half, int k0) {
#pragma unroll
        for (int j = 0; j < 2; j++) {
            int r = rbase + half * 128 + (slot + j) * 8 + srow;
            __builtin_amdgcn_global_load_lds(
                (const AS1 void*)(src + (size_t)r * K + k0 + schunk),
                (AS3 void*)(&lds[buf][mat][half][(slot + j) * 512]), 16, 0, 0);
        }
    };

    floatx4 zf = {0.f, 0.f, 0.f, 0.f};
    floatx4 acc[8][4];
#pragma unroll
    for (int i = 0; i < 8; i++)
#pragma unroll
        for (int jn = 0; jn < 4; jn++) acc[i][jn] = zf;

    const int NT = K >> 6;

    stage(Bt, n0, 0, 1, 0, 0);
    stage(Bt, n0, 0, 1, 1, 0);
    stage(A, m0, 0, 0, 0, 0);
    stage(A, m0, 0, 0, 1, 0);
    if (NT > 1) {
        stage(Bt, n0, 1, 1, 0, 64);
        stage(Bt, n0, 1, 1, 1, 64);
        stage(A, m0, 1, 0, 0, 64);
        asm volatile("s_waitcnt vmcnt(6)" ::: "memory");
    } else {
        asm volatile("s_waitcnt vmcnt(0)" ::: "memory");
    }
    __builtin_amdgcn_s_barrier();

    for (int kt = 0; kt < NT; kt++) {
        const int b = kt & 1;
        const u16* Ab = &lds[b][0][wm][0];
        const u16* Bb = &lds[b][1][wn >> 1][0];
        const int brow = (wn & 1) * 64;
        const int sx = lr & 7;
        const int nk = (kt + 2) << 6;

        // ---- phase 0 ----
        short8 bf0[4], bf1[4], af[4];
#pragma unroll
        for (int jn = 0; jn < 4; jn++) {
            int rh = brow + jn * 16 + lr;
            bf0[jn] = *(const short8*)(Bb + rh * 64 + ((lq ^ sx) << 3));
            bf1[jn] = *(const short8*)(Bb + rh * 64 + (((4 + lq) ^ sx) << 3));
        }
#pragma unroll
        for (int i = 0; i < 4; i++)
            af[i] = *(const short8*)(Ab + (i * 16 + lr) * 64 + ((lq ^ sx) << 3));
        if (kt + 1 < NT) stage(A, m0, b ^ 1, 0, 1, (kt + 1) << 6);
        __builtin_amdgcn_s_barrier();
        asm volatile("s_waitcnt lgkmcnt(0)" ::: "memory");
        __builtin_amdgcn_sched_barrier(0);
        __builtin_amdgcn_s_setprio(1);
#pragma unroll
        for (int i = 0; i < 4; i++)
#pragma unroll
            for (int jn = 0; jn < 4; jn++)
                acc[i][jn] = __builtin_amdgcn_mfma_f32_16x16x32_bf16(af[i], bf0[jn], acc[i][jn], 0, 0, 0);
        __builtin_amdgcn_s_setprio(0);
        __builtin_amdgcn_s_barrier();

        // ---- phase 1 ----
        short8 ag[4];
#pragma unroll
        for (int i = 0; i < 4; i++)
            ag[i] = *(const short8*)(Ab + ((i + 4) * 16 + lr) * 64 + ((lq ^ sx) << 3));
        if (kt + 2 < NT) stage(Bt, n0, b, 1, 0, nk);
        __builtin_amdgcn_s_barrier();
        asm volatile("s_waitcnt lgkmcnt(0)" ::: "memory");
        __builtin_amdgcn_sched_barrier(0);
        __builtin_amdgcn_s_setprio(1);
#pragma unroll
        for (int i = 0; i < 4; i++)
#pragma unroll
            for (int jn = 0; jn < 4; jn++)
                acc[i + 4][jn] = __builtin_amdgcn_mfma_f32_16x16x32_bf16(ag[i], bf0[jn], acc[i + 4][jn], 0, 0, 0);
        __builtin_amdgcn_s_setprio(0);
        __builtin_amdgcn_s_barrier();

        // ---- phase 2 ----
        short8 c0[4], c1[4];
#pragma unroll
        for (int i = 0; i < 4; i++) {
            c0[i] = *(const short8*)(Ab + (i * 16 + lr) * 64 + (((4 + lq) ^ sx) << 3));
            c1[i] = *(const short8*)(Ab + ((i + 4) * 16 + lr) * 64 + (((4 + lq) ^ sx) << 3));
        }
        if (kt + 2 < NT) stage(Bt, n0, b, 1, 1, nk);
        __builtin_amdgcn_s_barrier();
        asm volatile("s_waitcnt lgkmcnt(0)" ::: "memory");
        __builtin_amdgcn_sched_barrier(0);
        __builtin_amdgcn_s_setprio(1);
#pragma unroll
        for (int i = 0; i < 4; i++)
#pragma unroll
            for (int jn = 0; jn < 4; jn++)
                acc[i][jn] = __builtin_amdgcn_mfma_f32_16x16x32_bf16(c0[i], bf1[jn], acc[i][jn], 0, 0, 0);
        __builtin_amdgcn_s_setprio(0);
        __builtin_amdgcn_s_barrier();

        // ---- phase 3 ----
        if (kt + 2 < NT) stage(A, m0, b, 0, 0, nk);
        __builtin_amdgcn_s_barrier();
        __builtin_amdgcn_s_setprio(1);
#pragma unroll
        for (int i = 0; i < 4; i++)
#pragma unroll
            for (int jn = 0; jn < 4; jn++)
                acc[i + 4][jn] = __builtin_amdgcn_mfma_f32_16x16x32_bf16(c1[i], bf1[jn], acc[i + 4][jn], 0, 0, 0);
        __builtin_amdgcn_s_setprio(0);
        if (kt + 2 < NT) asm volatile("s_waitcnt vmcnt(6)" ::: "memory");
        else asm volatile("s_waitcnt vmcnt(0)" ::: "memory");
        __builtin_amdgcn_s_barrier();
    }

    if (FUSEV && n0 >= 3072) {
        // V columns -> Vt (b,kv,d,s), packed 4-consecutive-s u64 stores.
        const int bb = m0 >> 11;            // batch (256-row tile never straddles)
        const int sbase = (m0 & 2047) + wm * 128 + lq * 4;
#pragma unroll
        for (int i = 0; i < 8; i++)
#pragma unroll
            for (int jn = 0; jn < 4; jn++) {
                int dcol = (n0 - 3072) + wn * 64 + jn * 16 + lr;  // 0..1023
                int kv = dcol >> 7, d = dcol & 127;
                u16 o[4] = {f2bf(acc[i][jn][0]), f2bf(acc[i][jn][1]),
                            f2bf(acc[i][jn][2]), f2bf(acc[i][jn][3])};
                *(u64*)(Vt + (size_t)((bb * 8 + kv) * 128 + d) * 2048 +
                        sbase + i * 16) = *(u64*)o;
            }
        return;
    }

#pragma unroll
    for (int i = 0; i < 8; i++)
#pragma unroll
        for (int jn = 0; jn < 4; jn++)
#pragma unroll
            for (int r = 0; r < 4; r++) {
                int row = m0 + wm * 128 + i * 16 + lq * 4 + r;
                int col = n0 + wn * 64 + jn * 16 + lr;
                if constexpr (sizeof(OUT_T) == 2)
                    C[(size_t)row * N + col] = f2bf(acc[i][jn][r]);
                else
                    C[(size_t)row * N + col] = acc[i][jn][r];
            }
}

// ==========================================================================
// GEMM: BM=256 x BN=128, BK=64, 512 thr = 8 waves (4M x 2N), 64x64/wave.
// Same 8-phase counted-vmcnt schedule; 3 stage-units/tile -> vmcnt(4).
// Grid (N/128, M/256) -> 256 blocks for the Wo GEMM (full GPU).
// ==========================================================================
template <typename OUT_T>
__global__ __launch_bounds__(512, 2) void gemm128n(const u16* __restrict__ A,
                                                   const u16* __restrict__ Bt,
                                                   OUT_T* __restrict__ C,
                                                   int M, int N, int K) {
    (void)M;
    __shared__ __align__(16) u16 Abuf[2][2][128 * 64];  // [buf][half][r*64+c]
    __shared__ __align__(16) u16 Bbuf[2][128 * 64];     // [buf][r*64+c]
    const int tid = threadIdx.x;
    const int wave = tid >> 6, lane = tid & 63;
    const int lr = lane & 15, lq = lane >> 4;
    const int wm = wave >> 1, wn = wave & 1;
    const int m0 = blockIdx.y * 256, n0 = blockIdx.x * 128;

    const int srow = lane >> 3;
    const int schunk = ((lane & 7) ^ srow) << 3;
    const int slot = wave << 1;

    auto stage = [&](const u16* src, int rowbase, u16* ldsbase, int k0) {
#pragma unroll
        for (int j = 0; j < 2; j++) {
            int r = rowbase + (slot + j) * 8 + srow;
            __builtin_amdgcn_global_load_lds(
                (const AS1 void*)(src + (size_t)r * K + k0 + schunk),
                (AS3 void*)(ldsbase + (slot + j) * 512), 16, 0, 0);
        }
    };

    floatx4 zf = {0.f, 0.f, 0.f, 0.f};
    floatx4 acc[4][4];
#pragma unroll
    for (int i = 0; i < 4; i++)
#pragma unroll
        for (int jn = 0; jn < 4; jn++) acc[i][jn] = zf;

    const int NT = K >> 6;

    // prologue: t0 = {Ah0, Ah1, B}; t1 = {Ah0, B} (Ah1(t1) comes in t0.ph0)
    stage(A, m0, &Abuf[0][0][0], 0);
    stage(A, m0 + 128, &Abuf[0][1][0], 0);
    stage(Bt, n0, &Bbuf[0][0], 0);
    if (NT > 1) {
        stage(A, m0, &Abuf[1][0][0], 64);
        stage(Bt, n0, &Bbuf[1][0], 64);
        asm volatile("s_waitcnt vmcnt(4)" ::: "memory");
    } else {
        asm volatile("s_waitcnt vmcnt(0)" ::: "memory");
    }
    __builtin_amdgcn_s_barrier();

    for (int kt = 0; kt < NT; kt++) {
        const int b = kt & 1;
        const u16* Ab = &Abuf[b][wm >> 1][0];
        const u16* Bb = &Bbuf[b][0];
        const int ar = (wm & 1) * 64;
        const int br = wn * 64;
        const int sx = lr & 7;
        const int nk = (kt + 2) << 6;

        // ---- phase 0: read bf0,bf1,af(kk0); stage Ah1(kt+1); mfma kk0 i0-1 ----
        short8 bf0[4], bf1[4], af[4];
#pragma unroll
        for (int jn = 0; jn < 4; jn++) {
            int rh = br + jn * 16 + lr;
            bf0[jn] = *(const short8*)(Bb + rh * 64 + ((lq ^ sx) << 3));
            bf1[jn] = *(const short8*)(Bb + rh * 64 + (((4 + lq) ^ sx) << 3));
        }
#pragma unroll
        for (int i = 0; i < 4; i++)
            af[i] = *(const short8*)(Ab + (ar + i * 16 + lr) * 64 + ((lq ^ sx) << 3));
        if (kt + 1 < NT) stage(A, m0 + 128, &Abuf[b ^ 1][1][0], (kt + 1) << 6);
        __builtin_amdgcn_s_barrier();
        asm volatile("s_waitcnt lgkmcnt(0)" ::: "memory");
        __builtin_amdgcn_sched_barrier(0);
        __builtin_amdgcn_s_setprio(1);
#pragma unroll
        for (int i = 0; i < 2; i++)
#pragma unroll
            for (int jn = 0; jn < 4; jn++)
                acc[i][jn] = __builtin_amdgcn_mfma_f32_16x16x32_bf16(af[i], bf0[jn], acc[i][jn], 0, 0, 0);
        __builtin_amdgcn_s_setprio(0);
        __builtin_amdgcn_s_barrier();

        // ---- phase 1: stage B(kt+2); mfma kk0 i2-3 ----
        if (kt + 2 < NT) stage(Bt, n0, &Bbuf[b][0], nk);
        __builtin_amdgcn_s_barrier();
        __builtin_amdgcn_s_setprio(1);
#pragma unroll
        for (int i = 2; i < 4; i++)
#pragma unroll
            for (int jn = 0; jn < 4; jn++)
                acc[i][jn] = __builtin_amdgcn_mfma_f32_16x16x32_bf16(af[i], bf0[jn], acc[i][jn], 0, 0, 0);
        __builtin_amdgcn_s_setprio(0);
        __builtin_amdgcn_s_barrier();

        // ---- phase 2: read ag(kk1); mfma kk1 i0-1 ----
        short8 ag[4];
#pragma unroll
        for (int i = 0; i < 4; i++)
            ag[i] = *(const short8*)(Ab + (ar + i * 16 + lr) * 64 + (((4 + lq) ^ sx) << 3));
        __builtin_amdgcn_s_barrier();
        asm volatile("s_waitcnt lgkmcnt(0)" ::: "memory");
        __builtin_amdgcn_sched_barrier(0);
        __builtin_amdgcn_s_setprio(1);
#pragma unroll
        for (int i = 0; i < 2; i++)
#pragma unroll
            for (int jn = 0; jn < 4; jn++)
                acc[i][jn] = __builtin_amdgcn_mfma_f32_16x16x32_bf16(ag[i], bf1[jn], acc[i][jn], 0, 0, 0);
        __builtin_amdgcn_s_setprio(0);
        __builtin_amdgcn_s_barrier();

        // ---- phase 3: stage Ah0(kt+2); mfma kk1 i2-3; counted vmcnt ----
        if (kt + 2 < NT) stage(A, m0, &Abuf[b][0][0], nk);
        __builtin_amdgcn_s_barrier();
        __builtin_amdgcn_s_setprio(1);
#pragma unroll
        for (int i = 2; i < 4; i++)
#pragma unroll
            for (int jn = 0; jn < 4; jn++)
                acc[i][jn] = __builtin_amdgcn_mfma_f32_16x16x32_bf16(ag[i], bf1[jn], acc[i][jn], 0, 0, 0);
        __builtin_amdgcn_s_setprio(0);
        if (kt + 2 < NT) asm volatile("s_waitcnt vmcnt(4)" ::: "memory");
        else asm volatile("s_waitcnt vmcnt(0)" ::: "memory");
        __builtin_amdgcn_s_barrier();
    }

#pragma unroll
    for (int i = 0; i < 4; i++)
#pragma unroll
        for (int jn = 0; jn < 4; jn++)
#pragma unroll
            for (int r = 0; r < 4; r++) {
                int row = m0 + wm * 64 + i * 16 + lq * 4 + r;
                int col = n0 + wn * 64 + jn * 16 + lr;
                if constexpr (sizeof(OUT_T) == 2)
                    C[(size_t)row * N + col] = f2bf(acc[i][jn][r]);
                else
                    C[(size_t)row * N + col] = acc[i][jn][r];
            }
}

// ==========================================================================
// RMS-norm + RoPE only (V transpose now fused into gemm256 epilogue).
// 2 head-rows per wave (u64 = 8B/lane loads, float4 w/cos/sin, half-wave
// shfl reduce). In place on QKV. 12288 blocks x 4 waves x 2 rows.
// ==========================================================================
__global__ __launch_bounds__(256) void prep_qkv(u16* __restrict__ QKV,
                                                const float* __restrict__ cosb,
                                                const float* __restrict__ sinb,
                                                const float* __restrict__ qw,
                                                const float* __restrict__ kw) {
    const int bx = blockIdx.x;
    const int tid = threadIdx.x;
    const int wave = tid >> 6, lane = tid & 63;
    const int half = lane >> 5, l5 = lane & 31;
    const int t = bx * 4 + wave;        // 0..49151
    const int R = t * 2 + half;         // row id (never straddles Q/K: 65536 even)
    u16* ptr;
    const float* w;
    float scale;
    int bs;
    if (R < 65536) {
        bs = R >> 4;
        ptr = QKV + (size_t)bs * 4096 + (R & 15) * 128;
        w = qw;
        scale = 0.08838834764831845f * 1.4426950408889634f;  // D^-0.5 * log2(e)
    } else {
        int R2 = R - 65536;
        bs = R2 >> 3;
        ptr = QKV + (size_t)bs * 4096 + 2048 + (R2 & 7) * 128;
        w = kw;
        scale = 1.0f;
    }
    const int d = l5 * 4;
    u64 xv = *(const u64*)(ptr + d);
    float x0 = bf2f((u16)xv), x1 = bf2f((u16)(xv >> 16));
    float x2 = bf2f((u16)(xv >> 32)), x3 = bf2f((u16)(xv >> 48));
    float ss = x0 * x0 + x1 * x1 + x2 * x2 + x3 * x3;
#pragma unroll
    for (int off = 1; off < 32; off <<= 1) ss += __shfl_xor(ss, off);
    float rn = rsqrtf(ss * (1.0f / 128.0f) + 1e-6f);
    float4 wv = *(const float4*)(w + d);
    float y0 = x0 * rn * wv.x, y1 = x1 * rn * wv.y;
    float y2 = x2 * rn * wv.z, y3 = x3 * rn * wv.w;
    // rotate_half partner: d^64 <-> lane l5^16 (same half)
    float p0 = __shfl_xor(y0, 16), p1 = __shfl_xor(y1, 16);
    float p2 = __shfl_xor(y2, 16), p3 = __shfl_xor(y3, 16);
    float sgn = (l5 < 16) ? -1.0f : 1.0f;
    float4 cv = *(const float4*)(cosb + (size_t)bs * 128 + d);
    float4 sv = *(const float4*)(sinb + (size_t)bs * 128 + d);
    float o0 = (y0 * cv.x + sgn * p0 * sv.x) * scale;
    float o1 = (y1 * cv.y + sgn * p1 * sv.y) * scale;
    float o2 = (y2 * cv.z + sgn * p2 * sv.z) * scale;
    float o3 = (y3 * cv.w + sgn * p3 * sv.w) * scale;
    u64 res = (u64)f2bf_pk(o0, o1) | ((u64)f2bf_pk(o2, o3) << 32);
    *(u64*)(ptr + d) = res;
}

// ==========================================================================
// Causal GQA flash attention, transposed-score formulation.
// QBLK=64 (4 waves, 256 thr), KVBLK=64.
// LDS 50KB: K double-buffered (32KB) + V single-buffered (16KB) + ones rows
// (2KB) so PV's jn=8 column accumulates l = sum(P) inside the MFMA.
// Counted-vmcnt barriers (T4). 3 blocks/CU = 12 waves/CU.
// Decode: r6 LPT (qt = 31 - id/32) — the empirically best of three decode
// variants (r6 85.6 / r7 115.7 / r8 110.9 µs); placement models failed to
// predict better, so this is pinned. T5 setprio, T13 defer-max.
// ==========================================================================
__global__ __launch_bounds__(256, 3) void attn_kernel(const u16* __restrict__ QKV,
                                                      const u16* __restrict__ Vt,
                                                      u16* __restrict__ O) {
    __shared__ __align__(16) u16 Ks[2][64 * 128];   // [key][d] swizzled, 32KB
    __shared__ __align__(16) u16 Vs[144 * 64];      // [d][key] swizzled + ones rows 128..143
    const int tid = threadIdx.x;
    const int wave = tid >> 6, lane = tid & 63;
    const int lr = lane & 15, lq = lane >> 4;

    // LPT decode: rank 0 = longest (qt=31)
    const int id = blockIdx.x;        // 0..1023
    const int qt = 31 - (id >> 5);
    const int j = id & 31;
    const int h = j & 15;
    const int b = j >> 4;

    const int kv = h >> 1;
    const int q0 = qt * 64;
    const int wq = wave * 16;

    // async stage of one 64-key K tile into buffer `buf` (4 instrs/wave)
    auto stageK = [&](int buf, int k0s) {
#pragma unroll
        for (int jj = 0; jj < 4; jj++) {   // Ks: 64 rows x 256 B
            int r = wave * 16 + jj * 4 + (lane >> 4);
            int ch = (lane & 15) ^ (r & 15);   // inverse-swizzled source chunk
            __builtin_amdgcn_global_load_lds(
                (const AS1 void*)(QKV + (size_t)(b * 2048 + k0s + r) * 4096 + 2048 + kv * 128 + ch * 8),
                (AS3 void*)(&Ks[buf][(wave * 16 + jj * 4) * 128]), 16, 0, 0);
        }
    };
    // async stage of the V tile (rows 0..127 only; ones rows untouched)
    auto stageV = [&](int k0s) {
#pragma unroll
        for (int jj = 0; jj < 4; jj++) {   // Vs: 128 rows x 128 B
            int r = wave * 32 + jj * 8 + (lane >> 3);
            int ch = (lane & 7) ^ (r & 7);
            __builtin_amdgcn_global_load_lds(
                (const AS1 void*)(Vt + (size_t)((b * 8 + kv) * 128 + r) * 2048 + k0s + ch * 8),
                (AS3 void*)(&Vs[(wave * 32 + jj * 8) * 64]), 16, 0, 0);
        }
    };

    // fill ones rows (128..143) once; any swizzled read sees 1.0
    *(u64*)(&Vs[128 * 64 + tid * 4]) = 0x3F803F803F803F80ULL;
    asm volatile("s_waitcnt lgkmcnt(0)" ::: "memory");

    // Q fragments in registers (B-operand: n=qrow on lr, k=d on lq*8+j)
    short8 qf[4];
#pragma unroll
    for (int t = 0; t < 4; t++)
        qf[t] = *(const short8*)(QKV + (size_t)(b * 2048 + q0 + wq + lr) * 4096 + h * 128 + t * 32 + lq * 8);

    floatx4 zf = {0.f, 0.f, 0.f, 0.f};
    floatx4 oacc[9];   // [8] = l column (ones rows of Vs)
#pragma unroll
    for (int jn = 0; jn < 9; jn++) oacc[jn] = zf;
    float mstate = -1e30f;

    const int nIter = qt + 1;

    stageK(0, 0);

    for (int kt = 0; kt < nIter; kt++) {
        const int k0 = kt * 64;
        const int cur = kt & 1;
        // barrier #1: own outstanding = K(kt) only -> vmcnt(0) is exact.
        asm volatile("s_waitcnt vmcnt(0)" ::: "memory");
        __builtin_amdgcn_s_barrier();
        stageV(k0);
        if (kt + 1 < nIter) stageK(cur ^ 1, k0 + 64);

        const bool active = (k0 <= q0 + wq + 15);
        u64 pb[4];
        if (active) {
            const u16* KsC = &Ks[cur][0];
            floatx4 sacc[4];
#pragma unroll
            for (int jm = 0; jm < 4; jm++) sacc[jm] = zf;
            __builtin_amdgcn_s_setprio(1);
#pragma unroll
            for (int t = 0; t < 4; t++) {
                short8 a[4];
#pragma unroll
                for (int jm = 0; jm < 4; jm++)
                    a[jm] = *(const short8*)(KsC + (jm * 16 + lr) * 128 + (((t * 4 + lq) ^ lr) << 3));
#pragma unroll
                for (int jm = 0; jm < 4; jm++)
                    sacc[jm] = __builtin_amdgcn_mfma_f32_16x16x32_bf16(a[jm], qf[t], sacc[jm], 0, 0, 0);
            }
            __builtin_amdgcn_s_setprio(0);

            if (k0 + 63 > q0 + wq) {
#pragma unroll
                for (int jm = 0; jm < 4; jm++) {
                    int diff = (q0 + wq + lr) - (k0 + jm * 16 + lq * 4);
#pragma unroll
                    for (int r = 0; r < 4; r++)
                        if (r > diff) sacc[jm][r] = -1e30f;
                }
            }

            // per-qrow max (tree within jm, then cross-quad)
            float mx = -1e30f;
#pragma unroll
            for (int jm = 0; jm < 4; jm++) {
                float a0 = fmaxf(sacc[jm][0], sacc[jm][1]);
                float a1 = fmaxf(sacc[jm][2], sacc[jm][3]);
                mx = fmaxf(mx, fmaxf(a0, a1));
            }
            mx = fmaxf(mx, __shfl_xor(mx, 16));
            mx = fmaxf(mx, __shfl_xor(mx, 32));

            // T13 defer-max: skip rescale when all rows grew <= 8 (log2 dom)
            bool defer = __all(mx - mstate <= 8.0f);
            float mnew = defer ? mstate : fmaxf(mstate, mx);

#pragma unroll
            for (int jm = 0; jm < 4; jm++)
#pragma unroll
                for (int r = 0; r < 4; r++)
                    sacc[jm][r] = exp2f(sacc[jm][r] - mnew);

            if (!defer) {
                float alpha = exp2f(mstate - mnew);
                mstate = mnew;
                float ao[4];
#pragma unroll
                for (int r = 0; r < 4; r++) ao[r] = __shfl(alpha, lq * 4 + r);
#pragma unroll
                for (int jn = 0; jn < 9; jn++)   // includes l column
#pragma unroll
                    for (int r = 0; r < 4; r++) oacc[jn][r] *= ao[r];
            }

#pragma unroll
            for (int jm = 0; jm < 4; jm++) {
                u32 lo = f2bf_pk(sacc[jm][0], sacc[jm][1]);
                u32 hi = f2bf_pk(sacc[jm][2], sacc[jm][3]);
                pb[jm] = (u64)lo | ((u64)hi << 32);
            }
        }

        // barrier #2: wait ONLY the V loads (first 4 in own queue);
        // K(kt+1) (4 newer loads) stays in flight across PV + next barrier.
        if (kt + 1 < nIter) asm volatile("s_waitcnt vmcnt(4)" ::: "memory");
        else                asm volatile("s_waitcnt vmcnt(0)" ::: "memory");
        __builtin_amdgcn_s_barrier();

        if (active) {
            // O += P @ [V | 1]; jn=8 accumulates l per qrow inside MFMA.
            __builtin_amdgcn_s_setprio(1);
#pragma unroll
            for (int t = 0; t < 2; t++) {
                union { short8 v; u64 q[2]; } pa;
                pa.q[0] = pb[2 * t];
                pa.q[1] = pb[2 * t + 1];
#pragma unroll
                for (int jn = 0; jn < 9; jn++) {
                    const u16* vrow = Vs + (jn * 16 + lr) * 64 + (lq & 1) * 4;
                    union { short8 v; u64 q[2]; } vb;
                    vb.q[0] = *(const u64*)(vrow + (((t * 4 + (lq >> 1)) ^ (lr & 7)) << 3));
                    vb.q[1] = *(const u64*)(vrow + (((t * 4 + 2 + (lq >> 1)) ^ (lr & 7)) << 3));
                    oacc[jn] = __builtin_amdgcn_mfma_f32_16x16x32_bf16(pa.v, vb.v, oacc[jn], 0, 0, 0);
                }
            }
            __builtin_amdgcn_s_setprio(0);
        }
    }

    // epilogue: l already at the right lanes (oacc[8][r], qrow = lq*4+r)
#pragma unroll
    for (int jn = 0; jn < 8; jn++)
#pragma unroll
        for (int r = 0; r < 4; r++) {
            int row = q0 + wq + lq * 4 + r;
            O[(size_t)(b * 2048 + row) * 2048 + h * 128 + jn * 16 + lr] =
                f2bf(oacc[jn][r] / oacc[8][r]);
        }
}

// ==========================================================================
extern "C" void kernel_launch(void* const* d_in, const int* in_sizes, int n_in,
                              void* d_out, int out_size, void* d_ws, size_t ws_size,
                              hipStream_t stream) {
    const float* X = (const float*)d_in[0];
    const float* cosb = (const float*)d_in[1];
    const float* sinb = (const float*)d_in[2];
    const float* Wq = (const float*)d_in[3];
    const float* Wk = (const float*)d_in[4];
    const float* Wv = (const float*)d_in[5];
    const float* Wo = (const float*)d_in[6];
    const float* qw = (const float*)d_in[7];
    const float* kw = (const float*)d_in[8];
    float* out = (float*)d_out;
    u16* ws = (u16*)d_ws;

    u16* WqkvT = ws;                    // 4096x2048 = 8388608
    u16* WoT = WqkvT + 8388608;         // 4194304
    u16* Xb = WoT + 4194304;            // 8388608 (dead after QKV GEMM)
    u16* QKVb = Xb + 8388608;           // 4096x4096 = 16777216
    u16* Vtb = QKVb + 16777216;         // 4194304
    u16* Ob = Xb;                       // alias
    // total 41,943,040 u16 = 83.9 MB

    prep_weights<<<dim3(32, 32, 5), dim3(32, 8), 0, stream>>>(Wq, Wk, Wv, Wo, X,
                                                              WqkvT, WoT, Xb);

    gemm256<u16, true><<<dim3(16, 16), 512, 0, stream>>>(Xb, WqkvT, QKVb, Vtb,
                                                         4096, 4096, 2048);

    prep_qkv<<<12288, 256, 0, stream>>>(QKVb, cosb, sinb, qw, kw);

    attn_kernel<<<1024, 256, 0, stream>>>(QKVb, Vtb, Ob);

    gemm128n<float><<<dim3(16, 16), 512, 0, stream>>>(Ob, WoT, out, 4096, 2048, 2048);
}

// Round 12
// 330.303 us; speedup vs baseline: 1.1906x; 1.0357x over previous
//
#include <hip/hip_runtime.h>
#include <hip/hip_bf16.h>

typedef unsigned short u16;
typedef unsigned int u32;
typedef unsigned long long u64;
typedef __attribute__((ext_vector_type(8))) short short8;
typedef __attribute__((ext_vector_type(4))) float floatx4;

#define AS1 __attribute__((address_space(1)))
#define AS3 __attribute__((address_space(3)))

// ---- bf16 <-> f32 helpers (raw bits, RNE) ----
__device__ __forceinline__ float bf2f(u16 u) {
    u32 x = ((u32)u) << 16;
    float f;
    __builtin_memcpy(&f, &x, 4);
    return f;
}
__device__ __forceinline__ u16 f2bf(float f) {
    u32 x;
    __builtin_memcpy(&x, &f, 4);
    u32 r = (x + 0x7fffu + ((x >> 16) & 1u)) >> 16;
    return (u16)r;
}
// packed 2xf32 -> 2xbf16 (v_cvt_pk_bf16_f32), returned as u32 (lo=first)
__device__ __forceinline__ u32 f2bf_pk(float a, float b) {
    __hip_bfloat162 h = __float22bfloat162_rn(float2{a, b});
    u32 r;
    __builtin_memcpy(&r, &h, 4);
    return r;
}

// ==========================================================================
// Merged prep: z<4 = weight transposes (f32 RxC -> bf16 CxR), z=4 = X cast.
// 64x64 tiles, 2x2 micro-tile/thread: float2 reads (8B/lane), u32 packed
// writes (128B/wave segments). Block = dim3(32,8) — 2D indexing required.
// ==========================================================================
__global__ __launch_bounds__(256) void prep_weights(const float* __restrict__ Wq,
                                                    const float* __restrict__ Wk,
                                                    const float* __restrict__ Wv,
                                                    const float* __restrict__ Wo,
                                                    const float* __restrict__ X,
                                                    u16* __restrict__ WqkvT,
                                                    u16* __restrict__ WoT,
                                                    u16* __restrict__ Xb) {
    const int z = blockIdx.z;
    const int tx = threadIdx.x, ty = threadIdx.y;   // 32 x 8
    if (z == 4) {  // X cast: 1024 blocks x 256 thr x 8 float4 = 8.39M f32
        int tid = ty * 32 + tx;
        int idx = blockIdx.y * 32 + blockIdx.x;     // 0..1023
        if (idx >= 1024) return;
        size_t base = (size_t)idx * 256 + tid;
#pragma unroll
        for (int p = 0; p < 8; p++) {
            size_t i = (base + (size_t)p * 262144) * 4;
            float4 v = *(const float4*)(X + i);
            u16 o[4] = {f2bf(v.x), f2bf(v.y), f2bf(v.z), f2bf(v.w)};
            *(u64*)(Xb + i) = *(u64*)o;
        }
        return;
    }
    const float* in;
    u16* out;
    int C;
    if (z == 0) { in = Wq; out = WqkvT; C = 2048; }
    else if (z == 1) { in = Wk; out = WqkvT + 2048 * 2048; C = 1024; }
    else if (z == 2) { in = Wv; out = WqkvT + 3072 * 2048; C = 1024; }
    else { in = Wo; out = WoT; C = 2048; }
    const int c0 = blockIdx.x * 64, r0 = blockIdx.y * 64;
    if (c0 >= C) return;
    __shared__ u16 t[64][66];
#pragma unroll
    for (int p = 0; p < 4; p++) {
        int rr = (ty + 8 * p) * 2;
#pragma unroll
        for (int i = 0; i < 2; i++) {
            float2 v = *(const float2*)(in + (size_t)(r0 + rr + i) * C + c0 + tx * 2);
            *(u32*)&t[rr + i][tx * 2] = f2bf_pk(v.x, v.y);
        }
    }
    __syncthreads();
#pragma unroll
    for (int p = 0; p < 4; p++) {
        int cc = (ty + 8 * p) * 2;
        u32 a = *(const u32*)&t[tx * 2][cc];       // r=2tx : (col cc | col cc+1)
        u32 bq = *(const u32*)&t[tx * 2 + 1][cc];  // r=2tx+1
        u32 pk0 = (a & 0xffffu) | (bq << 16);            // col cc, rows 2tx,2tx+1
        u32 pk1 = (a >> 16) | (bq & 0xffff0000u);        // col cc+1
        *(u32*)(out + (size_t)(c0 + cc) * 2048 + r0 + tx * 2) = pk0;
        *(u32*)(out + (size_t)(c0 + cc + 1) * 2048 + r0 + tx * 2) = pk1;
    }
}

// ==========================================================================
// GEMM: C[M,N] = A[M,K] @ Bt[N,K]^T (bf16 in, fp32 acc, OUT_T out)
// 256x256 tile, BK=64, 512 thr (8 waves 2Mx4N), 8-phase-per-2-K-tiles
// schedule: counted vmcnt(6), raw s_barrier, XOR-swizzled LDS, setprio.
// FUSEV (QKV instantiation only): blocks with n0>=3072 hold the V columns;
// epilogue writes them transposed straight to Vt (b,kv,d,s) as packed u64.
// ==========================================================================
template <typename OUT_T, bool FUSEV>
__global__ __launch_bounds__(512, 2) void gemm256(const u16* __restrict__ A,
                                                  const u16* __restrict__ Bt,
                                                  OUT_T* __restrict__ C,
                                                  u16* __restrict__ Vt,
                                                  int M, int N, int K) {
    (void)M;
    __shared__ __align__(16) u16 lds[2][2][2][128 * 64];  // [buf][A/B][half][r*64+c]
    const int tid = threadIdx.x;
    const int wave = tid >> 6, lane = tid & 63;
    const int lr = lane & 15, lq = lane >> 4;
    const int wm = wave >> 2, wn = wave & 3;
    const int m0 = blockIdx.y * 256, n0 = blockIdx.x * 256;

    const int srow = lane >> 3;                    // 0..7 within 8-row group
    const int schunk = ((lane & 7) ^ srow) << 3;   // source chunk (elems)
    const int slot = wave << 1;

    auto stage = [&](const u16* src, int rbase, int buf, int mat, int half, int k0) {
#pragma unroll
        for (int j = 0; j < 2; j++) {
            int r = rbase + half * 128 + (slot + j) * 8 + srow;
            __builtin_amdgcn_global_load_lds(
                (const AS1 void*)(src + (size_t)r * K + k0 + schunk),
                (AS3 void*)(&lds[buf][mat][half][(slot + j) * 512]), 16, 0, 0);
        }
    };

    floatx4 zf = {0.f, 0.f, 0.f, 0.f};
    floatx4 acc[8][4];
#pragma unroll
    for (int i = 0; i < 8; i++)
#pragma unroll
        for (int jn = 0; jn < 4; jn++) acc[i][jn] = zf;

    const int NT = K >> 6;

    stage(Bt, n0, 0, 1, 0, 0);
    stage(Bt, n0, 0, 1, 1, 0);
    stage(A, m0, 0, 0, 0, 0);
    stage(A, m0, 0, 0, 1, 0);
    if (NT > 1) {
        stage(Bt, n0, 1, 1, 0, 64);
        stage(Bt, n0, 1, 1, 1, 64);
        stage(A, m0, 1, 0, 0, 64);
        asm volatile("s_waitcnt vmcnt(6)" ::: "memory");
    } else {
        asm volatile("s_waitcnt vmcnt(0)" ::: "memory");
    }
    __builtin_amdgcn_s_barrier();

    for (int kt = 0; kt < NT; kt++) {
        const int b = kt & 1;
        const u16* Ab = &lds[b][0][wm][0];
        const u16* Bb = &lds[b][1][wn >> 1][0];
        const int brow = (wn & 1) * 64;
        const int sx = lr & 7;
        const int nk = (kt + 2) << 6;

        // ---- phase 0 ----
        short8 bf0[4], bf1[4], af[4];
#pragma unroll
        for (int jn = 0; jn < 4; jn++) {
            int rh = brow + jn * 16 + lr;
            bf0[jn] = *(const short8*)(Bb + rh * 64 + ((lq ^ sx) << 3));
            bf1[jn] = *(const short8*)(Bb + rh * 64 + (((4 + lq) ^ sx) << 3));
        }
#pragma unroll
        for (int i = 0; i < 4; i++)
            af[i] = *(const short8*)(Ab + (i * 16 + lr) * 64 + ((lq ^ sx) << 3));
        if (kt + 1 < NT) stage(A, m0, b ^ 1, 0, 1, (kt + 1) << 6);
        __builtin_amdgcn_s_barrier();
        asm volatile("s_waitcnt lgkmcnt(0)" ::: "memory");
        __builtin_amdgcn_sched_barrier(0);
        __builtin_amdgcn_s_setprio(1);
#pragma unroll
        for (int i = 0; i < 4; i++)
#pragma unroll
            for (int jn = 0; jn < 4; jn++)
                acc[i][jn] = __builtin_amdgcn_mfma_f32_16x16x32_bf16(af[i], bf0[jn], acc[i][jn], 0, 0, 0);
        __builtin_amdgcn_s_setprio(0);
        __builtin_amdgcn_s_barrier();

        // ---- phase 1 ----
        short8 ag[4];
#pragma unroll
        for (int i = 0; i < 4; i++)
            ag[i] = *(const short8*)(Ab + ((i + 4) * 16 + lr) * 64 + ((lq ^ sx) << 3));
        if (kt + 2 < NT) stage(Bt, n0, b, 1, 0, nk);
        __builtin_amdgcn_s_barrier();
        asm volatile("s_waitcnt lgkmcnt(0)" ::: "memory");
        __builtin_amdgcn_sched_barrier(0);
        __builtin_amdgcn_s_setprio(1);
#pragma unroll
        for (int i = 0; i < 4; i++)
#pragma unroll
            for (int jn = 0; jn < 4; jn++)
                acc[i + 4][jn] = __builtin_amdgcn_mfma_f32_16x16x32_bf16(ag[i], bf0[jn], acc[i + 4][jn], 0, 0, 0);
        __builtin_amdgcn_s_setprio(0);
        __builtin_amdgcn_s_barrier();

        // ---- phase 2 ----
        short8 c0[4], c1[4];
#pragma unroll
        for (int i = 0; i < 4; i++) {
            c0[i] = *(const short8*)(Ab + (i * 16 + lr) * 64 + (((4 + lq) ^ sx) << 3));
            c1[i] = *(const short8*)(Ab + ((i + 4) * 16 + lr) * 64 + (((4 + lq) ^ sx) << 3));
        }
        if (kt + 2 < NT) stage(Bt, n0, b, 1, 1, nk);
        __builtin_amdgcn_s_barrier();
        asm volatile("s_waitcnt lgkmcnt(0)" ::: "memory");
        __builtin_amdgcn_sched_barrier(0);
        __builtin_amdgcn_s_setprio(1);
#pragma unroll
        for (int i = 0; i < 4; i++)
#pragma unroll
            for (int jn = 0; jn < 4; jn++)
                acc[i][jn] = __builtin_amdgcn_mfma_f32_16x16x32_bf16(c0[i], bf1[jn], acc[i][jn], 0, 0, 0);
        __builtin_amdgcn_s_setprio(0);
        __builtin_amdgcn_s_barrier();

        // ---- phase 3 ----
        if (kt + 2 < NT) stage(A, m0, b, 0, 0, nk);
        __builtin_amdgcn_s_barrier();
        __builtin_amdgcn_s_setprio(1);
#pragma unroll
        for (int i = 0; i < 4; i++)
#pragma unroll
            for (int jn = 0; jn < 4; jn++)
                acc[i + 4][jn] = __builtin_amdgcn_mfma_f32_16x16x32_bf16(c1[i], bf1[jn], acc[i + 4][jn], 0, 0, 0);
        __builtin_amdgcn_s_setprio(0);
        if (kt + 2 < NT) asm volatile("s_waitcnt vmcnt(6)" ::: "memory");
        else asm volatile("s_waitcnt vmcnt(0)" ::: "memory");
        __builtin_amdgcn_s_barrier();
    }

    if (FUSEV && n0 >= 3072) {
        // V columns -> Vt (b,kv,d,s), packed 4-consecutive-s u64 stores.
        const int bb = m0 >> 11;            // batch (256-row tile never straddles)
        const int sbase = (m0 & 2047) + wm * 128 + lq * 4;
#pragma unroll
        for (int i = 0; i < 8; i++)
#pragma unroll
            for (int jn = 0; jn < 4; jn++) {
                int dcol = (n0 - 3072) + wn * 64 + jn * 16 + lr;  // 0..1023
                int kv = dcol >> 7, d = dcol & 127;
                u16 o[4] = {f2bf(acc[i][jn][0]), f2bf(acc[i][jn][1]),
                            f2bf(acc[i][jn][2]), f2bf(acc[i][jn][3])};
                *(u64*)(Vt + (size_t)((bb * 8 + kv) * 128 + d) * 2048 +
                        sbase + i * 16) = *(u64*)o;
            }
        return;
    }

#pragma unroll
    for (int i = 0; i < 8; i++)
#pragma unroll
        for (int jn = 0; jn < 4; jn++)
#pragma unroll
            for (int r = 0; r < 4; r++) {
                int row = m0 + wm * 128 + i * 16 + lq * 4 + r;
                int col = n0 + wn * 64 + jn * 16 + lr;
                if constexpr (sizeof(OUT_T) == 2)
                    C[(size_t)row * N + col] = f2bf(acc[i][jn][r]);
                else
                    C[(size_t)row * N + col] = acc[i][jn][r];
            }
}

// ==========================================================================
// GEMM: BM=256 x BN=128, BK=64, 512 thr = 8 waves (4M x 2N), 64x64/wave.
// Same 8-phase counted-vmcnt schedule; 3 stage-units/tile -> vmcnt(4).
// Grid (N/128, M/256) -> 256 blocks for the Wo GEMM (full GPU).
// ==========================================================================
template <typename OUT_T>
__global__ __launch_bounds__(512, 2) void gemm128n(const u16* __restrict__ A,
                                                   const u16* __restrict__ Bt,
                                                   OUT_T* __restrict__ C,
                                                   int M, int N, int K) {
    (void)M;
    __shared__ __align__(16) u16 Abuf[2][2][128 * 64];  // [buf][half][r*64+c]
    __shared__ __align__(16) u16 Bbuf[2][128 * 64];     // [buf][r*64+c]
    const int tid = threadIdx.x;
    const int wave = tid >> 6, lane = tid & 63;
    const int lr = lane & 15, lq = lane >> 4;
    const int wm = wave >> 1, wn = wave & 1;
    const int m0 = blockIdx.y * 256, n0 = blockIdx.x * 128;

    const int srow = lane >> 3;
    const int schunk = ((lane & 7) ^ srow) << 3;
    const int slot = wave << 1;

    auto stage = [&](const u16* src, int rowbase, u16* ldsbase, int k0) {
#pragma unroll
        for (int j = 0; j < 2; j++) {
            int r = rowbase + (slot + j) * 8 + srow;
            __builtin_amdgcn_global_load_lds(
                (const AS1 void*)(src + (size_t)r * K + k0 + schunk),
                (AS3 void*)(ldsbase + (slot + j) * 512), 16, 0, 0);
        }
    };

    floatx4 zf = {0.f, 0.f, 0.f, 0.f};
    floatx4 acc[4][4];
#pragma unroll
    for (int i = 0; i < 4; i++)
#pragma unroll
        for (int jn = 0; jn < 4; jn++) acc[i][jn] = zf;

    const int NT = K >> 6;

    // prologue: t0 = {Ah0, Ah1, B}; t1 = {Ah0, B} (Ah1(t1) comes in t0.ph0)
    stage(A, m0, &Abuf[0][0][0], 0);
    stage(A, m0 + 128, &Abuf[0][1][0], 0);
    stage(Bt, n0, &Bbuf[0][0], 0);
    if (NT > 1) {
        stage(A, m0, &Abuf[1][0][0], 64);
        stage(Bt, n0, &Bbuf[1][0], 64);
        asm volatile("s_waitcnt vmcnt(4)" ::: "memory");
    } else {
        asm volatile("s_waitcnt vmcnt(0)" ::: "memory");
    }
    __builtin_amdgcn_s_barrier();

    for (int kt = 0; kt < NT; kt++) {
        const int b = kt & 1;
        const u16* Ab = &Abuf[b][wm >> 1][0];
        const u16* Bb = &Bbuf[b][0];
        const int ar = (wm & 1) * 64;
        const int br = wn * 64;
        const int sx = lr & 7;
        const int nk = (kt + 2) << 6;

        // ---- phase 0: read bf0,bf1,af(kk0); stage Ah1(kt+1); mfma kk0 i0-1 ----
        short8 bf0[4], bf1[4], af[4];
#pragma unroll
        for (int jn = 0; jn < 4; jn++) {
            int rh = br + jn * 16 + lr;
            bf0[jn] = *(const short8*)(Bb + rh * 64 + ((lq ^ sx) << 3));
            bf1[jn] = *(const short8*)(Bb + rh * 64 + (((4 + lq) ^ sx) << 3));
        }
#pragma unroll
        for (int i = 0; i < 4; i++)
            af[i] = *(const short8*)(Ab + (ar + i * 16 + lr) * 64 + ((lq ^ sx) << 3));
        if (kt + 1 < NT) stage(A, m0 + 128, &Abuf[b ^ 1][1][0], (kt + 1) << 6);
        __builtin_amdgcn_s_barrier();
        asm volatile("s_waitcnt lgkmcnt(0)" ::: "memory");
        __builtin_amdgcn_sched_barrier(0);
        __builtin_amdgcn_s_setprio(1);
#pragma unroll
        for (int i = 0; i < 2; i++)
#pragma unroll
            for (int jn = 0; jn < 4; jn++)
                acc[i][jn] = __builtin_amdgcn_mfma_f32_16x16x32_bf16(af[i], bf0[jn], acc[i][jn], 0, 0, 0);
        __builtin_amdgcn_s_setprio(0);
        __builtin_amdgcn_s_barrier();

        // ---- phase 1: stage B(kt+2); mfma kk0 i2-3 ----
        if (kt + 2 < NT) stage(Bt, n0, &Bbuf[b][0], nk);
        __builtin_amdgcn_s_barrier();
        __builtin_amdgcn_s_setprio(1);
#pragma unroll
        for (int i = 2; i < 4; i++)
#pragma unroll
            for (int jn = 0; jn < 4; jn++)
                acc[i][jn] = __builtin_amdgcn_mfma_f32_16x16x32_bf16(af[i], bf0[jn], acc[i][jn], 0, 0, 0);
        __builtin_amdgcn_s_setprio(0);
        __builtin_amdgcn_s_barrier();

        // ---- phase 2: read ag(kk1); mfma kk1 i0-1 ----
        short8 ag[4];
#pragma unroll
        for (int i = 0; i < 4; i++)
            ag[i] = *(const short8*)(Ab + (ar + i * 16 + lr) * 64 + (((4 + lq) ^ sx) << 3));
        __builtin_amdgcn_s_barrier();
        asm volatile("s_waitcnt lgkmcnt(0)" ::: "memory");
        __builtin_amdgcn_sched_barrier(0);
        __builtin_amdgcn_s_setprio(1);
#pragma unroll
        for (int i = 0; i < 2; i++)
#pragma unroll
            for (int jn = 0; jn < 4; jn++)
                acc[i][jn] = __builtin_amdgcn_mfma_f32_16x16x32_bf16(ag[i], bf1[jn], acc[i][jn], 0, 0, 0);
        __builtin_amdgcn_s_setprio(0);
        __builtin_amdgcn_s_barrier();

        // ---- phase 3: stage Ah0(kt+2); mfma kk1 i2-3; counted vmcnt ----
        if (kt + 2 < NT) stage(A, m0, &Abuf[b][0][0], nk);
        __builtin_amdgcn_s_barrier();
        __builtin_amdgcn_s_setprio(1);
#pragma unroll
        for (int i = 2; i < 4; i++)
#pragma unroll
            for (int jn = 0; jn < 4; jn++)
                acc[i][jn] = __builtin_amdgcn_mfma_f32_16x16x32_bf16(ag[i], bf1[jn], acc[i][jn], 0, 0, 0);
        __builtin_amdgcn_s_setprio(0);
        if (kt + 2 < NT) asm volatile("s_waitcnt vmcnt(4)" ::: "memory");
        else asm volatile("s_waitcnt vmcnt(0)" ::: "memory");
        __builtin_amdgcn_s_barrier();
    }

#pragma unroll
    for (int i = 0; i < 4; i++)
#pragma unroll
        for (int jn = 0; jn < 4; jn++)
#pragma unroll
            for (int r = 0; r < 4; r++) {
                int row = m0 + wm * 64 + i * 16 + lq * 4 + r;
                int col = n0 + wn * 64 + jn * 16 + lr;
                if constexpr (sizeof(OUT_T) == 2)
                    C[(size_t)row * N + col] = f2bf(acc[i][jn][r]);
                else
                    C[(size_t)row * N + col] = acc[i][jn][r];
            }
}

// ==========================================================================
// RMS-norm + RoPE only (V transpose fused into gemm256 epilogue).
// 2 head-rows per wave (u64 = 8B/lane loads, float4 w/cos/sin, half-wave
// shfl reduce). In place on QKV. 12288 blocks x 4 waves x 2 rows.
// ==========================================================================
__global__ __launch_bounds__(256) void prep_qkv(u16* __restrict__ QKV,
                                                const float* __restrict__ cosb,
                                                const float* __restrict__ sinb,
                                                const float* __restrict__ qw,
                                                const float* __restrict__ kw) {
    const int bx = blockIdx.x;
    const int tid = threadIdx.x;
    const int wave = tid >> 6, lane = tid & 63;
    const int half = lane >> 5, l5 = lane & 31;
    const int t = bx * 4 + wave;        // 0..49151
    const int R = t * 2 + half;         // row id (never straddles Q/K: 65536 even)
    u16* ptr;
    const float* w;
    float scale;
    int bs;
    if (R < 65536) {
        bs = R >> 4;
        ptr = QKV + (size_t)bs * 4096 + (R & 15) * 128;
        w = qw;
        scale = 0.08838834764831845f * 1.4426950408889634f;  // D^-0.5 * log2(e)
    } else {
        int R2 = R - 65536;
        bs = R2 >> 3;
        ptr = QKV + (size_t)bs * 4096 + 2048 + (R2 & 7) * 128;
        w = kw;
        scale = 1.0f;
    }
    const int d = l5 * 4;
    u64 xv = *(const u64*)(ptr + d);
    float x0 = bf2f((u16)xv), x1 = bf2f((u16)(xv >> 16));
    float x2 = bf2f((u16)(xv >> 32)), x3 = bf2f((u16)(xv >> 48));
    float ss = x0 * x0 + x1 * x1 + x2 * x2 + x3 * x3;
#pragma unroll
    for (int off = 1; off < 32; off <<= 1) ss += __shfl_xor(ss, off);
    float rn = rsqrtf(ss * (1.0f / 128.0f) + 1e-6f);
    float4 wv = *(const float4*)(w + d);
    float y0 = x0 * rn * wv.x, y1 = x1 * rn * wv.y;
    float y2 = x2 * rn * wv.z, y3 = x3 * rn * wv.w;
    // rotate_half partner: d^64 <-> lane l5^16 (same half)
    float p0 = __shfl_xor(y0, 16), p1 = __shfl_xor(y1, 16);
    float p2 = __shfl_xor(y2, 16), p3 = __shfl_xor(y3, 16);
    float sgn = (l5 < 16) ? -1.0f : 1.0f;
    float4 cv = *(const float4*)(cosb + (size_t)bs * 128 + d);
    float4 sv = *(const float4*)(sinb + (size_t)bs * 128 + d);
    float o0 = (y0 * cv.x + sgn * p0 * sv.x) * scale;
    float o1 = (y1 * cv.y + sgn * p1 * sv.y) * scale;
    float o2 = (y2 * cv.z + sgn * p2 * sv.z) * scale;
    float o3 = (y3 * cv.w + sgn * p3 * sv.w) * scale;
    u64 res = (u64)f2bf_pk(o0, o1) | ((u64)f2bf_pk(o2, o3) << 32);
    *(u64*)(ptr + d) = res;
}

// ==========================================================================
// Causal GQA flash attention, transposed-score formulation.
// QBLK=64 (4 waves, 256 thr), KVBLK=64.
// PADDED-GROUP LDS (r12): 16B pad after each 1KB staging group (one
// global_load_lds wave-write). Ks: 4-row groups (520 u16), Vs: 8-row
// groups (520 u16). DMA dests stay contiguous per instruction; row groups
// start at bank offset 4g mod 32 -> QK-read bank = 4*((row>>2)+chunk),
// breaking the lr/lr^8 8-way degeneracy of the unpadded layout (9.2M
// conflicts/dispatch). LDS 52000B -> still 3 blocks/CU.
// K double-buffered + V single-buffered + ones rows (l via jn=8 MFMA col).
// Counted-vmcnt barriers (T4); r6 LPT decode (pinned, measured-best);
// T5 setprio, T13 defer-max.
// ==========================================================================
__global__ __launch_bounds__(256, 3) void attn_kernel(const u16* __restrict__ QKV,
                                                      const u16* __restrict__ Vt,
                                                      u16* __restrict__ O) {
    // Ks: 16 groups x (4 rows x 128 u16 + 8 pad) = 8320 u16 per buffer
    __shared__ __align__(16) u16 Ks[2][16 * 520];
    // Vs: 18 groups x (8 rows x 64 u16 + 8 pad); groups 16-17 = ones rows
    __shared__ __align__(16) u16 Vs[18 * 520];
    const int tid = threadIdx.x;
    const int wave = tid >> 6, lane = tid & 63;
    const int lr = lane & 15, lq = lane >> 4;

    // LPT decode: rank 0 = longest (qt=31)
    const int id = blockIdx.x;        // 0..1023
    const int qt = 31 - (id >> 5);
    const int j = id & 31;
    const int h = j & 15;
    const int b = j >> 4;

    const int kv = h >> 1;
    const int q0 = qt * 64;
    const int wq = wave * 16;

    // async stage of one 64-key K tile into buffer `buf` (4 instrs/wave)
    auto stageK = [&](int buf, int k0s) {
#pragma unroll
        for (int jj = 0; jj < 4; jj++) {   // group = 4 rows x 256 B
            int r = wave * 16 + jj * 4 + (lane >> 4);
            int ch = (lane & 15) ^ (r & 15);   // inverse-swizzled source chunk
            __builtin_amdgcn_global_load_lds(
                (const AS1 void*)(QKV + (size_t)(b * 2048 + k0s + r) * 4096 + 2048 + kv * 128 + ch * 8),
                (AS3 void*)(&Ks[buf][(wave * 4 + jj) * 520]), 16, 0, 0);
        }
    };
    // async stage of the V tile (rows 0..127 only; ones groups untouched)
    auto stageV = [&](int k0s) {
#pragma unroll
        for (int jj = 0; jj < 4; jj++) {   // group = 8 rows x 128 B
            int r = wave * 32 + jj * 8 + (lane >> 3);
            int ch = (lane & 7) ^ (r & 7);
            __builtin_amdgcn_global_load_lds(
                (const AS1 void*)(Vt + (size_t)((b * 8 + kv) * 128 + r) * 2048 + k0s + ch * 8),
                (AS3 void*)(&Vs[(wave * 4 + jj) * 520]), 16, 0, 0);
        }
    };

    // fill ones groups 16-17 (u16 [8320, 9360)) once; pads harmless
#pragma unroll
    for (int k = tid; k < 260; k += 256)
        *(u64*)(&Vs[8320 + k * 4]) = 0x3F803F803F803F80ULL;
    asm volatile("s_waitcnt lgkmcnt(0)" ::: "memory");

    // Q fragments in registers (B-operand: n=qrow on lr, k=d on lq*8+j)
    short8 qf[4];
#pragma unroll
    for (int t = 0; t < 4; t++)
        qf[t] = *(const short8*)(QKV + (size_t)(b * 2048 + q0 + wq + lr) * 4096 + h * 128 + t * 32 + lq * 8);

    floatx4 zf = {0.f, 0.f, 0.f, 0.f};
    floatx4 oacc[9];   // [8] = l column (ones groups of Vs)
#pragma unroll
    for (int jn = 0; jn < 9; jn++) oacc[jn] = zf;
    float mstate = -1e30f;

    const int nIter = qt + 1;

    stageK(0, 0);

    for (int kt = 0; kt < nIter; kt++) {
        const int k0 = kt * 64;
        const int cur = kt & 1;
        // barrier #1: own outstanding = K(kt) only -> vmcnt(0) is exact.
        asm volatile("s_waitcnt vmcnt(0)" ::: "memory");
        __builtin_amdgcn_s_barrier();
        stageV(k0);
        if (kt + 1 < nIter) stageK(cur ^ 1, k0 + 64);

        const bool active = (k0 <= q0 + wq + 15);
        u64 pb[4];
        if (active) {
            const u16* KsC = &Ks[cur][0];
            floatx4 sacc[4];
#pragma unroll
            for (int jm = 0; jm < 4; jm++) sacc[jm] = zf;
            __builtin_amdgcn_s_setprio(1);
#pragma unroll
            for (int t = 0; t < 4; t++) {
                short8 a[4];
#pragma unroll
                for (int jm = 0; jm < 4; jm++) {
                    // row = jm*16+lr: group = jm*4+(lr>>2), in-group row = lr&3
                    int off = (jm * 4 + (lr >> 2)) * 520 + (lr & 3) * 128 +
                              (((t * 4 + lq) ^ lr) << 3);
                    a[jm] = *(const short8*)(KsC + off);
                }
#pragma unroll
                for (int jm = 0; jm < 4; jm++)
                    sacc[jm] = __builtin_amdgcn_mfma_f32_16x16x32_bf16(a[jm], qf[t], sacc[jm], 0, 0, 0);
            }
            __builtin_amdgcn_s_setprio(0);

            if (k0 + 63 > q0 + wq) {
#pragma unroll
                for (int jm = 0; jm < 4; jm++) {
                    int diff = (q0 + wq + lr) - (k0 + jm * 16 + lq * 4);
#pragma unroll
                    for (int r = 0; r < 4; r++)
                        if (r > diff) sacc[jm][r] = -1e30f;
                }
            }

            // per-qrow max (tree within jm, then cross-quad)
            float mx = -1e30f;
#pragma unroll
            for (int jm = 0; jm < 4; jm++) {
                float a0 = fmaxf(sacc[jm][0], sacc[jm][1]);
                float a1 = fmaxf(sacc[jm][2], sacc[jm][3]);
                mx = fmaxf(mx, fmaxf(a0, a1));
            }
            mx = fmaxf(mx, __shfl_xor(mx, 16));
            mx = fmaxf(mx, __shfl_xor(mx, 32));

            // T13 defer-max: skip rescale when all rows grew <= 8 (log2 dom)
            bool defer = __all(mx - mstate <= 8.0f);
            float mnew = defer ? mstate : fmaxf(mstate, mx);

#pragma unroll
            for (int jm = 0; jm < 4; jm++)
#pragma unroll
                for (int r = 0; r < 4; r++)
                    sacc[jm][r] = exp2f(sacc[jm][r] - mnew);

            if (!defer) {
                float alpha = exp2f(mstate - mnew);
                mstate = mnew;
                float ao[4];
#pragma unroll
                for (int r = 0; r < 4; r++) ao[r] = __shfl(alpha, lq * 4 + r);
#pragma unroll
                for (int jn = 0; jn < 9; jn++)   // includes l column
#pragma unroll
                    for (int r = 0; r < 4; r++) oacc[jn][r] *= ao[r];
            }

#pragma unroll
            for (int jm = 0; jm < 4; jm++) {
                u32 lo = f2bf_pk(sacc[jm][0], sacc[jm][1]);
                u32 hi = f2bf_pk(sacc[jm][2], sacc[jm][3]);
                pb[jm] = (u64)lo | ((u64)hi << 32);
            }
        }

        // barrier #2: wait ONLY the V loads (first 4 in own queue);
        // K(kt+1) (4 newer loads) stays in flight across PV + next barrier.
        if (kt + 1 < nIter) asm volatile("s_waitcnt vmcnt(4)" ::: "memory");
        else                asm volatile("s_waitcnt vmcnt(0)" ::: "memory");
        __builtin_amdgcn_s_barrier();

        if (active) {
            // O += P @ [V | 1]; jn=8 accumulates l per qrow inside MFMA.
            __builtin_amdgcn_s_setprio(1);
#pragma unroll
            for (int t = 0; t < 2; t++) {
                union { short8 v; u64 q[2]; } pa;
                pa.q[0] = pb[2 * t];
                pa.q[1] = pb[2 * t + 1];
#pragma unroll
                for (int jn = 0; jn < 9; jn++) {
                    // row = jn*16+lr: group = jn*2+(lr>>3), in-group row = lr&7
                    const u16* vrow = Vs + (jn * 2 + (lr >> 3)) * 520 +
                                      (lr & 7) * 64 + (lq & 1) * 4;
                    union { short8 v; u64 q[2]; } vb;
                    vb.q[0] = *(const u64*)(vrow + (((t * 4 + (lq >> 1)) ^ (lr & 7)) << 3));
                    vb.q[1] = *(const u64*)(vrow + (((t * 4 + 2 + (lq >> 1)) ^ (lr & 7)) << 3));
                    oacc[jn] = __builtin_amdgcn_mfma_f32_16x16x32_bf16(pa.v, vb.v, oacc[jn], 0, 0, 0);
                }
            }
            __builtin_amdgcn_s_setprio(0);
        }
    }

    // epilogue: l already at the right lanes (oacc[8][r], qrow = lq*4+r)
#pragma unroll
    for (int jn = 0; jn < 8; jn++)
#pragma unroll
        for (int r = 0; r < 4; r++) {
            int row = q0 + wq + lq * 4 + r;
            O[(size_t)(b * 2048 + row) * 2048 + h * 128 + jn * 16 + lr] =
                f2bf(oacc[jn][r] / oacc[8][r]);
        }
}

// ==========================================================================
extern "C" void kernel_launch(void* const* d_in, const int* in_sizes, int n_in,
                              void* d_out, int out_size, void* d_ws, size_t ws_size,
                              hipStream_t stream) {
    const float* X = (const float*)d_in[0];
    const float* cosb = (const float*)d_in[1];
    const float* sinb = (const float*)d_in[2];
    const float* Wq = (const float*)d_in[3];
    const float* Wk = (const float*)d_in[4];
    const float* Wv = (const float*)d_in[5];
    const float* Wo = (const float*)d_in[6];
    const float* qw = (const float*)d_in[7];
    const float* kw = (const float*)d_in[8];
    float* out = (float*)d_out;
    u16* ws = (u16*)d_ws;

    u16* WqkvT = ws;                    // 4096x2048 = 8388608
    u16* WoT = WqkvT + 8388608;         // 4194304
    u16* Xb = WoT + 4194304;            // 8388608 (dead after QKV GEMM)
    u16* QKVb = Xb + 8388608;           // 4096x4096 = 16777216
    u16* Vtb = QKVb + 16777216;         // 4194304
    u16* Ob = Xb;                       // alias
    // total 41,943,040 u16 = 83.9 MB

    prep_weights<<<dim3(32, 32, 5), dim3(32, 8), 0, stream>>>(Wq, Wk, Wv, Wo, X,
                                                              WqkvT, WoT, Xb);

    gemm256<u16, true><<<dim3(16, 16), 512, 0, stream>>>(Xb, WqkvT, QKVb, Vtb,
                                                         4096, 4096, 2048);

    prep_qkv<<<12288, 256, 0, stream>>>(QKVb, cosb, sinb, qw, kw);

    attn_kernel<<<1024, 256, 0, stream>>>(QKVb, Vtb, Ob);

    gemm128n<float><<<dim3(16, 16), 512, 0, stream>>>(Ob, WoT, out, 4096, 2048, 2048);
}

// Round 14
// 329.759 us; speedup vs baseline: 1.1926x; 1.0016x over previous
//
#include <hip/hip_runtime.h>
#include <hip/hip_bf16.h>

typedef unsigned short u16;
typedef unsigned int u32;
typedef unsigned long long u64;
typedef __attribute__((ext_vector_type(8))) short short8;
typedef __attribute__((ext_vector_type(4))) float floatx4;

#define AS1 __attribute__((address_space(1)))
#define AS3 __attribute__((address_space(3)))

// ---- bf16 <-> f32 helpers (raw bits, RNE) ----
__device__ __forceinline__ float bf2f(u16 u) {
    u32 x = ((u32)u) << 16;
    float f;
    __builtin_memcpy(&f, &x, 4);
    return f;
}
__device__ __forceinline__ u16 f2bf(float f) {
    u32 x;
    __builtin_memcpy(&x, &f, 4);
    u32 r = (x + 0x7fffu + ((x >> 16) & 1u)) >> 16;
    return (u16)r;
}
// packed 2xf32 -> 2xbf16 (v_cvt_pk_bf16_f32), returned as u32 (lo=first)
__device__ __forceinline__ u32 f2bf_pk(float a, float b) {
    __hip_bfloat162 h = __float22bfloat162_rn(float2{a, b});
    u32 r;
    __builtin_memcpy(&r, &h, 4);
    return r;
}

// ==========================================================================
// Merged prep: z<4 = weight transposes (f32 RxC -> bf16 CxR), z=4 = X cast.
// 64x64 tiles, 2x2 micro-tile/thread: float2 reads (8B/lane), u32 packed
// writes (128B/wave segments). Block = dim3(32,8) — 2D indexing required.
// ==========================================================================
__global__ __launch_bounds__(256) void prep_weights(const float* __restrict__ Wq,
                                                    const float* __restrict__ Wk,
                                                    const float* __restrict__ Wv,
                                                    const float* __restrict__ Wo,
                                                    const float* __restrict__ X,
                                                    u16* __restrict__ WqkvT,
                                                    u16* __restrict__ WoT,
                                                    u16* __restrict__ Xb) {
    const int z = blockIdx.z;
    const int tx = threadIdx.x, ty = threadIdx.y;   // 32 x 8
    if (z == 4) {  // X cast: 1024 blocks x 256 thr x 8 float4 = 8.39M f32
        int tid = ty * 32 + tx;
        int idx = blockIdx.y * 32 + blockIdx.x;     // 0..1023
        if (idx >= 1024) return;
        size_t base = (size_t)idx * 256 + tid;
#pragma unroll
        for (int p = 0; p < 8; p++) {
            size_t i = (base + (size_t)p * 262144) * 4;
            float4 v = *(const float4*)(X + i);
            u16 o[4] = {f2bf(v.x), f2bf(v.y), f2bf(v.z), f2bf(v.w)};
            *(u64*)(Xb + i) = *(u64*)o;
        }
        return;
    }
    const float* in;
    u16* out;
    int C;
    if (z == 0) { in = Wq; out = WqkvT; C = 2048; }
    else if (z == 1) { in = Wk; out = WqkvT + 2048 * 2048; C = 1024; }
    else if (z == 2) { in = Wv; out = WqkvT + 3072 * 2048; C = 1024; }
    else { in = Wo; out = WoT; C = 2048; }
    const int c0 = blockIdx.x * 64, r0 = blockIdx.y * 64;
    if (c0 >= C) return;
    __shared__ u16 t[64][66];
#pragma unroll
    for (int p = 0; p < 4; p++) {
        int rr = (ty + 8 * p) * 2;
#pragma unroll
        for (int i = 0; i < 2; i++) {
            float2 v = *(const float2*)(in + (size_t)(r0 + rr + i) * C + c0 + tx * 2);
            *(u32*)&t[rr + i][tx * 2] = f2bf_pk(v.x, v.y);
        }
    }
    __syncthreads();
#pragma unroll
    for (int p = 0; p < 4; p++) {
        int cc = (ty + 8 * p) * 2;
        u32 a = *(const u32*)&t[tx * 2][cc];       // r=2tx : (col cc | col cc+1)
        u32 bq = *(const u32*)&t[tx * 2 + 1][cc];  // r=2tx+1
        u32 pk0 = (a & 0xffffu) | (bq << 16);            // col cc, rows 2tx,2tx+1
        u32 pk1 = (a >> 16) | (bq & 0xffff0000u);        // col cc+1
        *(u32*)(out + (size_t)(c0 + cc) * 2048 + r0 + tx * 2) = pk0;
        *(u32*)(out + (size_t)(c0 + cc + 1) * 2048 + r0 + tx * 2) = pk1;
    }
}

// ==========================================================================
// GEMM: C[M,N] = A[M,K] @ Bt[N,K]^T (bf16 in, fp32 acc, OUT_T out)
// 256x256 tile, BK=64, 512 thr (8 waves 2Mx4N), 8-phase-per-2-K-tiles
// schedule: counted vmcnt(6), raw s_barrier, XOR-swizzled LDS, setprio.
// Flat 256-block grid, XCD-rectangle swizzle: each XCD (id&7) owns a
// 4col x 8row tile rectangle -> its A/B panels (12MB) are L2-resident
// (perf heuristic only; mapping is bijective).
// FUSEV (QKV instantiation only): blocks with n0>=3072 hold the V columns;
// epilogue writes them transposed straight to Vt (b,kv,d,s) as packed u64.
// ==========================================================================
template <typename OUT_T, bool FUSEV>
__global__ __launch_bounds__(512, 2) void gemm256(const u16* __restrict__ A,
                                                  const u16* __restrict__ Bt,
                                                  OUT_T* __restrict__ C,
                                                  u16* __restrict__ Vt,
                                                  int M, int N, int K) {
    (void)M;
    __shared__ __align__(16) u16 lds[2][2][2][128 * 64];  // [buf][A/B][half][r*64+c]
    const int tid = threadIdx.x;
    const int wave = tid >> 6, lane = tid & 63;
    const int lr = lane & 15, lq = lane >> 4;
    const int wm = wave >> 2, wn = wave & 3;
    // XCD-rectangle decode (flat 256-block grid)
    const int id = blockIdx.x;
    const int xcd = id & 7, kk2 = id >> 3;
    const int bx = (xcd & 3) * 4 + (kk2 & 3);
    const int by = (xcd >> 2) * 8 + (kk2 >> 2);
    const int m0 = by * 256, n0 = bx * 256;

    const int srow = lane >> 3;                    // 0..7 within 8-row group
    const int schunk = ((lane & 7) ^ srow) << 3;   // source chunk (elems)
    const int slot = wave << 1;

    auto stage = [&](const u16* src, int rbase, int buf, int mat, int half, int k0) {
#pragma unroll
        for (int j = 0; j < 2; j++) {
            int r = rbase + half * 128 + (slot + j) * 8 + srow;
            __builtin_amdgcn_global_load_lds(
                (const AS1 void*)(src + (size_t)r * K + k0 + schunk),
                (AS3 void*)(&lds[buf][mat][half][(slot + j) * 512]), 16, 0, 0);
        }
    };

    floatx4 zf = {0.f, 0.f, 0.f, 0.f};
    floatx4 acc[8][4];
#pragma unroll
    for (int i = 0; i < 8; i++)
#pragma unroll
        for (int jn = 0; jn < 4; jn++) acc[i][jn] = zf;

    const int NT = K >> 6;

    stage(Bt, n0, 0, 1, 0, 0);
    stage(Bt, n0, 0, 1, 1, 0);
    stage(A, m0, 0, 0, 0, 0);
    stage(A, m0, 0, 0, 1, 0);
    if (NT > 1) {
        stage(Bt, n0, 1, 1, 0, 64);
        stage(Bt, n0, 1, 1, 1, 64);
        stage(A, m0, 1, 0, 0, 64);
        asm volatile("s_waitcnt vmcnt(6)" ::: "memory");
    } else {
        asm volatile("s_waitcnt vmcnt(0)" ::: "memory");
    }
    __builtin_amdgcn_s_barrier();

    for (int kt = 0; kt < NT; kt++) {
        const int b = kt & 1;
        const u16* Ab = &lds[b][0][wm][0];
        const u16* Bb = &lds[b][1][wn >> 1][0];
        const int brow = (wn & 1) * 64;
        const int sx = lr & 7;
        const int nk = (kt + 2) << 6;

        // ---- phase 0 ----
        short8 bf0[4], bf1[4], af[4];
#pragma unroll
        for (int jn = 0; jn < 4; jn++) {
            int rh = brow + jn * 16 + lr;
            bf0[jn] = *(const short8*)(Bb + rh * 64 + ((lq ^ sx) << 3));
            bf1[jn] = *(const short8*)(Bb + rh * 64 + (((4 + lq) ^ sx) << 3));
        }
#pragma unroll
        for (int i = 0; i < 4; i++)
            af[i] = *(const short8*)(Ab + (i * 16 + lr) * 64 + ((lq ^ sx) << 3));
        if (kt + 1 < NT) stage(A, m0, b ^ 1, 0, 1, (kt + 1) << 6);
        __builtin_amdgcn_s_barrier();
        asm volatile("s_waitcnt lgkmcnt(0)" ::: "memory");
        __builtin_amdgcn_sched_barrier(0);
        __builtin_amdgcn_s_setprio(1);
#pragma unroll
        for (int i = 0; i < 4; i++)
#pragma unroll
            for (int jn = 0; jn < 4; jn++)
                acc[i][jn] = __builtin_amdgcn_mfma_f32_16x16x32_bf16(af[i], bf0[jn], acc[i][jn], 0, 0, 0);
        __builtin_amdgcn_s_setprio(0);
        __builtin_amdgcn_s_barrier();

        // ---- phase 1 ----
        short8 ag[4];
#pragma unroll
        for (int i = 0; i < 4; i++)
            ag[i] = *(const short8*)(Ab + ((i + 4) * 16 + lr) * 64 + ((lq ^ sx) << 3));
        if (kt + 2 < NT) stage(Bt, n0, b, 1, 0, nk);
        __builtin_amdgcn_s_barrier();
        asm volatile("s_waitcnt lgkmcnt(0)" ::: "memory");
        __builtin_amdgcn_sched_barrier(0);
        __builtin_amdgcn_s_setprio(1);
#pragma unroll
        for (int i = 0; i < 4; i++)
#pragma unroll
            for (int jn = 0; jn < 4; jn++)
                acc[i + 4][jn] = __builtin_amdgcn_mfma_f32_16x16x32_bf16(ag[i], bf0[jn], acc[i + 4][jn], 0, 0, 0);
        __builtin_amdgcn_s_setprio(0);
        __builtin_amdgcn_s_barrier();

        // ---- phase 2 ----
        short8 c0[4], c1[4];
#pragma unroll
        for (int i = 0; i < 4; i++) {
            c0[i] = *(const short8*)(Ab + (i * 16 + lr) * 64 + (((4 + lq) ^ sx) << 3));
            c1[i] = *(const short8*)(Ab + ((i + 4) * 16 + lr) * 64 + (((4 + lq) ^ sx) << 3));
        }
        if (kt + 2 < NT) stage(Bt, n0, b, 1, 1, nk);
        __builtin_amdgcn_s_barrier();
        asm volatile("s_waitcnt lgkmcnt(0)" ::: "memory");
        __builtin_amdgcn_sched_barrier(0);
        __builtin_amdgcn_s_setprio(1);
#pragma unroll
        for (int i = 0; i < 4; i++)
#pragma unroll
            for (int jn = 0; jn < 4; jn++)
                acc[i][jn] = __builtin_amdgcn_mfma_f32_16x16x32_bf16(c0[i], bf1[jn], acc[i][jn], 0, 0, 0);
        __builtin_amdgcn_s_setprio(0);
        __builtin_amdgcn_s_barrier();

        // ---- phase 3 ----
        if (kt + 2 < NT) stage(A, m0, b, 0, 0, nk);
        __builtin_amdgcn_s_barrier();
        __builtin_amdgcn_s_setprio(1);
#pragma unroll
        for (int i = 0; i < 4; i++)
#pragma unroll
            for (int jn = 0; jn < 4; jn++)
                acc[i + 4][jn] = __builtin_amdgcn_mfma_f32_16x16x32_bf16(c1[i], bf1[jn], acc[i + 4][jn], 0, 0, 0);
        __builtin_amdgcn_s_setprio(0);
        if (kt + 2 < NT) asm volatile("s_waitcnt vmcnt(6)" ::: "memory");
        else asm volatile("s_waitcnt vmcnt(0)" ::: "memory");
        __builtin_amdgcn_s_barrier();
    }

    if (FUSEV && n0 >= 3072) {
        // V columns -> Vt (b,kv,d,s), packed 4-consecutive-s u64 stores.
        const int bb = m0 >> 11;            // batch (256-row tile never straddles)
        const int sbase = (m0 & 2047) + wm * 128 + lq * 4;
#pragma unroll
        for (int i = 0; i < 8; i++)
#pragma unroll
            for (int jn = 0; jn < 4; jn++) {
                int dcol = (n0 - 3072) + wn * 64 + jn * 16 + lr;  // 0..1023
                int kv = dcol >> 7, d = dcol & 127;
                u16 o[4] = {f2bf(acc[i][jn][0]), f2bf(acc[i][jn][1]),
                            f2bf(acc[i][jn][2]), f2bf(acc[i][jn][3])};
                *(u64*)(Vt + (size_t)((bb * 8 + kv) * 128 + d) * 2048 +
                        sbase + i * 16) = *(u64*)o;
            }
        return;
    }

#pragma unroll
    for (int i = 0; i < 8; i++)
#pragma unroll
        for (int jn = 0; jn < 4; jn++)
#pragma unroll
            for (int r = 0; r < 4; r++) {
                int row = m0 + wm * 128 + i * 16 + lq * 4 + r;
                int col = n0 + wn * 64 + jn * 16 + lr;
                if constexpr (sizeof(OUT_T) == 2)
                    C[(size_t)row * N + col] = f2bf(acc[i][jn][r]);
                else
                    C[(size_t)row * N + col] = acc[i][jn][r];
            }
}

// ==========================================================================
// GEMM: BM=256 x BN=128, BK=64, 512 thr = 8 waves (4M x 2N), 64x64/wave.
// Same 8-phase counted-vmcnt schedule; 3 stage-units/tile -> vmcnt(4).
// Flat 256-block grid with the same XCD-rectangle swizzle.
// ==========================================================================
template <typename OUT_T>
__global__ __launch_bounds__(512, 2) void gemm128n(const u16* __restrict__ A,
                                                   const u16* __restrict__ Bt,
                                                   OUT_T* __restrict__ C,
                                                   int M, int N, int K) {
    (void)M;
    __shared__ __align__(16) u16 Abuf[2][2][128 * 64];  // [buf][half][r*64+c]
    __shared__ __align__(16) u16 Bbuf[2][128 * 64];     // [buf][r*64+c]
    const int tid = threadIdx.x;
    const int wave = tid >> 6, lane = tid & 63;
    const int lr = lane & 15, lq = lane >> 4;
    const int wm = wave >> 1, wn = wave & 1;
    const int id = blockIdx.x;
    const int xcd = id & 7, kk2 = id >> 3;
    const int bx = (xcd & 3) * 4 + (kk2 & 3);
    const int by = (xcd >> 2) * 8 + (kk2 >> 2);
    const int m0 = by * 256, n0 = bx * 128;

    const int srow = lane >> 3;
    const int schunk = ((lane & 7) ^ srow) << 3;
    const int slot = wave << 1;

    auto stage = [&](const u16* src, int rowbase, u16* ldsbase, int k0) {
#pragma unroll
        for (int j = 0; j < 2; j++) {
            int r = rowbase + (slot + j) * 8 + srow;
            __builtin_amdgcn_global_load_lds(
                (const AS1 void*)(src + (size_t)r * K + k0 + schunk),
                (AS3 void*)(ldsbase + (slot + j) * 512), 16, 0, 0);
        }
    };

    floatx4 zf = {0.f, 0.f, 0.f, 0.f};
    floatx4 acc[4][4];
#pragma unroll
    for (int i = 0; i < 4; i++)
#pragma unroll
        for (int jn = 0; jn < 4; jn++) acc[i][jn] = zf;

    const int NT = K >> 6;

    // prologue: t0 = {Ah0, Ah1, B}; t1 = {Ah0, B} (Ah1(t1) comes in t0.ph0)
    stage(A, m0, &Abuf[0][0][0], 0);
    stage(A, m0 + 128, &Abuf[0][1][0], 0);
    stage(Bt, n0, &Bbuf[0][0], 0);
    if (NT > 1) {
        stage(A, m0, &Abuf[1][0][0], 64);
        stage(Bt, n0, &Bbuf[1][0], 64);
        asm volatile("s_waitcnt vmcnt(4)" ::: "memory");
    } else {
        asm volatile("s_waitcnt vmcnt(0)" ::: "memory");
    }
    __builtin_amdgcn_s_barrier();

    for (int kt = 0; kt < NT; kt++) {
        const int b = kt & 1;
        const u16* Ab = &Abuf[b][wm >> 1][0];
        const u16* Bb = &Bbuf[b][0];
        const int ar = (wm & 1) * 64;
        const int br = wn * 64;
        const int sx = lr & 7;
        const int nk = (kt + 2) << 6;

        // ---- phase 0: read bf0,bf1,af(kk0); stage Ah1(kt+1); mfma kk0 i0-1 ----
        short8 bf0[4], bf1[4], af[4];
#pragma unroll
        for (int jn = 0; jn < 4; jn++) {
            int rh = br + jn * 16 + lr;
            bf0[jn] = *(const short8*)(Bb + rh * 64 + ((lq ^ sx) << 3));
            bf1[jn] = *(const short8*)(Bb + rh * 64 + (((4 + lq) ^ sx) << 3));
        }
#pragma unroll
        for (int i = 0; i < 4; i++)
            af[i] = *(const short8*)(Ab + (ar + i * 16 + lr) * 64 + ((lq ^ sx) << 3));
        if (kt + 1 < NT) stage(A, m0 + 128, &Abuf[b ^ 1][1][0], (kt + 1) << 6);
        __builtin_amdgcn_s_barrier();
        asm volatile("s_waitcnt lgkmcnt(0)" ::: "memory");
        __builtin_amdgcn_sched_barrier(0);
        __builtin_amdgcn_s_setprio(1);
#pragma unroll
        for (int i = 0; i < 2; i++)
#pragma unroll
            for (int jn = 0; jn < 4; jn++)
                acc[i][jn] = __builtin_amdgcn_mfma_f32_16x16x32_bf16(af[i], bf0[jn], acc[i][jn], 0, 0, 0);
        __builtin_amdgcn_s_setprio(0);
        __builtin_amdgcn_s_barrier();

        // ---- phase 1: stage B(kt+2); mfma kk0 i2-3 ----
        if (kt + 2 < NT) stage(Bt, n0, &Bbuf[b][0], nk);
        __builtin_amdgcn_s_barrier();
        __builtin_amdgcn_s_setprio(1);
#pragma unroll
        for (int i = 2; i < 4; i++)
#pragma unroll
            for (int jn = 0; jn < 4; jn++)
                acc[i][jn] = __builtin_amdgcn_mfma_f32_16x16x32_bf16(af[i], bf0[jn], acc[i][jn], 0, 0, 0);
        __builtin_amdgcn_s_setprio(0);
        __builtin_amdgcn_s_barrier();

        // ---- phase 2: read ag(kk1); mfma kk1 i0-1 ----
        short8 ag[4];
#pragma unroll
        for (int i = 0; i < 4; i++)
            ag[i] = *(const short8*)(Ab + (ar + i * 16 + lr) * 64 + (((4 + lq) ^ sx) << 3));
        __builtin_amdgcn_s_barrier();
        asm volatile("s_waitcnt lgkmcnt(0)" ::: "memory");
        __builtin_amdgcn_sched_barrier(0);
        __builtin_amdgcn_s_setprio(1);
#pragma unroll
        for (int i = 0; i < 2; i++)
#pragma unroll
            for (int jn = 0; jn < 4; jn++)
                acc[i][jn] = __builtin_amdgcn_mfma_f32_16x16x32_bf16(ag[i], bf1[jn], acc[i][jn], 0, 0, 0);
        __builtin_amdgcn_s_setprio(0);
        __builtin_amdgcn_s_barrier();

        // ---- phase 3: stage Ah0(kt+2); mfma kk1 i2-3; counted vmcnt ----
        if (kt + 2 < NT) stage(A, m0, &Abuf[b][0][0], nk);
        __builtin_amdgcn_s_barrier();
        __builtin_amdgcn_s_setprio(1);
#pragma unroll
        for (int i = 2; i < 4; i++)
#pragma unroll
            for (int jn = 0; jn < 4; jn++)
                acc[i][jn] = __builtin_amdgcn_mfma_f32_16x16x32_bf16(ag[i], bf1[jn], acc[i][jn], 0, 0, 0);
        __builtin_amdgcn_s_setprio(0);
        if (kt + 2 < NT) asm volatile("s_waitcnt vmcnt(4)" ::: "memory");
        else asm volatile("s_waitcnt vmcnt(0)" ::: "memory");
        __builtin_amdgcn_s_barrier();
    }

#pragma unroll
    for (int i = 0; i < 4; i++)
#pragma unroll
        for (int jn = 0; jn < 4; jn++)
#pragma unroll
            for (int r = 0; r < 4; r++) {
                int row = m0 + wm * 64 + i * 16 + lq * 4 + r;
                int col = n0 + wn * 64 + jn * 16 + lr;
                if constexpr (sizeof(OUT_T) == 2)
                    C[(size_t)row * N + col] = f2bf(acc[i][jn][r]);
                else
                    C[(size_t)row * N + col] = acc[i][jn][r];
            }
}

// ==========================================================================
// K-only RMS-norm + RoPE (Q norm fused into attn; V fused into gemm256).
// 2 K-rows per wave (u64 = 8B/lane loads, float4 w/cos/sin, half-wave
// shfl reduce). In place on QKV K region. 4096 blocks x 4 waves x 2 rows.
// ==========================================================================
__global__ __launch_bounds__(256) void prep_qkv(u16* __restrict__ QKV,
                                                const float* __restrict__ cosb,
                                                const float* __restrict__ sinb,
                                                const float* __restrict__ kw) {
    const int bx = blockIdx.x;
    const int tid = threadIdx.x;
    const int wave = tid >> 6, lane = tid & 63;
    const int half = lane >> 5, l5 = lane & 31;
    const int t = bx * 4 + wave;        // 0..16383
    const int R = t * 2 + half;         // K row id 0..32767
    const int bs = R >> 3;
    u16* ptr = QKV + (size_t)bs * 4096 + 2048 + (R & 7) * 128;
    const int d = l5 * 4;
    u64 xv = *(const u64*)(ptr + d);
    float x0 = bf2f((u16)xv), x1 = bf2f((u16)(xv >> 16));
    float x2 = bf2f((u16)(xv >> 32)), x3 = bf2f((u16)(xv >> 48));
    float ss = x0 * x0 + x1 * x1 + x2 * x2 + x3 * x3;
#pragma unroll
    for (int off = 1; off < 32; off <<= 1) ss += __shfl_xor(ss, off);
    float rn = rsqrtf(ss * (1.0f / 128.0f) + 1e-6f);
    float4 wv = *(const float4*)(kw + d);
    float y0 = x0 * rn * wv.x, y1 = x1 * rn * wv.y;
    float y2 = x2 * rn * wv.z, y3 = x3 * rn * wv.w;
    // rotate_half partner: d^64 <-> lane l5^16 (same half)
    float p0 = __shfl_xor(y0, 16), p1 = __shfl_xor(y1, 16);
    float p2 = __shfl_xor(y2, 16), p3 = __shfl_xor(y3, 16);
    float sgn = (l5 < 16) ? -1.0f : 1.0f;
    float4 cv = *(const float4*)(cosb + (size_t)bs * 128 + d);
    float4 sv = *(const float4*)(sinb + (size_t)bs * 128 + d);
    float o0 = y0 * cv.x + sgn * p0 * sv.x;
    float o1 = y1 * cv.y + sgn * p1 * sv.y;
    float o2 = y2 * cv.z + sgn * p2 * sv.z;
    float o3 = y3 * cv.w + sgn * p3 * sv.w;
    u64 res = (u64)f2bf_pk(o0, o1) | ((u64)f2bf_pk(o2, o3) << 32);
    *(u64*)(ptr + d) = res;
}

// ==========================================================================
// Causal GQA flash attention, transposed-score formulation.
// QBLK=64 (4 waves, 256 thr), KVBLK=64.
// Q RMS-norm + RoPE fused into the Q-load prologue (Q rows are
// block-private; partner d^64 = fragment t^2, lane-local; row sum via
// shfl_xor(16,32) over lq). QKV Q region stays raw.
// PADDED-GROUP LDS (r12, measured: conflicts 9.2M -> 0-class): 16B pad per
// 1KB staging group. K dbuf + V single + ones rows (l via jn=8 MFMA col).
// Counted-vmcnt barriers (T4); r6 LPT decode (pinned); T5, T13.
// ==========================================================================
__global__ __launch_bounds__(256, 3) void attn_kernel(const u16* __restrict__ QKV,
                                                      const u16* __restrict__ Vt,
                                                      u16* __restrict__ O,
                                                      const float* __restrict__ cosb,
                                                      const float* __restrict__ sinb,
                                                      const float* __restrict__ qw) {
    __shared__ __align__(16) u16 Ks[2][16 * 520];
    __shared__ __align__(16) u16 Vs[18 * 520];
    const int tid = threadIdx.x;
    const int wave = tid >> 6, lane = tid & 63;
    const int lr = lane & 15, lq = lane >> 4;

    // LPT decode: rank 0 = longest (qt=31)
    const int id = blockIdx.x;        // 0..1023
    const int qt = 31 - (id >> 5);
    const int j = id & 31;
    const int h = j & 15;
    const int b = j >> 4;

    const int kv = h >> 1;
    const int q0 = qt * 64;
    const int wq = wave * 16;

    auto stageK = [&](int buf, int k0s) {
#pragma unroll
        for (int jj = 0; jj < 4; jj++) {   // group = 4 rows x 256 B
            int r = wave * 16 + jj * 4 + (lane >> 4);
            int ch = (lane & 15) ^ (r & 15);
            __builtin_amdgcn_global_load_lds(
                (const AS1 void*)(QKV + (size_t)(b * 2048 + k0s + r) * 4096 + 2048 + kv * 128 + ch * 8),
                (AS3 void*)(&Ks[buf][(wave * 4 + jj) * 520]), 16, 0, 0);
        }
    };
    auto stageV = [&](int k0s) {
#pragma unroll
        for (int jj = 0; jj < 4; jj++) {   // group = 8 rows x 128 B
            int r = wave * 32 + jj * 8 + (lane >> 3);
            int ch = (lane & 7) ^ (r & 7);
            __builtin_amdgcn_global_load_lds(
                (const AS1 void*)(Vt + (size_t)((b * 8 + kv) * 128 + r) * 2048 + k0s + ch * 8),
                (AS3 void*)(&Vs[(wave * 4 + jj) * 520]), 16, 0, 0);
        }
    };

    // fill ones groups 16-17 once; pads harmless
#pragma unroll
    for (int k = tid; k < 260; k += 256)
        *(u64*)(&Vs[8320 + k * 4]) = 0x3F803F803F803F80ULL;
    asm volatile("s_waitcnt lgkmcnt(0)" ::: "memory");

    // ---- fused Q-load: raw bf16 -> RMS-norm -> RoPE -> bf16 frags ----
    const int qrow_s = q0 + wq + lr;                 // sequence position
    const u16* qrow = QKV + (size_t)(b * 2048 + qrow_s) * 4096 + h * 128;
    float yv[4][8];
    float ss = 0.f;
#pragma unroll
    for (int t = 0; t < 4; t++) {
        int d0 = t * 32 + lq * 8;
        u64 v0 = *(const u64*)(qrow + d0);
        u64 v1 = *(const u64*)(qrow + d0 + 4);
#pragma unroll
        for (int e = 0; e < 4; e++) {
            yv[t][e] = bf2f((u16)(v0 >> (16 * e)));
            yv[t][e + 4] = bf2f((u16)(v1 >> (16 * e)));
        }
#pragma unroll
        for (int e = 0; e < 8; e++) ss += yv[t][e] * yv[t][e];
    }
    ss += __shfl_xor(ss, 16);
    ss += __shfl_xor(ss, 32);
    {
        float rn = rsqrtf(ss * (1.0f / 128.0f) + 1e-6f);
#pragma unroll
        for (int t = 0; t < 4; t++) {
            int d0 = t * 32 + lq * 8;
            float4 w0 = *(const float4*)(qw + d0);
            float4 w1 = *(const float4*)(qw + d0 + 4);
            yv[t][0] *= rn * w0.x; yv[t][1] *= rn * w0.y;
            yv[t][2] *= rn * w0.z; yv[t][3] *= rn * w0.w;
            yv[t][4] *= rn * w1.x; yv[t][5] *= rn * w1.y;
            yv[t][6] *= rn * w1.z; yv[t][7] *= rn * w1.w;
        }
    }
    const float QS = 0.08838834764831845f * 1.4426950408889634f;  // D^-.5*log2e
    short8 qf[4];
#pragma unroll
    for (int t = 0; t < 4; t++) {
        int d0 = t * 32 + lq * 8;
        const float* cb = cosb + ((size_t)b * 2048 + qrow_s) * 128 + d0;
        const float* sb = sinb + ((size_t)b * 2048 + qrow_s) * 128 + d0;
        float4 c0 = *(const float4*)cb, c1 = *(const float4*)(cb + 4);
        float4 s0 = *(const float4*)sb, s1 = *(const float4*)(sb + 4);
        float sgn = (t < 2) ? -1.0f : 1.0f;
        float o0 = (yv[t][0] * c0.x + sgn * yv[t ^ 2][0] * s0.x) * QS;
        float o1 = (yv[t][1] * c0.y + sgn * yv[t ^ 2][1] * s0.y) * QS;
        float o2 = (yv[t][2] * c0.z + sgn * yv[t ^ 2][2] * s0.z) * QS;
        float o3 = (yv[t][3] * c0.w + sgn * yv[t ^ 2][3] * s0.w) * QS;
        float o4 = (yv[t][4] * c1.x + sgn * yv[t ^ 2][4] * s1.x) * QS;
        float o5 = (yv[t][5] * c1.y + sgn * yv[t ^ 2][5] * s1.y) * QS;
        float o6 = (yv[t][6] * c1.z + sgn * yv[t ^ 2][6] * s1.z) * QS;
        float o7 = (yv[t][7] * c1.w + sgn * yv[t ^ 2][7] * s1.w) * QS;
        union { short8 v; u32 w[4]; } qq;
        qq.w[0] = f2bf_pk(o0, o1); qq.w[1] = f2bf_pk(o2, o3);
        qq.w[2] = f2bf_pk(o4, o5); qq.w[3] = f2bf_pk(o6, o7);
        qf[t] = qq.v;
    }

    floatx4 zf = {0.f, 0.f, 0.f, 0.f};
    floatx4 oacc[9];   // [8] = l column (ones groups of Vs)
#pragma unroll
    for (int jn = 0; jn < 9; jn++) oacc[jn] = zf;
    float mstate = -1e30f;

    const int nIter = qt + 1;

    stageK(0, 0);

    for (int kt = 0; kt < nIter; kt++) {
        const int k0 = kt * 64;
        const int cur = kt & 1;
        // barrier #1: own outstanding = K(kt) only -> vmcnt(0) is exact.
        asm volatile("s_waitcnt vmcnt(0)" ::: "memory");
        __builtin_amdgcn_s_barrier();
        stageV(k0);
        if (kt + 1 < nIter) stageK(cur ^ 1, k0 + 64);

        const bool active = (k0 <= q0 + wq + 15);
        u64 pb[4];
        if (active) {
            const u16* KsC = &Ks[cur][0];
            floatx4 sacc[4];
#pragma unroll
            for (int jm = 0; jm < 4; jm++) sacc[jm] = zf;
            __builtin_amdgcn_s_setprio(1);
#pragma unroll
            for (int t = 0; t < 4; t++) {
                short8 a[4];
#pragma unroll
                for (int jm = 0; jm < 4; jm++) {
                    int off = (jm * 4 + (lr >> 2)) * 520 + (lr & 3) * 128 +
                              (((t * 4 + lq) ^ lr) << 3);
                    a[jm] = *(const short8*)(KsC + off);
                }
#pragma unroll
                for (int jm = 0; jm < 4; jm++)
                    sacc[jm] = __builtin_amdgcn_mfma_f32_16x16x32_bf16(a[jm], qf[t], sacc[jm], 0, 0, 0);
            }
            __builtin_amdgcn_s_setprio(0);

            if (k0 + 63 > q0 + wq) {
#pragma unroll
                for (int jm = 0; jm < 4; jm++) {
                    int diff = (q0 + wq + lr) - (k0 + jm * 16 + lq * 4);
#pragma unroll
                    for (int r = 0; r < 4; r++)
                        if (r > diff) sacc[jm][r] = -1e30f;
                }
            }

            // per-qrow max (tree within jm, then cross-quad)
            float mx = -1e30f;
#pragma unroll
            for (int jm = 0; jm < 4; jm++) {
                float a0 = fmaxf(sacc[jm][0], sacc[jm][1]);
                float a1 = fmaxf(sacc[jm][2], sacc[jm][3]);
                mx = fmaxf(mx, fmaxf(a0, a1));
            }
            mx = fmaxf(mx, __shfl_xor(mx, 16));
            mx = fmaxf(mx, __shfl_xor(mx, 32));

            // T13 defer-max: skip rescale when all rows grew <= 8 (log2 dom)
            bool defer = __all(mx - mstate <= 8.0f);
            float mnew = defer ? mstate : fmaxf(mstate, mx);

#pragma unroll
            for (int jm = 0; jm < 4; jm++)
#pragma unroll
                for (int r = 0; r < 4; r++)
                    sacc[jm][r] = exp2f(sacc[jm][r] - mnew);

            if (!defer) {
                float alpha = exp2f(mstate - mnew);
                mstate = mnew;
                float ao[4];
#pragma unroll
                for (int r = 0; r < 4; r++) ao[r] = __shfl(alpha, lq * 4 + r);
#pragma unroll
                for (int jn = 0; jn < 9; jn++)   // includes l column
#pragma unroll
                    for (int r = 0; r < 4; r++) oacc[jn][r] *= ao[r];
            }

#pragma unroll
            for (int jm = 0; jm < 4; jm++) {
                u32 lo = f2bf_pk(sacc[jm][0], sacc[jm][1]);
                u32 hi = f2bf_pk(sacc[jm][2], sacc[jm][3]);
                pb[jm] = (u64)lo | ((u64)hi << 32);
            }
        }

        // barrier #2: wait ONLY the V loads (first 4 in own queue);
        // K(kt+1) (4 newer loads) stays in flight across PV + next barrier.
        if (kt + 1 < nIter) asm volatile("s_waitcnt vmcnt(4)" ::: "memory");
        else                asm volatile("s_waitcnt vmcnt(0)" ::: "memory");
        __builtin_amdgcn_s_barrier();

        if (active) {
            // O += P @ [V | 1]; jn=8 accumulates l per qrow inside MFMA.
            __builtin_amdgcn_s_setprio(1);
#pragma unroll
            for (int t = 0; t < 2; t++) {
                union { short8 v; u64 q[2]; } pa;
                pa.q[0] = pb[2 * t];
                pa.q[1] = pb[2 * t + 1];
#pragma unroll
                for (int jn = 0; jn < 9; jn++) {
                    const u16* vrow = Vs + (jn * 2 + (lr >> 3)) * 520 +
                                      (lr & 7) * 64 + (lq & 1) * 4;
                    union { short8 v; u64 q[2]; } vb;
                    vb.q[0] = *(const u64*)(vrow + (((t * 4 + (lq >> 1)) ^ (lr & 7)) << 3));
                    vb.q[1] = *(const u64*)(vrow + (((t * 4 + 2 + (lq >> 1)) ^ (lr & 7)) << 3));
                    oacc[jn] = __builtin_amdgcn_mfma_f32_16x16x32_bf16(pa.v, vb.v, oacc[jn], 0, 0, 0);
                }
            }
            __builtin_amdgcn_s_setprio(0);
        }
    }

    // epilogue: l already at the right lanes (oacc[8][r], qrow = lq*4+r)
#pragma unroll
    for (int jn = 0; jn < 8; jn++)
#pragma unroll
        for (int r = 0; r < 4; r++) {
            int row = q0 + wq + lq * 4 + r;
            O[(size_t)(b * 2048 + row) * 2048 + h * 128 + jn * 16 + lr] =
                f2bf(oacc[jn][r] / oacc[8][r]);
        }
}

// ==========================================================================
extern "C" void kernel_launch(void* const* d_in, const int* in_sizes, int n_in,
                              void* d_out, int out_size, void* d_ws, size_t ws_size,
                              hipStream_t stream) {
    const float* X = (const float*)d_in[0];
    const float* cosb = (const float*)d_in[1];
    const float* sinb = (const float*)d_in[2];
    const float* Wq = (const float*)d_in[3];
    const float* Wk = (const float*)d_in[4];
    const float* Wv = (const float*)d_in[5];
    const float* Wo = (const float*)d_in[6];
    const float* qw = (const float*)d_in[7];
    const float* kw = (const float*)d_in[8];
    float* out = (float*)d_out;
    u16* ws = (u16*)d_ws;

    u16* WqkvT = ws;                    // 4096x2048 = 8388608
    u16* WoT = WqkvT + 8388608;         // 4194304
    u16* Xb = WoT + 4194304;            // 8388608 (dead after QKV GEMM)
    u16* QKVb = Xb + 8388608;           // 4096x4096 = 16777216
    u16* Vtb = QKVb + 16777216;         // 4194304
    u16* Ob = Xb;                       // alias
    // total 41,943,040 u16 = 83.9 MB

    prep_weights<<<dim3(32, 32, 5), dim3(32, 8), 0, stream>>>(Wq, Wk, Wv, Wo, X,
                                                              WqkvT, WoT, Xb);

    gemm256<u16, true><<<256, 512, 0, stream>>>(Xb, WqkvT, QKVb, Vtb,
                                                4096, 4096, 2048);

    prep_qkv<<<4096, 256, 0, stream>>>(QKVb, cosb, sinb, kw);

    attn_kernel<<<1024, 256, 0, stream>>>(QKVb, Vtb, Ob, cosb, sinb, qw);

    gemm128n<float><<<256, 512, 0, stream>>>(Ob, WoT, out, 4096, 2048, 2048);
}